// Round 3
// baseline (1531.657 us; speedup 1.0000x reference)
//
#include <hip/hip_runtime.h>

typedef unsigned short USH;
typedef __attribute__((ext_vector_type(8))) short bf16x8;   // 8 bf16 = 4 VGPR
typedef __attribute__((ext_vector_type(4))) float f32x4;

#define MFMA16(a,b,c) __builtin_amdgcn_mfma_f32_16x16x32_bf16((a),(b),(c),0,0,0)

#define BB 4
#define HH 192
#define NN 36864            // 192*192
#define NTOT 147456         // 4*NN
#define CSTR 72             // conv LDS row stride (USH); 70 needed, 72 keeps 16B align; 31.1KB -> 5 blocks/CU

__device__ __forceinline__ float bf2f(USH h) {
    union { unsigned int u; float f; } v; v.u = ((unsigned int)h) << 16; return v.f;
}
__device__ __forceinline__ USH f2bf(float f) {
    union { float f; unsigned int u; } v; v.f = f;
    unsigned int u = v.u;
    return (USH)((u + 0x7FFFu + ((u >> 16) & 1u)) >> 16);
}

// ---------------------------------------------------------------- transpose x: fp32 [b][c][n] -> bf16 [b][n][c]
__global__ void transpose64_k(const float* __restrict__ in, USH* __restrict__ out) {
    __shared__ float tf[64][65];
    int bid = blockIdx.x; int b = bid / 576; int nt = bid - b * 576; int n0 = nt * 64;
    int tid = threadIdx.x;
    for (int p = 0; p < 16; ++p) {
        int idx = p * 256 + tid; int c = idx >> 6, nn = idx & 63;
        tf[nn][c] = in[((size_t)b * 64 + c) * NN + n0 + nn];
    }
    __syncthreads();
    for (int p = 0; p < 16; ++p) {
        int idx = p * 256 + tid; int nn = idx >> 6, c = idx & 63;
        out[((size_t)b * NN + n0 + nn) * 64 + c] = f2bf(tf[nn][c]);
    }
}

// ---------------------------------------------------------------- ALL weight prep in ONE dispatch
// blocks 0..551: conv A-frags (184 blocks x 3 layers); 552..569: qkv frags+bias (6 x 3); 570..571: final frags
struct PrepArgs {
    const float* wq[3]; const float* wk[3]; const float* wv[3];
    const float* qg[3]; const float* qb[3]; const float* vg[3]; const float* vb[3];
    const float* pw[3]; const float* cw;
};
__global__ void prep_all_k(PrepArgs pa, USH* __restrict__ apc, USH* __restrict__ apq,
                           float* __restrict__ biasq, USH* __restrict__ apf) {
    int bid = blockIdx.x, tid = threadIdx.x;
    if (bid < 552) {
        // conv A-frags: chunk cg=(r*4+u)*23+dy ; slot k=(lane>>4)*8+j -> dx=k-r ; kk=lane&15
        int L = bid / 184, cb = bid - L * 184;
        int t = cb * 256 + tid;
        if (t < 736 * 64) {
            const float* pw = pa.pw[L];
            USH* ap = apc + (size_t)L * 376832;       // 736*64*8 USH per layer
            int lane = t & 63, cg = t >> 6;
            int dy = cg % 23; int ru = cg / 23; int u = ru & 3; int r = ru >> 2;
            int kk = lane & 15, q8 = (lane >> 4) * 8;
            for (int j = 0; j < 8; ++j) {
                int k = q8 + j, dx = k - r;
                USH w = 0;
                if (dx >= 0 && dx < 23) w = f2bf(pw[((kk * 4 + u) * 23 + dy) * 23 + dx]);
                ap[t * 8 + j] = w;
            }
        }
    } else if (bid < 570) {
        // qkv A-frags: o = mt*16+(lane&15), c = kc*32+(lane>>4)*8+j
        int idx = bid - 552; int L = idx / 6; int qblk = idx - L * 6;
        int t = qblk * 256 + tid;
        USH* apl = apq + (size_t)L * 12288;
        float* bl = biasq + L * 192;
        if (t < 1536) {
            int lane = t & 63, chunk = t >> 6;
            int mt = chunk >> 1, kc = chunk & 1;
            int o = mt * 16 + (lane & 15);
            int c0 = kc * 32 + (lane >> 4) * 8;
            float scale; const float* wrow;
            if (o < 64)       { scale = pa.qg[L][o]       * rsqrtf(1.0f + 1e-5f); wrow = pa.wq[L] + o * 64; }
            else if (o < 128) { scale = 1.0f;                                     wrow = pa.wk[L] + (o - 64) * 64; }
            else              { scale = pa.vg[L][o - 128] * rsqrtf(1.0f + 1e-5f); wrow = pa.wv[L] + (o - 128) * 64; }
            for (int j = 0; j < 8; ++j) apl[t * 8 + j] = f2bf(wrow[c0 + j] * scale);
        }
        if (t < 192) {
            float bvv;
            if (t < 64) bvv = pa.qb[L][t]; else if (t < 128) bvv = 0.0f; else bvv = pa.vb[L][t - 128];
            bl[t] = bvv;
        }
    } else {
        int t = (bid - 570) * 256 + tid;
        if (t < 512) {
            int lane = t & 63, chunk = t >> 6;
            int mt = chunk >> 1, kc = chunk & 1;
            int o = mt * 16 + (lane & 15);
            int c0 = kc * 32 + (lane >> 4) * 8;
            for (int j = 0; j < 8; ++j) apf[t * 8 + j] = f2bf(pa.cw[o * 64 + c0 + j]);
        }
    }
}

// ---------------------------------------------------------------- QKV GEMM (MFMA, B from global XT)
__global__ __launch_bounds__(256) void qkv_gemm_k(
    const USH* __restrict__ XT, const bf16x8* __restrict__ apre, const float* __restrict__ bias,
    USH* __restrict__ qT, USH* __restrict__ kbuf, USH* __restrict__ vbuf) {
    const int tid = threadIdx.x, lane = tid & 63, wv = tid >> 6;
    const int gw = blockIdx.x * 4 + wv;
    const int nl = lane & 15, quad = lane >> 4;
    bf16x8 afr[24];
    #pragma unroll
    for (int i = 0; i < 24; ++i) afr[i] = apre[i * 64 + lane];
    for (int t = 0; t < 16; ++t) {
        int tile = gw * 16 + t;
        int b = tile / 2304, nt = tile - b * 2304;
        int n = nt * 16 + nl;
        const USH* xrow = XT + ((size_t)b * NN + n) * 64 + quad * 8;
        bf16x8 b0 = *(const bf16x8*)(xrow);
        bf16x8 b1 = *(const bf16x8*)(xrow + 32);
        #pragma unroll
        for (int mt = 0; mt < 12; ++mt) {
            f32x4 acc = {0.f, 0.f, 0.f, 0.f};
            acc = MFMA16(afr[mt * 2 + 0], b0, acc);
            acc = MFMA16(afr[mt * 2 + 1], b1, acc);
            int o0 = mt * 16 + quad * 4;
            float4 bs = *(const float4*)(bias + o0);
            float v0 = acc[0] + bs.x, v1 = acc[1] + bs.y, v2 = acc[2] + bs.z, v3 = acc[3] + bs.w;
            if (mt < 4) {                       // q -> qT[b][n][o] (o = h*16+kk)
                ushort4 pk; pk.x = f2bf(v0); pk.y = f2bf(v1); pk.z = f2bf(v2); pk.w = f2bf(v3);
                *(ushort4*)(qT + ((size_t)b * NN + n) * 64 + o0) = pk;
            } else if (mt < 8) {                // k raw -> kbuf[b][u*16+kk][n]
                int ko = o0 - 64;
                kbuf[((size_t)b * 64 + ko    ) * NN + n] = f2bf(v0);
                kbuf[((size_t)b * 64 + ko + 1) * NN + n] = f2bf(v1);
                kbuf[((size_t)b * 64 + ko + 2) * NN + n] = f2bf(v2);
                kbuf[((size_t)b * 64 + ko + 3) * NN + n] = f2bf(v3);
            } else {                            // v -> vbuf[(b*16+vv)*4+u][n]
                int u = mt - 8, vv0 = quad * 4;
                vbuf[(((size_t)b * 16 + vv0    ) * 4 + u) * NN + n] = f2bf(v0);
                vbuf[(((size_t)b * 16 + vv0 + 1) * 4 + u) * NN + n] = f2bf(v1);
                vbuf[(((size_t)b * 16 + vv0 + 2) * 4 + u) * NN + n] = f2bf(v2);
                vbuf[(((size_t)b * 16 + vv0 + 3) * 4 + u) * NN + n] = f2bf(v3);
            }
        }
    }
}

// ---------------------------------------------------------------- softmax over n, in-place, 1 block/row
__global__ void softmax_k(USH* __restrict__ kbuf) {
    USH* p = kbuf + (size_t)blockIdx.x * NN;
    __shared__ float red[64];
    int tid = threadIdx.x, lane = tid & 63, w = tid >> 6;
    float m = -1e30f;
    for (int i = tid; i < NN; i += 1024) m = fmaxf(m, bf2f(p[i]));
    for (int off = 32; off; off >>= 1) m = fmaxf(m, __shfl_down(m, off));
    if (lane == 0) red[w] = m;
    __syncthreads();
    if (tid == 0) { float mm = red[0]; for (int i = 1; i < 16; ++i) mm = fmaxf(mm, red[i]); red[16] = mm; }
    __syncthreads();
    float M = red[16];
    float s = 0.f;
    for (int i = tid; i < NN; i += 1024) s += __expf(bf2f(p[i]) - M);
    for (int off = 32; off; off >>= 1) s += __shfl_down(s, off);
    if (lane == 0) red[32 + w] = s;
    __syncthreads();
    if (tid == 0) { float ss = 0.f; for (int i = 0; i < 16; ++i) ss += red[32 + i]; red[17] = 1.0f / ss; }
    __syncthreads();
    float inv = red[17];
    for (int i = tid; i < NN; i += 1024) p[i] = f2bf(__expf(bf2f(p[i]) - M) * inv);
}

// ---------------------------------------------------------------- lam_c split-K
__global__ void lamc_stage1_k(const USH* __restrict__ kbuf, const USH* __restrict__ vbuf,
                              float* __restrict__ part) {
    int bid = blockIdx.x;                  // (cidx 0..35)*16 + b*4 + u
    int cidx = bid / 16; int rem = bid - cidx * 16; int b = rem >> 2; int u = rem & 3;
    int tid = threadIdx.x; int vv = tid >> 4; int kk = tid & 15;
    const USH* kp = kbuf + ((size_t)b * 64 + u * 16 + kk) * NN + cidx * 1024;
    const USH* vp = vbuf + (((size_t)b * 16 + vv) * 4 + u) * NN + cidx * 1024;
    float acc = 0.f;
    for (int i = 0; i < 1024; i += 4) {
        ushort4 k4 = *(const ushort4*)(kp + i);
        ushort4 v4 = *(const ushort4*)(vp + i);
        acc += bf2f(k4.x) * bf2f(v4.x) + bf2f(k4.y) * bf2f(v4.y)
             + bf2f(k4.z) * bf2f(v4.z) + bf2f(k4.w) * bf2f(v4.w);
    }
    part[((size_t)(cidx * 4 + b) * 4 + u) * 256 + tid] = acc;
}
__global__ void lamc_stage2_k(const float* __restrict__ part, const float* __restrict__ pb,
                              float* __restrict__ lamcf) {
    int b = blockIdx.x, tid = threadIdx.x;   // tid = vv*16+kk
    float acc = 0.f;
    for (int c = 0; c < 36; ++c)
        for (int u = 0; u < 4; ++u)
            acc += part[((size_t)(c * 4 + b) * 4 + u) * 256 + tid];
    lamcf[b * 256 + tid] = acc + pb[tid & 15];   // fold conv bias pb[kk]
}

// ---------------------------------------------------------------- position conv 23x23 (MFMA implicit GEMM)
// + FUSED y-epilogue. 3-way r-blocking, rolled dy (unroll 2).
// THEORY (R3): previous tile 32x96 had LDS 51.9KB -> 3 blocks/CU AND grid 768
// = exactly 3 blocks/CU: zero spare parallelism; 3 waves/SIMD cannot saturate
// the matrix pipes (MfmaUtil stuck at 38%, Occupancy 30%, all data-path fixes
// time-neutral). This version: tile 32x48 (wave = 16y x 24x, xi=3), LDS
// 4*54*72*2 = 31.1KB -> 5 blocks/CU; grid 4x6x64 = 1536 = 6 blocks/CU;
// launch_bounds(256,5) budgets 102 regs for 5 waves/SIMD (20 waves/CU).
// Per-output MFMA/B-read/epilogue unchanged; A-frag L2 traffic doubles (OK).
// D-frag: row kk = quad*4+reg, col y = lane&15. shfl_xor(16,32) completes kk-sum.
__global__ __launch_bounds__(256, 5) void conv_pos_fused_k(
    const USH* __restrict__ vbuf, const bf16x8* __restrict__ apre,
    const USH* __restrict__ qT, const float* __restrict__ lamcf,
    USH* __restrict__ yb) {
    __shared__ __align__(16) USH in_s[4 * 54 * CSTR];     // 31,104 B
    __shared__ float lc_s[16];
    const int xh = blockIdx.x, yt = blockIdx.y, img = blockIdx.z;
    const int b = img >> 4, vvch = img & 15;
    const int tid = threadIdx.x;
    if (tid < 16) lc_s[tid] = lamcf[b * 256 + vvch * 16 + tid];
    {
        const USH* vb = vbuf + (size_t)img * 4 * NN;
        const int y0 = yt * 32 - 11, x0 = xh * 48 - 11;
        for (int idx = tid; idx < 4 * 54 * CSTR; idx += 256) {
            int u = idx / (54 * CSTR);
            int rem = idx - u * (54 * CSTR);
            int rr = rem / CSTR;
            int cc = rem - rr * CSTR;
            int gy = y0 + rr, gx = x0 + cc;
            USH val = 0;
            if (gy >= 0 && gy < HH && gx >= 0 && gx < HH) val = vb[u * NN + gy * HH + gx];
            in_s[idx] = val;
        }
    }
    __syncthreads();

    const int lane = tid & 63, wv = tid >> 6;
    const int wy = wv >> 1, wx = wv & 1;
    const int nl = lane & 15, quad = lane >> 4;
    const USH* sbase = in_s + (wy * 16 + nl) * CSTR + wx * 24 + quad * 8;
    const int ybase = yt * 32 + wy * 16 + nl;
    float lcr0 = lc_s[quad * 4], lcr1 = lc_s[quad * 4 + 1],
          lcr2 = lc_s[quad * 4 + 2], lcr3 = lc_s[quad * 4 + 3];
    const USH* qbase = qT + ((size_t)b * NN + ybase * HH) * 64 + quad * 4;
    USH* ybbase = yb + ((size_t)b * 64 + quad * 16 + vvch) * NN + ybase * HH;

#define CONV_EPILOGUE(ACC, RVAL)                                                            \
    {                                                                                       \
        _Pragma("unroll")                                                                   \
        for (int xi = 0; xi < 3; ++xi) {                                                    \
            int x = xh * 48 + wx * 24 + (RVAL) + 8 * xi;                                    \
            float l0 = ACC[xi][0] + lcr0, l1 = ACC[xi][1] + lcr1;                           \
            float l2 = ACC[xi][2] + lcr2, l3 = ACC[xi][3] + lcr3;                           \
            const USH* qp = qbase + (size_t)x * 64;                                         \
            float s0, s1, s2, s3;                                                           \
            {                                                                               \
                ushort4 q4 = *(const ushort4*)(qp);                                         \
                s0 = bf2f(q4.x) * l0 + bf2f(q4.y) * l1 + bf2f(q4.z) * l2 + bf2f(q4.w) * l3; \
            }                                                                               \
            {                                                                               \
                ushort4 q4 = *(const ushort4*)(qp + 16);                                    \
                s1 = bf2f(q4.x) * l0 + bf2f(q4.y) * l1 + bf2f(q4.z) * l2 + bf2f(q4.w) * l3; \
            }                                                                               \
            {                                                                               \
                ushort4 q4 = *(const ushort4*)(qp + 32);                                    \
                s2 = bf2f(q4.x) * l0 + bf2f(q4.y) * l1 + bf2f(q4.z) * l2 + bf2f(q4.w) * l3; \
            }                                                                               \
            {                                                                               \
                ushort4 q4 = *(const ushort4*)(qp + 48);                                    \
                s3 = bf2f(q4.x) * l0 + bf2f(q4.y) * l1 + bf2f(q4.z) * l2 + bf2f(q4.w) * l3; \
            }                                                                               \
            s0 += __shfl_xor(s0, 16); s0 += __shfl_xor(s0, 32);                             \
            s1 += __shfl_xor(s1, 16); s1 += __shfl_xor(s1, 32);                             \
            s2 += __shfl_xor(s2, 16); s2 += __shfl_xor(s2, 32);                             \
            s3 += __shfl_xor(s3, 16); s3 += __shfl_xor(s3, 32);                             \
            float sel = (quad == 0) ? s0 : (quad == 1) ? s1 : (quad == 2) ? s2 : s3;        \
            ybbase[x] = f2bf(sel);                                                          \
        }                                                                                   \
    }

#define CONV_PASS3(R0)                                                                      \
    {                                                                                       \
        f32x4 acc0[3] = {}; f32x4 acc1[3] = {}; f32x4 acc2[3] = {};                         \
        for (int u = 0; u < 4; ++u) {                                                       \
            const bf16x8* ap0 = apre + ((size_t)((R0) * 4 + u) * 23) * 64 + lane;           \
            const bf16x8* ap1 = ap0 + 4 * 23 * 64;                                          \
            const bf16x8* ap2 = ap0 + 2 * 4 * 23 * 64;                                      \
            const USH* srow = sbase + u * (54 * CSTR);                                      \
            _Pragma("unroll 2")                                                             \
            for (int dy = 0; dy < 23; ++dy) {                                               \
                bf16x8 a0 = *ap0, a1 = *ap1, a2 = *ap2;                                     \
                _Pragma("unroll")                                                           \
                for (int xi = 0; xi < 3; ++xi) {                                            \
                    bf16x8 bfr = *(const bf16x8*)(srow + 8 * xi);                           \
                    acc0[xi] = MFMA16(a0, bfr, acc0[xi]);                                   \
                    acc1[xi] = MFMA16(a1, bfr, acc1[xi]);                                   \
                    acc2[xi] = MFMA16(a2, bfr, acc2[xi]);                                   \
                }                                                                           \
                ap0 += 64; ap1 += 64; ap2 += 64; srow += CSTR;                               \
            }                                                                               \
        }                                                                                   \
        CONV_EPILOGUE(acc0, (R0))                                                           \
        CONV_EPILOGUE(acc1, (R0) + 1)                                                       \
        CONV_EPILOGUE(acc2, (R0) + 2)                                                       \
    }

    CONV_PASS3(0)
    CONV_PASS3(3)
    {   // last pass: r = 6,7
        f32x4 acc0[3] = {}; f32x4 acc1[3] = {};
        for (int u = 0; u < 4; ++u) {
            const bf16x8* ap0 = apre + ((size_t)(6 * 4 + u) * 23) * 64 + lane;
            const bf16x8* ap1 = ap0 + 4 * 23 * 64;
            const USH* srow = sbase + u * (54 * CSTR);
            #pragma unroll 2
            for (int dy = 0; dy < 23; ++dy) {
                bf16x8 a0 = *ap0, a1 = *ap1;
                #pragma unroll
                for (int xi = 0; xi < 3; ++xi) {
                    bf16x8 bfr = *(const bf16x8*)(srow + 8 * xi);
                    acc0[xi] = MFMA16(a0, bfr, acc0[xi]);
                    acc1[xi] = MFMA16(a1, bfr, acc1[xi]);
                }
                ap0 += 64; ap1 += 64; srow += CSTR;
            }
        }
        CONV_EPILOGUE(acc0, 6)
        CONV_EPILOGUE(acc1, 7)
    }
#undef CONV_PASS3
#undef CONV_EPILOGUE
}

// ---------------------------------------------------------------- GroupNorm
__global__ void gn_passA_k(const USH* __restrict__ yb, float* __restrict__ part) {
    int bid = blockIdx.x;                  // (b*8+g)*18 + cz
    int cz = bid % 18; int bg = bid / 18;
    int tid = threadIdx.x;
    const USH* base = yb + (size_t)bg * 8 * NN + cz * 2048;
    float s = 0.f, sq = 0.f;
    for (int c = 0; c < 8; ++c) {
        const USH* p = base + (size_t)c * NN;
        for (int i = tid * 4; i < 2048; i += 1024) {
            ushort4 t4 = *(const ushort4*)(p + i);
            float f0 = bf2f(t4.x), f1 = bf2f(t4.y), f2 = bf2f(t4.z), f3 = bf2f(t4.w);
            s += f0 + f1 + f2 + f3;
            sq += f0 * f0 + f1 * f1 + f2 * f2 + f3 * f3;
        }
    }
    for (int off = 32; off; off >>= 1) { s += __shfl_down(s, off); sq += __shfl_down(sq, off); }
    __shared__ float rs[4], rq[4];
    int w = tid >> 6, lane = tid & 63;
    if (lane == 0) { rs[w] = s; rq[w] = sq; }
    __syncthreads();
    if (tid == 0) {
        part[bid * 2]     = rs[0] + rs[1] + rs[2] + rs[3];
        part[bid * 2 + 1] = rq[0] + rq[1] + rq[2] + rq[3];
    }
}
__global__ void gn_passB_k(const float* __restrict__ part, float* __restrict__ stats) {
    int t = threadIdx.x;
    if (t < 32) {
        float s = 0.f, q = 0.f;
        for (int c = 0; c < 18; ++c) { s += part[(t * 18 + c) * 2]; q += part[(t * 18 + c) * 2 + 1]; }
        float mean = s / 294912.0f;
        float var = q / 294912.0f - mean * mean;
        stats[t * 2] = mean;
        stats[t * 2 + 1] = rsqrtf(fmaxf(var, 0.0f) + 1e-5f);
    }
}
// normalize + affine + transpose to XT[b][n][c]  (gamma/beta fp32)
__global__ void gn_passC_k(const USH* __restrict__ yb, const float* __restrict__ stats,
                           const float* __restrict__ gg, const float* __restrict__ gb,
                           USH* __restrict__ out) {
    __shared__ float tf[64][65];
    __shared__ float sc[64], sb[64];
    int bid = blockIdx.x; int b = bid / 576; int nt = bid - b * 576; int n0 = nt * 64;
    int tid = threadIdx.x;
    if (tid < 64) {
        int g = tid >> 3;
        float mean = stats[(b * 8 + g) * 2], rstd = stats[(b * 8 + g) * 2 + 1];
        float ga = gg[tid];
        sc[tid] = rstd * ga;
        sb[tid] = gb[tid] - mean * rstd * ga;
    }
    __syncthreads();
    for (int p = 0; p < 16; ++p) {
        int idx = p * 256 + tid; int c = idx >> 6, nn = idx & 63;
        tf[nn][c] = bf2f(yb[((size_t)b * 64 + c) * NN + n0 + nn]) * sc[c] + sb[c];
    }
    __syncthreads();
    for (int p = 0; p < 16; ++p) {
        int idx = p * 256 + tid; int nn = idx >> 6, c = idx & 63;
        out[((size_t)b * NN + n0 + nn) * 64 + c] = f2bf(tf[nn][c]);
    }
}

// ---------------------------------------------------------------- final conv1x1 + *0.2 + x (fp32 out)
__global__ __launch_bounds__(256) void final_gemm_k(
    const USH* __restrict__ XT, const bf16x8* __restrict__ apre,
    const float* __restrict__ cb, const float* __restrict__ xin, float* __restrict__ out) {
    const int tid = threadIdx.x, lane = tid & 63, wv = tid >> 6;
    const int gw = blockIdx.x * 4 + wv;
    const int nl = lane & 15, quad = lane >> 4;
    bf16x8 afr[8];
    #pragma unroll
    for (int i = 0; i < 8; ++i) afr[i] = apre[i * 64 + lane];
    for (int t = 0; t < 16; ++t) {
        int tile = gw * 16 + t;
        int b = tile / 2304, nt = tile - b * 2304;
        int n = nt * 16 + nl;
        const USH* xrow = XT + ((size_t)b * NN + n) * 64 + quad * 8;
        bf16x8 b0 = *(const bf16x8*)(xrow);
        bf16x8 b1 = *(const bf16x8*)(xrow + 32);
        #pragma unroll
        for (int mt = 0; mt < 4; ++mt) {
            f32x4 acc = {0.f, 0.f, 0.f, 0.f};
            acc = MFMA16(afr[mt * 2 + 0], b0, acc);
            acc = MFMA16(afr[mt * 2 + 1], b1, acc);
            int o0 = mt * 16 + quad * 4;
            float4 cb4 = *(const float4*)(cb + o0);
            float cbv[4] = { cb4.x, cb4.y, cb4.z, cb4.w };
            #pragma unroll
            for (int rg = 0; rg < 4; ++rg) {
                int o = o0 + rg;
                float xv = xin[((size_t)b * 64 + o) * NN + n];
                out[((size_t)b * 64 + o) * NN + n] = (acc[rg] + cbv[rg]) * 0.2f + xv;
            }
        }
    }
}

// ================================================================ host
extern "C" void kernel_launch(void* const* d_in, const int* in_sizes, int n_in,
                              void* d_out, int out_size, void* d_ws, size_t ws_size,
                              hipStream_t stream) {
    (void)in_sizes; (void)n_in; (void)out_size; (void)ws_size;
    const float* x = (const float*)d_in[0];
    char* ws = (char*)d_ws;

    // Workspace: 4 big bf16 planes + tail (all-layer prep tables) ≈ 78 MiB.
    // ybuf aliases kbuf (kbuf dead after lamc_stage1).
    const size_t SZP = (size_t)NTOT * 64 * 2;          // 18,874,368 B
    USH*   XT    = (USH*)(ws);
    USH*   qT    = (USH*)(ws + SZP);
    USH*   kbuf  = (USH*)(ws + 2 * SZP);
    USH*   ybuf  = kbuf;                               // alias
    USH*   vbuf  = (USH*)(ws + 3 * SZP);
    char*  tail  = ws + 4 * SZP;
    USH*   apc   = (USH*)(tail);            tail += 753664 * 3;   // conv A-frags x3 layers
    USH*   apq   = (USH*)(tail);            tail += 24576 * 3;    // qkv A-frags x3
    float* biasq = (float*)(tail);          tail += 768 * 3;
    USH*   apf   = (USH*)(tail);            tail += 8192;         // final A-frags
    float* lcp   = (float*)(tail);          tail += 589824;       // lam_c partials
    float* lcf   = (float*)(tail);          tail += 4096;         // lam_c + pb, [b][vv][kk]
    float* gnp   = (float*)(tail);          tail += 4608;         // GN partials
    float* gns   = (float*)(tail);                                // GN mean/rstd (256 B)

    PrepArgs pa;
    for (int L = 0; L < 3; ++L) {
        int base = 1 + L * 9;
        pa.wq[L] = (const float*)d_in[base + 0];
        pa.wk[L] = (const float*)d_in[base + 1];
        pa.wv[L] = (const float*)d_in[base + 2];
        pa.qg[L] = (const float*)d_in[base + 3];
        pa.qb[L] = (const float*)d_in[base + 4];
        pa.vg[L] = (const float*)d_in[base + 5];
        pa.vb[L] = (const float*)d_in[base + 6];
        pa.pw[L] = (const float*)d_in[base + 7];
    }
    pa.cw = (const float*)d_in[32];

    transpose64_k<<<2304, 256, 0, stream>>>(x, XT);
    prep_all_k<<<572, 256, 0, stream>>>(pa, apc, apq, biasq, apf);

    for (int L = 0; L < 3; ++L) {
        const float* pb = (const float*)d_in[1 + L * 9 + 8];

        qkv_gemm_k<<<144, 256, 0, stream>>>(XT, (const bf16x8*)apq + (size_t)L * 1536,
                                            biasq + L * 192, qT, kbuf, vbuf);
        softmax_k<<<256, 1024, 0, stream>>>(kbuf);
        lamc_stage1_k<<<576, 256, 0, stream>>>(kbuf, vbuf, lcp);
        lamc_stage2_k<<<4, 256, 0, stream>>>(lcp, pb, lcf);
        dim3 cg(4, 6, 64);
        conv_pos_fused_k<<<cg, 256, 0, stream>>>(vbuf, (const bf16x8*)apc + (size_t)L * 47104,
                                                 qT, lcf, ybuf);
        gn_passA_k<<<576, 256, 0, stream>>>(ybuf, gnp);
        gn_passB_k<<<1, 256, 0, stream>>>(gnp, gns);
        const float* gg = (const float*)d_in[(L == 2) ? 30 : 28];
        const float* gb = (const float*)d_in[(L == 2) ? 31 : 29];
        gn_passC_k<<<2304, 256, 0, stream>>>(ybuf, gns, gg, gb, XT);
    }

    final_gemm_k<<<144, 256, 0, stream>>>(XT, (const bf16x8*)apf,
                                          (const float*)d_in[33], x, (float*)d_out);
}

// Round 4
// 1160.961 us; speedup vs baseline: 1.3193x; 1.3193x over previous
//
#include <hip/hip_runtime.h>

typedef unsigned short USH;
typedef __attribute__((ext_vector_type(8))) short bf16x8;   // 8 bf16 = 4 VGPR
typedef __attribute__((ext_vector_type(4))) float f32x4;

#define MFMA16(a,b,c) __builtin_amdgcn_mfma_f32_16x16x32_bf16((a),(b),(c),0,0,0)

#define BB 4
#define HH 192
#define NN 36864            // 192*192
#define NTOT 147456         // 4*NN
#define CSTR 120            // conv LDS row stride (USH); 118 needed, 120 keeps 16B align, 51.9KB -> 3 blocks/CU

__device__ __forceinline__ float bf2f(USH h) {
    union { unsigned int u; float f; } v; v.u = ((unsigned int)h) << 16; return v.f;
}
__device__ __forceinline__ USH f2bf(float f) {
    union { float f; unsigned int u; } v; v.f = f;
    unsigned int u = v.u;
    return (USH)((u + 0x7FFFu + ((u >> 16) & 1u)) >> 16);
}

// ---------------------------------------------------------------- transpose x: fp32 [b][c][n] -> bf16 [b][n][c]
__global__ void transpose64_k(const float* __restrict__ in, USH* __restrict__ out) {
    __shared__ float tf[64][65];
    int bid = blockIdx.x; int b = bid / 576; int nt = bid - b * 576; int n0 = nt * 64;
    int tid = threadIdx.x;
    for (int p = 0; p < 16; ++p) {
        int idx = p * 256 + tid; int c = idx >> 6, nn = idx & 63;
        tf[nn][c] = in[((size_t)b * 64 + c) * NN + n0 + nn];
    }
    __syncthreads();
    for (int p = 0; p < 16; ++p) {
        int idx = p * 256 + tid; int nn = idx >> 6, c = idx & 63;
        out[((size_t)b * NN + n0 + nn) * 64 + c] = f2bf(tf[nn][c]);
    }
}

// ---------------------------------------------------------------- ALL weight prep in ONE dispatch
// blocks 0..551: conv A-frags (184 blocks x 3 layers); 552..569: qkv frags+bias (6 x 3); 570..571: final frags
struct PrepArgs {
    const float* wq[3]; const float* wk[3]; const float* wv[3];
    const float* qg[3]; const float* qb[3]; const float* vg[3]; const float* vb[3];
    const float* pw[3]; const float* cw;
};
__global__ void prep_all_k(PrepArgs pa, USH* __restrict__ apc, USH* __restrict__ apq,
                           float* __restrict__ biasq, USH* __restrict__ apf) {
    int bid = blockIdx.x, tid = threadIdx.x;
    if (bid < 552) {
        // conv A-frags: chunk cg=(r*4+u)*23+dy ; slot k=(lane>>4)*8+j -> dx=k-r ; kk=lane&15
        int L = bid / 184, cb = bid - L * 184;
        int t = cb * 256 + tid;
        if (t < 736 * 64) {
            const float* pw = pa.pw[L];
            USH* ap = apc + (size_t)L * 376832;       // 736*64*8 USH per layer
            int lane = t & 63, cg = t >> 6;
            int dy = cg % 23; int ru = cg / 23; int u = ru & 3; int r = ru >> 2;
            int kk = lane & 15, q8 = (lane >> 4) * 8;
            for (int j = 0; j < 8; ++j) {
                int k = q8 + j, dx = k - r;
                USH w = 0;
                if (dx >= 0 && dx < 23) w = f2bf(pw[((kk * 4 + u) * 23 + dy) * 23 + dx]);
                ap[t * 8 + j] = w;
            }
        }
    } else if (bid < 570) {
        // qkv A-frags: o = mt*16+(lane&15), c = kc*32+(lane>>4)*8+j
        int idx = bid - 552; int L = idx / 6; int qblk = idx - L * 6;
        int t = qblk * 256 + tid;
        USH* apl = apq + (size_t)L * 12288;
        float* bl = biasq + L * 192;
        if (t < 1536) {
            int lane = t & 63, chunk = t >> 6;
            int mt = chunk >> 1, kc = chunk & 1;
            int o = mt * 16 + (lane & 15);
            int c0 = kc * 32 + (lane >> 4) * 8;
            float scale; const float* wrow;
            if (o < 64)       { scale = pa.qg[L][o]       * rsqrtf(1.0f + 1e-5f); wrow = pa.wq[L] + o * 64; }
            else if (o < 128) { scale = 1.0f;                                     wrow = pa.wk[L] + (o - 64) * 64; }
            else              { scale = pa.vg[L][o - 128] * rsqrtf(1.0f + 1e-5f); wrow = pa.wv[L] + (o - 128) * 64; }
            for (int j = 0; j < 8; ++j) apl[t * 8 + j] = f2bf(wrow[c0 + j] * scale);
        }
        if (t < 192) {
            float bvv;
            if (t < 64) bvv = pa.qb[L][t]; else if (t < 128) bvv = 0.0f; else bvv = pa.vb[L][t - 128];
            bl[t] = bvv;
        }
    } else {
        int t = (bid - 570) * 256 + tid;
        if (t < 512) {
            int lane = t & 63, chunk = t >> 6;
            int mt = chunk >> 1, kc = chunk & 1;
            int o = mt * 16 + (lane & 15);
            int c0 = kc * 32 + (lane >> 4) * 8;
            for (int j = 0; j < 8; ++j) apf[t * 8 + j] = f2bf(pa.cw[o * 64 + c0 + j]);
        }
    }
}

// ---------------------------------------------------------------- QKV GEMM (MFMA, B from global XT)
// R4: grid 144 -> 1152 blocks (0.56 -> 4.5 blocks/CU); 2 tiles/wave instead of 16.
// Memory-bound (~75MB); at 144 blocks there were only 2.25 waves/CU to hide latency.
__global__ __launch_bounds__(256) void qkv_gemm_k(
    const USH* __restrict__ XT, const bf16x8* __restrict__ apre, const float* __restrict__ bias,
    USH* __restrict__ qT, USH* __restrict__ kbuf, USH* __restrict__ vbuf) {
    const int tid = threadIdx.x, lane = tid & 63, wv = tid >> 6;
    const int gw = blockIdx.x * 4 + wv;
    const int nl = lane & 15, quad = lane >> 4;
    bf16x8 afr[24];
    #pragma unroll
    for (int i = 0; i < 24; ++i) afr[i] = apre[i * 64 + lane];
    for (int t = 0; t < 2; ++t) {
        int tile = gw * 2 + t;
        int b = tile / 2304, nt = tile - b * 2304;
        int n = nt * 16 + nl;
        const USH* xrow = XT + ((size_t)b * NN + n) * 64 + quad * 8;
        bf16x8 b0 = *(const bf16x8*)(xrow);
        bf16x8 b1 = *(const bf16x8*)(xrow + 32);
        #pragma unroll
        for (int mt = 0; mt < 12; ++mt) {
            f32x4 acc = {0.f, 0.f, 0.f, 0.f};
            acc = MFMA16(afr[mt * 2 + 0], b0, acc);
            acc = MFMA16(afr[mt * 2 + 1], b1, acc);
            int o0 = mt * 16 + quad * 4;
            float4 bs = *(const float4*)(bias + o0);
            float v0 = acc[0] + bs.x, v1 = acc[1] + bs.y, v2 = acc[2] + bs.z, v3 = acc[3] + bs.w;
            if (mt < 4) {                       // q -> qT[b][n][o] (o = h*16+kk)
                ushort4 pk; pk.x = f2bf(v0); pk.y = f2bf(v1); pk.z = f2bf(v2); pk.w = f2bf(v3);
                *(ushort4*)(qT + ((size_t)b * NN + n) * 64 + o0) = pk;
            } else if (mt < 8) {                // k raw -> kbuf[b][u*16+kk][n]
                int ko = o0 - 64;
                kbuf[((size_t)b * 64 + ko    ) * NN + n] = f2bf(v0);
                kbuf[((size_t)b * 64 + ko + 1) * NN + n] = f2bf(v1);
                kbuf[((size_t)b * 64 + ko + 2) * NN + n] = f2bf(v2);
                kbuf[((size_t)b * 64 + ko + 3) * NN + n] = f2bf(v3);
            } else {                            // v -> vbuf[(b*16+vv)*4+u][n]
                int u = mt - 8, vv0 = quad * 4;
                vbuf[(((size_t)b * 16 + vv0    ) * 4 + u) * NN + n] = f2bf(v0);
                vbuf[(((size_t)b * 16 + vv0 + 1) * 4 + u) * NN + n] = f2bf(v1);
                vbuf[(((size_t)b * 16 + vv0 + 2) * 4 + u) * NN + n] = f2bf(v2);
                vbuf[(((size_t)b * 16 + vv0 + 3) * 4 + u) * NN + n] = f2bf(v3);
            }
        }
    }
}

// ---------------------------------------------------------------- softmax over n, in-place, 1 block/row
// R4: cache the row (73.7KB bf16) in LDS during the max pass; sum + write passes
// read LDS. Global traffic 56.6MB read -> 18.9MB read (+18.9 write unchanged).
__global__ __launch_bounds__(1024) void softmax_k(USH* __restrict__ kbuf) {
    __shared__ USH row_s[NN];                  // 73,728 B
    __shared__ float red[64];
    USH* p = kbuf + (size_t)blockIdx.x * NN;
    int tid = threadIdx.x, lane = tid & 63, w = tid >> 6;
    float m = -1e30f;
    for (int i = tid * 4; i < NN; i += 4096) {
        ushort4 t4 = *(const ushort4*)(p + i);
        *(ushort4*)(row_s + i) = t4;
        m = fmaxf(m, fmaxf(fmaxf(bf2f(t4.x), bf2f(t4.y)), fmaxf(bf2f(t4.z), bf2f(t4.w))));
    }
    for (int off = 32; off; off >>= 1) m = fmaxf(m, __shfl_down(m, off));
    if (lane == 0) red[w] = m;
    __syncthreads();
    if (tid == 0) { float mm = red[0]; for (int i = 1; i < 16; ++i) mm = fmaxf(mm, red[i]); red[16] = mm; }
    __syncthreads();
    float M = red[16];
    float s = 0.f;
    for (int i = tid * 4; i < NN; i += 4096) {
        ushort4 t4 = *(const ushort4*)(row_s + i);
        s += __expf(bf2f(t4.x) - M) + __expf(bf2f(t4.y) - M)
           + __expf(bf2f(t4.z) - M) + __expf(bf2f(t4.w) - M);
    }
    for (int off = 32; off; off >>= 1) s += __shfl_down(s, off);
    if (lane == 0) red[32 + w] = s;
    __syncthreads();
    if (tid == 0) { float ss = 0.f; for (int i = 0; i < 16; ++i) ss += red[32 + i]; red[17] = 1.0f / ss; }
    __syncthreads();
    float inv = red[17];
    for (int i = tid * 4; i < NN; i += 4096) {
        ushort4 t4 = *(const ushort4*)(row_s + i);
        ushort4 o4;
        o4.x = f2bf(__expf(bf2f(t4.x) - M) * inv);
        o4.y = f2bf(__expf(bf2f(t4.y) - M) * inv);
        o4.z = f2bf(__expf(bf2f(t4.z) - M) * inv);
        o4.w = f2bf(__expf(bf2f(t4.w) - M) * inv);
        *(ushort4*)(p + i) = o4;
    }
}

// ---------------------------------------------------------------- lam_c split-K
__global__ void lamc_stage1_k(const USH* __restrict__ kbuf, const USH* __restrict__ vbuf,
                              float* __restrict__ part) {
    int bid = blockIdx.x;                  // (cidx 0..35)*16 + b*4 + u
    int cidx = bid / 16; int rem = bid - cidx * 16; int b = rem >> 2; int u = rem & 3;
    int tid = threadIdx.x; int vv = tid >> 4; int kk = tid & 15;
    const USH* kp = kbuf + ((size_t)b * 64 + u * 16 + kk) * NN + cidx * 1024;
    const USH* vp = vbuf + (((size_t)b * 16 + vv) * 4 + u) * NN + cidx * 1024;
    float acc = 0.f;
    for (int i = 0; i < 1024; i += 4) {
        ushort4 k4 = *(const ushort4*)(kp + i);
        ushort4 v4 = *(const ushort4*)(vp + i);
        acc += bf2f(k4.x) * bf2f(v4.x) + bf2f(k4.y) * bf2f(v4.y)
             + bf2f(k4.z) * bf2f(v4.z) + bf2f(k4.w) * bf2f(v4.w);
    }
    part[((size_t)(cidx * 4 + b) * 4 + u) * 256 + tid] = acc;
}
__global__ void lamc_stage2_k(const float* __restrict__ part, const float* __restrict__ pb,
                              float* __restrict__ lamcf) {
    int b = blockIdx.x, tid = threadIdx.x;   // tid = vv*16+kk
    float acc = 0.f;
    for (int c = 0; c < 36; ++c)
        for (int u = 0; u < 4; ++u)
            acc += part[((size_t)(c * 4 + b) * 4 + u) * 256 + tid];
    lamcf[b * 256 + tid] = acc + pb[tid & 15];   // fold conv bias pb[kk]
}

// ---------------------------------------------------------------- position conv 23x23 (MFMA implicit GEMM)
// + FUSED y-epilogue. EXACT R2 configuration (best measured: 254 us, VGPR 80):
// 3-way r-blocking, rolled dy (unroll 2), tile 32x96, LDS 51.9KB, 3 blocks/CU.
// R3's smaller tile (32x48, 5+ blocks/CU) REGRESSED 40%: per-wave A-load stream
// (736 loads) is fixed overhead; halving MFMA per wave doubled its relative cost.
// Time tracks the per-wave non-MFMA stream; 6x A-reuse is the sweet spot found.
// D-frag: row kk = quad*4+reg, col y = lane&15. shfl_xor(16,32) completes kk-sum.
__global__ __launch_bounds__(256, 3) void conv_pos_fused_k(
    const USH* __restrict__ vbuf, const bf16x8* __restrict__ apre,
    const USH* __restrict__ qT, const float* __restrict__ lamcf,
    USH* __restrict__ yb) {
    __shared__ __align__(16) USH in_s[4 * 54 * CSTR];     // 51,840 B
    __shared__ float lc_s[16];
    const int xh = blockIdx.x, yt = blockIdx.y, img = blockIdx.z;
    const int b = img >> 4, vvch = img & 15;
    const int tid = threadIdx.x;
    if (tid < 16) lc_s[tid] = lamcf[b * 256 + vvch * 16 + tid];
    {
        const USH* vb = vbuf + (size_t)img * 4 * NN;
        const int y0 = yt * 32 - 11, x0 = xh * 96 - 11;
        for (int idx = tid; idx < 4 * 54 * CSTR; idx += 256) {
            int u = idx / (54 * CSTR);
            int rem = idx - u * (54 * CSTR);
            int rr = rem / CSTR;
            int cc = rem - rr * CSTR;
            int gy = y0 + rr, gx = x0 + cc;
            USH val = 0;
            if (gy >= 0 && gy < HH && gx >= 0 && gx < HH) val = vb[u * NN + gy * HH + gx];
            in_s[idx] = val;
        }
    }
    __syncthreads();

    const int lane = tid & 63, wv = tid >> 6;
    const int wy = wv >> 1, wx = wv & 1;
    const int nl = lane & 15, quad = lane >> 4;
    const USH* sbase = in_s + (wy * 16 + nl) * CSTR + wx * 48 + quad * 8;
    const int ybase = yt * 32 + wy * 16 + nl;
    float lcr0 = lc_s[quad * 4], lcr1 = lc_s[quad * 4 + 1],
          lcr2 = lc_s[quad * 4 + 2], lcr3 = lc_s[quad * 4 + 3];
    const USH* qbase = qT + ((size_t)b * NN + ybase * HH) * 64 + quad * 4;
    USH* ybbase = yb + ((size_t)b * 64 + quad * 16 + vvch) * NN + ybase * HH;

#define CONV_EPILOGUE(ACC, RVAL)                                                            \
    {                                                                                       \
        _Pragma("unroll")                                                                   \
        for (int xi = 0; xi < 6; ++xi) {                                                    \
            int x = xh * 96 + wx * 48 + (RVAL) + 8 * xi;                                    \
            float l0 = ACC[xi][0] + lcr0, l1 = ACC[xi][1] + lcr1;                           \
            float l2 = ACC[xi][2] + lcr2, l3 = ACC[xi][3] + lcr3;                           \
            const USH* qp = qbase + (size_t)x * 64;                                         \
            float s0, s1, s2, s3;                                                           \
            {                                                                               \
                ushort4 q4 = *(const ushort4*)(qp);                                         \
                s0 = bf2f(q4.x) * l0 + bf2f(q4.y) * l1 + bf2f(q4.z) * l2 + bf2f(q4.w) * l3; \
            }                                                                               \
            {                                                                               \
                ushort4 q4 = *(const ushort4*)(qp + 16);                                    \
                s1 = bf2f(q4.x) * l0 + bf2f(q4.y) * l1 + bf2f(q4.z) * l2 + bf2f(q4.w) * l3; \
            }                                                                               \
            {                                                                               \
                ushort4 q4 = *(const ushort4*)(qp + 32);                                    \
                s2 = bf2f(q4.x) * l0 + bf2f(q4.y) * l1 + bf2f(q4.z) * l2 + bf2f(q4.w) * l3; \
            }                                                                               \
            {                                                                               \
                ushort4 q4 = *(const ushort4*)(qp + 48);                                    \
                s3 = bf2f(q4.x) * l0 + bf2f(q4.y) * l1 + bf2f(q4.z) * l2 + bf2f(q4.w) * l3; \
            }                                                                               \
            s0 += __shfl_xor(s0, 16); s0 += __shfl_xor(s0, 32);                             \
            s1 += __shfl_xor(s1, 16); s1 += __shfl_xor(s1, 32);                             \
            s2 += __shfl_xor(s2, 16); s2 += __shfl_xor(s2, 32);                             \
            s3 += __shfl_xor(s3, 16); s3 += __shfl_xor(s3, 32);                             \
            float sel = (quad == 0) ? s0 : (quad == 1) ? s1 : (quad == 2) ? s2 : s3;        \
            ybbase[x] = f2bf(sel);                                                          \
        }                                                                                   \
    }

#define CONV_PASS3(R0)                                                                      \
    {                                                                                       \
        f32x4 acc0[6] = {}; f32x4 acc1[6] = {}; f32x4 acc2[6] = {};                         \
        for (int u = 0; u < 4; ++u) {                                                       \
            const bf16x8* ap0 = apre + ((size_t)((R0) * 4 + u) * 23) * 64 + lane;           \
            const bf16x8* ap1 = ap0 + 4 * 23 * 64;                                          \
            const bf16x8* ap2 = ap0 + 2 * 4 * 23 * 64;                                      \
            const USH* srow = sbase + u * (54 * CSTR);                                      \
            _Pragma("unroll 2")                                                             \
            for (int dy = 0; dy < 23; ++dy) {                                               \
                bf16x8 a0 = *ap0, a1 = *ap1, a2 = *ap2;                                     \
                _Pragma("unroll")                                                           \
                for (int xi = 0; xi < 6; ++xi) {                                            \
                    bf16x8 bfr = *(const bf16x8*)(srow + 8 * xi);                           \
                    acc0[xi] = MFMA16(a0, bfr, acc0[xi]);                                   \
                    acc1[xi] = MFMA16(a1, bfr, acc1[xi]);                                   \
                    acc2[xi] = MFMA16(a2, bfr, acc2[xi]);                                   \
                }                                                                           \
                ap0 += 64; ap1 += 64; ap2 += 64; srow += CSTR;                               \
            }                                                                               \
        }                                                                                   \
        CONV_EPILOGUE(acc0, (R0))                                                           \
        CONV_EPILOGUE(acc1, (R0) + 1)                                                       \
        CONV_EPILOGUE(acc2, (R0) + 2)                                                       \
    }

    CONV_PASS3(0)
    CONV_PASS3(3)
    {   // last pass: r = 6,7
        f32x4 acc0[6] = {}; f32x4 acc1[6] = {};
        for (int u = 0; u < 4; ++u) {
            const bf16x8* ap0 = apre + ((size_t)(6 * 4 + u) * 23) * 64 + lane;
            const bf16x8* ap1 = ap0 + 4 * 23 * 64;
            const USH* srow = sbase + u * (54 * CSTR);
            #pragma unroll 2
            for (int dy = 0; dy < 23; ++dy) {
                bf16x8 a0 = *ap0, a1 = *ap1;
                #pragma unroll
                for (int xi = 0; xi < 6; ++xi) {
                    bf16x8 bfr = *(const bf16x8*)(srow + 8 * xi);
                    acc0[xi] = MFMA16(a0, bfr, acc0[xi]);
                    acc1[xi] = MFMA16(a1, bfr, acc1[xi]);
                }
                ap0 += 64; ap1 += 64; srow += CSTR;
            }
        }
        CONV_EPILOGUE(acc0, 6)
        CONV_EPILOGUE(acc1, 7)
    }
#undef CONV_PASS3
#undef CONV_EPILOGUE
}

// ---------------------------------------------------------------- GroupNorm
__global__ void gn_passA_k(const USH* __restrict__ yb, float* __restrict__ part) {
    int bid = blockIdx.x;                  // (b*8+g)*18 + cz
    int cz = bid % 18; int bg = bid / 18;
    int tid = threadIdx.x;
    const USH* base = yb + (size_t)bg * 8 * NN + cz * 2048;
    float s = 0.f, sq = 0.f;
    for (int c = 0; c < 8; ++c) {
        const USH* p = base + (size_t)c * NN;
        for (int i = tid * 4; i < 2048; i += 1024) {
            ushort4 t4 = *(const ushort4*)(p + i);
            float f0 = bf2f(t4.x), f1 = bf2f(t4.y), f2 = bf2f(t4.z), f3 = bf2f(t4.w);
            s += f0 + f1 + f2 + f3;
            sq += f0 * f0 + f1 * f1 + f2 * f2 + f3 * f3;
        }
    }
    for (int off = 32; off; off >>= 1) { s += __shfl_down(s, off); sq += __shfl_down(sq, off); }
    __shared__ float rs[4], rq[4];
    int w = tid >> 6, lane = tid & 63;
    if (lane == 0) { rs[w] = s; rq[w] = sq; }
    __syncthreads();
    if (tid == 0) {
        part[bid * 2]     = rs[0] + rs[1] + rs[2] + rs[3];
        part[bid * 2 + 1] = rq[0] + rq[1] + rq[2] + rq[3];
    }
}
__global__ void gn_passB_k(const float* __restrict__ part, float* __restrict__ stats) {
    int t = threadIdx.x;
    if (t < 32) {
        float s = 0.f, q = 0.f;
        for (int c = 0; c < 18; ++c) { s += part[(t * 18 + c) * 2]; q += part[(t * 18 + c) * 2 + 1]; }
        float mean = s / 294912.0f;
        float var = q / 294912.0f - mean * mean;
        stats[t * 2] = mean;
        stats[t * 2 + 1] = rsqrtf(fmaxf(var, 0.0f) + 1e-5f);
    }
}
// normalize + affine + transpose to XT[b][n][c]  (gamma/beta fp32)
__global__ void gn_passC_k(const USH* __restrict__ yb, const float* __restrict__ stats,
                           const float* __restrict__ gg, const float* __restrict__ gb,
                           USH* __restrict__ out) {
    __shared__ float tf[64][65];
    __shared__ float sc[64], sb[64];
    int bid = blockIdx.x; int b = bid / 576; int nt = bid - b * 576; int n0 = nt * 64;
    int tid = threadIdx.x;
    if (tid < 64) {
        int g = tid >> 3;
        float mean = stats[(b * 8 + g) * 2], rstd = stats[(b * 8 + g) * 2 + 1];
        float ga = gg[tid];
        sc[tid] = rstd * ga;
        sb[tid] = gb[tid] - mean * rstd * ga;
    }
    __syncthreads();
    for (int p = 0; p < 16; ++p) {
        int idx = p * 256 + tid; int c = idx >> 6, nn = idx & 63;
        tf[nn][c] = bf2f(yb[((size_t)b * 64 + c) * NN + n0 + nn]) * sc[c] + sb[c];
    }
    __syncthreads();
    for (int p = 0; p < 16; ++p) {
        int idx = p * 256 + tid; int nn = idx >> 6, c = idx & 63;
        out[((size_t)b * NN + n0 + nn) * 64 + c] = f2bf(tf[nn][c]);
    }
}

// ---------------------------------------------------------------- final conv1x1 + *0.2 + x (fp32 out)
// R4: grid 144 -> 1152 blocks; 2 tiles/wave (memory-bound, needed latency hiding).
__global__ __launch_bounds__(256) void final_gemm_k(
    const USH* __restrict__ XT, const bf16x8* __restrict__ apre,
    const float* __restrict__ cb, const float* __restrict__ xin, float* __restrict__ out) {
    const int tid = threadIdx.x, lane = tid & 63, wv = tid >> 6;
    const int gw = blockIdx.x * 4 + wv;
    const int nl = lane & 15, quad = lane >> 4;
    bf16x8 afr[8];
    #pragma unroll
    for (int i = 0; i < 8; ++i) afr[i] = apre[i * 64 + lane];
    for (int t = 0; t < 2; ++t) {
        int tile = gw * 2 + t;
        int b = tile / 2304, nt = tile - b * 2304;
        int n = nt * 16 + nl;
        const USH* xrow = XT + ((size_t)b * NN + n) * 64 + quad * 8;
        bf16x8 b0 = *(const bf16x8*)(xrow);
        bf16x8 b1 = *(const bf16x8*)(xrow + 32);
        #pragma unroll
        for (int mt = 0; mt < 4; ++mt) {
            f32x4 acc = {0.f, 0.f, 0.f, 0.f};
            acc = MFMA16(afr[mt * 2 + 0], b0, acc);
            acc = MFMA16(afr[mt * 2 + 1], b1, acc);
            int o0 = mt * 16 + quad * 4;
            float4 cb4 = *(const float4*)(cb + o0);
            float cbv[4] = { cb4.x, cb4.y, cb4.z, cb4.w };
            #pragma unroll
            for (int rg = 0; rg < 4; ++rg) {
                int o = o0 + rg;
                float xv = xin[((size_t)b * 64 + o) * NN + n];
                out[((size_t)b * 64 + o) * NN + n] = (acc[rg] + cbv[rg]) * 0.2f + xv;
            }
        }
    }
}

// ================================================================ host
extern "C" void kernel_launch(void* const* d_in, const int* in_sizes, int n_in,
                              void* d_out, int out_size, void* d_ws, size_t ws_size,
                              hipStream_t stream) {
    (void)in_sizes; (void)n_in; (void)out_size; (void)ws_size;
    const float* x = (const float*)d_in[0];
    char* ws = (char*)d_ws;

    // Workspace: 4 big bf16 planes + tail (all-layer prep tables) ≈ 78 MiB.
    // ybuf aliases kbuf (kbuf dead after lamc_stage1).
    const size_t SZP = (size_t)NTOT * 64 * 2;          // 18,874,368 B
    USH*   XT    = (USH*)(ws);
    USH*   qT    = (USH*)(ws + SZP);
    USH*   kbuf  = (USH*)(ws + 2 * SZP);
    USH*   ybuf  = kbuf;                               // alias
    USH*   vbuf  = (USH*)(ws + 3 * SZP);
    char*  tail  = ws + 4 * SZP;
    USH*   apc   = (USH*)(tail);            tail += 753664 * 3;   // conv A-frags x3 layers
    USH*   apq   = (USH*)(tail);            tail += 24576 * 3;    // qkv A-frags x3
    float* biasq = (float*)(tail);          tail += 768 * 3;
    USH*   apf   = (USH*)(tail);            tail += 8192;         // final A-frags
    float* lcp   = (float*)(tail);          tail += 589824;       // lam_c partials
    float* lcf   = (float*)(tail);          tail += 4096;         // lam_c + pb, [b][vv][kk]
    float* gnp   = (float*)(tail);          tail += 4608;         // GN partials
    float* gns   = (float*)(tail);                                // GN mean/rstd (256 B)

    PrepArgs pa;
    for (int L = 0; L < 3; ++L) {
        int base = 1 + L * 9;
        pa.wq[L] = (const float*)d_in[base + 0];
        pa.wk[L] = (const float*)d_in[base + 1];
        pa.wv[L] = (const float*)d_in[base + 2];
        pa.qg[L] = (const float*)d_in[base + 3];
        pa.qb[L] = (const float*)d_in[base + 4];
        pa.vg[L] = (const float*)d_in[base + 5];
        pa.vb[L] = (const float*)d_in[base + 6];
        pa.pw[L] = (const float*)d_in[base + 7];
    }
    pa.cw = (const float*)d_in[32];

    transpose64_k<<<2304, 256, 0, stream>>>(x, XT);
    prep_all_k<<<572, 256, 0, stream>>>(pa, apc, apq, biasq, apf);

    for (int L = 0; L < 3; ++L) {
        const float* pb = (const float*)d_in[1 + L * 9 + 8];

        qkv_gemm_k<<<1152, 256, 0, stream>>>(XT, (const bf16x8*)apq + (size_t)L * 1536,
                                             biasq + L * 192, qT, kbuf, vbuf);
        softmax_k<<<256, 1024, 0, stream>>>(kbuf);
        lamc_stage1_k<<<576, 256, 0, stream>>>(kbuf, vbuf, lcp);
        lamc_stage2_k<<<4, 256, 0, stream>>>(lcp, pb, lcf);
        dim3 cg(2, 6, 64);
        conv_pos_fused_k<<<cg, 256, 0, stream>>>(vbuf, (const bf16x8*)apc + (size_t)L * 47104,
                                                 qT, lcf, ybuf);
        gn_passA_k<<<576, 256, 0, stream>>>(ybuf, gnp);
        gn_passB_k<<<1, 256, 0, stream>>>(gnp, gns);
        const float* gg = (const float*)d_in[(L == 2) ? 30 : 28];
        const float* gb = (const float*)d_in[(L == 2) ? 31 : 29];
        gn_passC_k<<<2304, 256, 0, stream>>>(ybuf, gns, gg, gb, XT);
    }

    final_gemm_k<<<1152, 256, 0, stream>>>(XT, (const bf16x8*)apf,
                                           (const float*)d_in[33], x, (float*)d_out);
}

// Round 5
// 1145.726 us; speedup vs baseline: 1.3368x; 1.0133x over previous
//
#include <hip/hip_runtime.h>

typedef unsigned short USH;
typedef __attribute__((ext_vector_type(8))) short bf16x8;   // 8 bf16 = 4 VGPR
typedef __attribute__((ext_vector_type(4))) float f32x4;

#define MFMA16(a,b,c) __builtin_amdgcn_mfma_f32_16x16x32_bf16((a),(b),(c),0,0,0)

#define BB 4
#define HH 192
#define NN 36864            // 192*192
#define NTOT 147456         // 4*NN
#define CSTR 120            // conv LDS row stride (USH); 118 needed, 120 keeps 16B align, 51.9KB -> 3 blocks/CU

__device__ __forceinline__ float bf2f(USH h) {
    union { unsigned int u; float f; } v; v.u = ((unsigned int)h) << 16; return v.f;
}
__device__ __forceinline__ USH f2bf(float f) {
    union { float f; unsigned int u; } v; v.f = f;
    unsigned int u = v.u;
    return (USH)((u + 0x7FFFu + ((u >> 16) & 1u)) >> 16);
}

// ---------------------------------------------------------------- transpose x: fp32 [b][c][n] -> bf16 [b][n][c]
__global__ void transpose64_k(const float* __restrict__ in, USH* __restrict__ out) {
    __shared__ float tf[64][65];
    int bid = blockIdx.x; int b = bid / 576; int nt = bid - b * 576; int n0 = nt * 64;
    int tid = threadIdx.x;
    for (int p = 0; p < 16; ++p) {
        int idx = p * 256 + tid; int c = idx >> 6, nn = idx & 63;
        tf[nn][c] = in[((size_t)b * 64 + c) * NN + n0 + nn];
    }
    __syncthreads();
    for (int p = 0; p < 16; ++p) {
        int idx = p * 256 + tid; int nn = idx >> 6, c = idx & 63;
        out[((size_t)b * NN + n0 + nn) * 64 + c] = f2bf(tf[nn][c]);
    }
}

// ---------------------------------------------------------------- ALL weight prep in ONE dispatch
struct PrepArgs {
    const float* wq[3]; const float* wk[3]; const float* wv[3];
    const float* qg[3]; const float* qb[3]; const float* vg[3]; const float* vb[3];
    const float* pw[3]; const float* cw;
};
__global__ void prep_all_k(PrepArgs pa, USH* __restrict__ apc, USH* __restrict__ apq,
                           float* __restrict__ biasq, USH* __restrict__ apf) {
    int bid = blockIdx.x, tid = threadIdx.x;
    if (bid < 552) {
        // conv A-frags: chunk cg=(r*4+u)*23+dy ; slot k=(lane>>4)*8+j -> dx=k-r ; kk=lane&15
        int L = bid / 184, cb = bid - L * 184;
        int t = cb * 256 + tid;
        if (t < 736 * 64) {
            const float* pw = pa.pw[L];
            USH* ap = apc + (size_t)L * 376832;       // 736*64*8 USH per layer
            int lane = t & 63, cg = t >> 6;
            int dy = cg % 23; int ru = cg / 23; int u = ru & 3; int r = ru >> 2;
            int kk = lane & 15, q8 = (lane >> 4) * 8;
            for (int j = 0; j < 8; ++j) {
                int k = q8 + j, dx = k - r;
                USH w = 0;
                if (dx >= 0 && dx < 23) w = f2bf(pw[((kk * 4 + u) * 23 + dy) * 23 + dx]);
                ap[t * 8 + j] = w;
            }
        }
    } else if (bid < 570) {
        // qkv A-frags: o = mt*16+(lane&15), c = kc*32+(lane>>4)*8+j
        int idx = bid - 552; int L = idx / 6; int qblk = idx - L * 6;
        int t = qblk * 256 + tid;
        USH* apl = apq + (size_t)L * 12288;
        float* bl = biasq + L * 192;
        if (t < 1536) {
            int lane = t & 63, chunk = t >> 6;
            int mt = chunk >> 1, kc = chunk & 1;
            int o = mt * 16 + (lane & 15);
            int c0 = kc * 32 + (lane >> 4) * 8;
            float scale; const float* wrow;
            if (o < 64)       { scale = pa.qg[L][o]       * rsqrtf(1.0f + 1e-5f); wrow = pa.wq[L] + o * 64; }
            else if (o < 128) { scale = 1.0f;                                     wrow = pa.wk[L] + (o - 64) * 64; }
            else              { scale = pa.vg[L][o - 128] * rsqrtf(1.0f + 1e-5f); wrow = pa.wv[L] + (o - 128) * 64; }
            for (int j = 0; j < 8; ++j) apl[t * 8 + j] = f2bf(wrow[c0 + j] * scale);
        }
        if (t < 192) {
            float bvv;
            if (t < 64) bvv = pa.qb[L][t]; else if (t < 128) bvv = 0.0f; else bvv = pa.vb[L][t - 128];
            bl[t] = bvv;
        }
    } else {
        int t = (bid - 570) * 256 + tid;
        if (t < 512) {
            int lane = t & 63, chunk = t >> 6;
            int mt = chunk >> 1, kc = chunk & 1;
            int o = mt * 16 + (lane & 15);
            int c0 = kc * 32 + (lane >> 4) * 8;
            for (int j = 0; j < 8; ++j) apf[t * 8 + j] = f2bf(pa.cw[o * 64 + c0 + j]);
        }
    }
}

// ---------------------------------------------------------------- QKV GEMM (L0 only; B from global XT)
__global__ __launch_bounds__(256) void qkv_gemm_k(
    const USH* __restrict__ XT, const bf16x8* __restrict__ apre, const float* __restrict__ bias,
    USH* __restrict__ qT, USH* __restrict__ kbuf, USH* __restrict__ vbuf) {
    const int tid = threadIdx.x, lane = tid & 63, wv = tid >> 6;
    const int gw = blockIdx.x * 4 + wv;
    const int nl = lane & 15, quad = lane >> 4;
    bf16x8 afr[24];
    #pragma unroll
    for (int i = 0; i < 24; ++i) afr[i] = apre[i * 64 + lane];
    for (int t = 0; t < 2; ++t) {
        int tile = gw * 2 + t;
        int b = tile / 2304, nt = tile - b * 2304;
        int n = nt * 16 + nl;
        const USH* xrow = XT + ((size_t)b * NN + n) * 64 + quad * 8;
        bf16x8 b0 = *(const bf16x8*)(xrow);
        bf16x8 b1 = *(const bf16x8*)(xrow + 32);
        #pragma unroll
        for (int mt = 0; mt < 12; ++mt) {
            f32x4 acc = {0.f, 0.f, 0.f, 0.f};
            acc = MFMA16(afr[mt * 2 + 0], b0, acc);
            acc = MFMA16(afr[mt * 2 + 1], b1, acc);
            int o0 = mt * 16 + quad * 4;
            float4 bs = *(const float4*)(bias + o0);
            float v0 = acc[0] + bs.x, v1 = acc[1] + bs.y, v2 = acc[2] + bs.z, v3 = acc[3] + bs.w;
            if (mt < 4) {                       // q -> qT[b][n][o] (o = h*16+kk)
                ushort4 pk; pk.x = f2bf(v0); pk.y = f2bf(v1); pk.z = f2bf(v2); pk.w = f2bf(v3);
                *(ushort4*)(qT + ((size_t)b * NN + n) * 64 + o0) = pk;
            } else if (mt < 8) {                // k raw -> kbuf[b][u*16+kk][n]
                int ko = o0 - 64;
                kbuf[((size_t)b * 64 + ko    ) * NN + n] = f2bf(v0);
                kbuf[((size_t)b * 64 + ko + 1) * NN + n] = f2bf(v1);
                kbuf[((size_t)b * 64 + ko + 2) * NN + n] = f2bf(v2);
                kbuf[((size_t)b * 64 + ko + 3) * NN + n] = f2bf(v3);
            } else {                            // v -> vbuf[(b*16+vv)*4+u][n]
                int u = mt - 8, vv0 = quad * 4;
                vbuf[(((size_t)b * 16 + vv0    ) * 4 + u) * NN + n] = f2bf(v0);
                vbuf[(((size_t)b * 16 + vv0 + 1) * 4 + u) * NN + n] = f2bf(v1);
                vbuf[(((size_t)b * 16 + vv0 + 2) * 4 + u) * NN + n] = f2bf(v2);
                vbuf[(((size_t)b * 16 + vv0 + 3) * 4 + u) * NN + n] = f2bf(v3);
            }
        }
    }
}

// ---------------------------------------------------------------- softmax over n, in-place, 1 block/row (LDS row cache)
__global__ __launch_bounds__(1024) void softmax_k(USH* __restrict__ kbuf) {
    __shared__ USH row_s[NN];                  // 73,728 B
    __shared__ float red[64];
    USH* p = kbuf + (size_t)blockIdx.x * NN;
    int tid = threadIdx.x, lane = tid & 63, w = tid >> 6;
    float m = -1e30f;
    for (int i = tid * 4; i < NN; i += 4096) {
        ushort4 t4 = *(const ushort4*)(p + i);
        *(ushort4*)(row_s + i) = t4;
        m = fmaxf(m, fmaxf(fmaxf(bf2f(t4.x), bf2f(t4.y)), fmaxf(bf2f(t4.z), bf2f(t4.w))));
    }
    for (int off = 32; off; off >>= 1) m = fmaxf(m, __shfl_down(m, off));
    if (lane == 0) red[w] = m;
    __syncthreads();
    if (tid == 0) { float mm = red[0]; for (int i = 1; i < 16; ++i) mm = fmaxf(mm, red[i]); red[16] = mm; }
    __syncthreads();
    float M = red[16];
    float s = 0.f;
    for (int i = tid * 4; i < NN; i += 4096) {
        ushort4 t4 = *(const ushort4*)(row_s + i);
        s += __expf(bf2f(t4.x) - M) + __expf(bf2f(t4.y) - M)
           + __expf(bf2f(t4.z) - M) + __expf(bf2f(t4.w) - M);
    }
    for (int off = 32; off; off >>= 1) s += __shfl_down(s, off);
    if (lane == 0) red[32 + w] = s;
    __syncthreads();
    if (tid == 0) { float ss = 0.f; for (int i = 0; i < 16; ++i) ss += red[32 + i]; red[17] = 1.0f / ss; }
    __syncthreads();
    float inv = red[17];
    for (int i = tid * 4; i < NN; i += 4096) {
        ushort4 t4 = *(const ushort4*)(row_s + i);
        ushort4 o4;
        o4.x = f2bf(__expf(bf2f(t4.x) - M) * inv);
        o4.y = f2bf(__expf(bf2f(t4.y) - M) * inv);
        o4.z = f2bf(__expf(bf2f(t4.z) - M) * inv);
        o4.w = f2bf(__expf(bf2f(t4.w) - M) * inv);
        *(ushort4*)(p + i) = o4;
    }
}

// ---------------------------------------------------------------- lam_c split-K
__global__ void lamc_stage1_k(const USH* __restrict__ kbuf, const USH* __restrict__ vbuf,
                              float* __restrict__ part) {
    int bid = blockIdx.x;                  // (cidx 0..35)*16 + b*4 + u
    int cidx = bid / 16; int rem = bid - cidx * 16; int b = rem >> 2; int u = rem & 3;
    int tid = threadIdx.x; int vv = tid >> 4; int kk = tid & 15;
    const USH* kp = kbuf + ((size_t)b * 64 + u * 16 + kk) * NN + cidx * 1024;
    const USH* vp = vbuf + (((size_t)b * 16 + vv) * 4 + u) * NN + cidx * 1024;
    float acc = 0.f;
    for (int i = 0; i < 1024; i += 4) {
        ushort4 k4 = *(const ushort4*)(kp + i);
        ushort4 v4 = *(const ushort4*)(vp + i);
        acc += bf2f(k4.x) * bf2f(v4.x) + bf2f(k4.y) * bf2f(v4.y)
             + bf2f(k4.z) * bf2f(v4.z) + bf2f(k4.w) * bf2f(v4.w);
    }
    part[((size_t)(cidx * 4 + b) * 4 + u) * 256 + tid] = acc;
}
__global__ void lamc_stage2_k(const float* __restrict__ part, const float* __restrict__ pb,
                              float* __restrict__ lamcf) {
    int b = blockIdx.x, tid = threadIdx.x;   // tid = vv*16+kk
    float acc = 0.f;
    for (int c = 0; c < 36; ++c)
        for (int u = 0; u < 4; ++u)
            acc += part[((size_t)(c * 4 + b) * 4 + u) * 256 + tid];
    lamcf[b * 256 + tid] = acc + pb[tid & 15];   // fold conv bias pb[kk]
}

// ---------------------------------------------------------------- position conv 23x23 (MFMA implicit GEMM)
// + FUSED y-epilogue + FUSED GroupNorm partial sums (replaces gn_passA).
// Proven R2 config: 3-way r-blocking, rolled dy (unroll 2), tile 32x96, 3 blocks/CU.
// GN partials: per lane Σw, Σw² over its 48 bf16-rounded outputs (identical data
// gn_passA would have re-read); shfl_xor reduce within 16-lane quad group
// (channel = quad*16+vvch); cross-wave via 128B LDS; 8 floats/block -> gnp2.
__global__ __launch_bounds__(256, 3) void conv_pos_fused_k(
    const USH* __restrict__ vbuf, const bf16x8* __restrict__ apre,
    const USH* __restrict__ qT, const float* __restrict__ lamcf,
    USH* __restrict__ yb, float* __restrict__ gnp2) {
    __shared__ __align__(16) USH in_s[4 * 54 * CSTR];     // 51,840 B
    __shared__ float lc_s[16];
    __shared__ float gn_s[16], gn_q[16];
    const int xh = blockIdx.x, yt = blockIdx.y, img = blockIdx.z;
    const int b = img >> 4, vvch = img & 15;
    const int tid = threadIdx.x;
    if (tid < 16) lc_s[tid] = lamcf[b * 256 + vvch * 16 + tid];
    {
        const USH* vb = vbuf + (size_t)img * 4 * NN;
        const int y0 = yt * 32 - 11, x0 = xh * 96 - 11;
        for (int idx = tid; idx < 4 * 54 * CSTR; idx += 256) {
            int u = idx / (54 * CSTR);
            int rem = idx - u * (54 * CSTR);
            int rr = rem / CSTR;
            int cc = rem - rr * CSTR;
            int gy = y0 + rr, gx = x0 + cc;
            USH val = 0;
            if (gy >= 0 && gy < HH && gx >= 0 && gx < HH) val = vb[u * NN + gy * HH + gx];
            in_s[idx] = val;
        }
    }
    __syncthreads();

    const int lane = tid & 63, wv = tid >> 6;
    const int wy = wv >> 1, wx = wv & 1;
    const int nl = lane & 15, quad = lane >> 4;
    const USH* sbase = in_s + (wy * 16 + nl) * CSTR + wx * 48 + quad * 8;
    const int ybase = yt * 32 + wy * 16 + nl;
    float lcr0 = lc_s[quad * 4], lcr1 = lc_s[quad * 4 + 1],
          lcr2 = lc_s[quad * 4 + 2], lcr3 = lc_s[quad * 4 + 3];
    const USH* qbase = qT + ((size_t)b * NN + ybase * HH) * 64 + quad * 4;
    USH* ybbase = yb + ((size_t)b * 64 + quad * 16 + vvch) * NN + ybase * HH;
    float SG = 0.f, QG = 0.f;

#define CONV_EPILOGUE(ACC, RVAL)                                                            \
    {                                                                                       \
        _Pragma("unroll")                                                                   \
        for (int xi = 0; xi < 6; ++xi) {                                                    \
            int x = xh * 96 + wx * 48 + (RVAL) + 8 * xi;                                    \
            float l0 = ACC[xi][0] + lcr0, l1 = ACC[xi][1] + lcr1;                           \
            float l2 = ACC[xi][2] + lcr2, l3 = ACC[xi][3] + lcr3;                           \
            const USH* qp = qbase + (size_t)x * 64;                                         \
            float s0, s1, s2, s3;                                                           \
            {                                                                               \
                ushort4 q4 = *(const ushort4*)(qp);                                         \
                s0 = bf2f(q4.x) * l0 + bf2f(q4.y) * l1 + bf2f(q4.z) * l2 + bf2f(q4.w) * l3; \
            }                                                                               \
            {                                                                               \
                ushort4 q4 = *(const ushort4*)(qp + 16);                                    \
                s1 = bf2f(q4.x) * l0 + bf2f(q4.y) * l1 + bf2f(q4.z) * l2 + bf2f(q4.w) * l3; \
            }                                                                               \
            {                                                                               \
                ushort4 q4 = *(const ushort4*)(qp + 32);                                    \
                s2 = bf2f(q4.x) * l0 + bf2f(q4.y) * l1 + bf2f(q4.z) * l2 + bf2f(q4.w) * l3; \
            }                                                                               \
            {                                                                               \
                ushort4 q4 = *(const ushort4*)(qp + 48);                                    \
                s3 = bf2f(q4.x) * l0 + bf2f(q4.y) * l1 + bf2f(q4.z) * l2 + bf2f(q4.w) * l3; \
            }                                                                               \
            s0 += __shfl_xor(s0, 16); s0 += __shfl_xor(s0, 32);                             \
            s1 += __shfl_xor(s1, 16); s1 += __shfl_xor(s1, 32);                             \
            s2 += __shfl_xor(s2, 16); s2 += __shfl_xor(s2, 32);                             \
            s3 += __shfl_xor(s3, 16); s3 += __shfl_xor(s3, 32);                             \
            float sel = (quad == 0) ? s0 : (quad == 1) ? s1 : (quad == 2) ? s2 : s3;        \
            USH wo = f2bf(sel);                                                             \
            ybbase[x] = wo;                                                                 \
            float wf = bf2f(wo);                                                            \
            SG += wf; QG += wf * wf;                                                        \
        }                                                                                   \
    }

#define CONV_PASS3(R0)                                                                      \
    {                                                                                       \
        f32x4 acc0[6] = {}; f32x4 acc1[6] = {}; f32x4 acc2[6] = {};                         \
        for (int u = 0; u < 4; ++u) {                                                       \
            const bf16x8* ap0 = apre + ((size_t)((R0) * 4 + u) * 23) * 64 + lane;           \
            const bf16x8* ap1 = ap0 + 4 * 23 * 64;                                          \
            const bf16x8* ap2 = ap0 + 2 * 4 * 23 * 64;                                      \
            const USH* srow = sbase + u * (54 * CSTR);                                      \
            _Pragma("unroll 2")                                                             \
            for (int dy = 0; dy < 23; ++dy) {                                               \
                bf16x8 a0 = *ap0, a1 = *ap1, a2 = *ap2;                                     \
                _Pragma("unroll")                                                           \
                for (int xi = 0; xi < 6; ++xi) {                                            \
                    bf16x8 bfr = *(const bf16x8*)(srow + 8 * xi);                           \
                    acc0[xi] = MFMA16(a0, bfr, acc0[xi]);                                   \
                    acc1[xi] = MFMA16(a1, bfr, acc1[xi]);                                   \
                    acc2[xi] = MFMA16(a2, bfr, acc2[xi]);                                   \
                }                                                                           \
                ap0 += 64; ap1 += 64; ap2 += 64; srow += CSTR;                               \
            }                                                                               \
        }                                                                                   \
        CONV_EPILOGUE(acc0, (R0))                                                           \
        CONV_EPILOGUE(acc1, (R0) + 1)                                                       \
        CONV_EPILOGUE(acc2, (R0) + 2)                                                       \
    }

    CONV_PASS3(0)
    CONV_PASS3(3)
    {   // last pass: r = 6,7
        f32x4 acc0[6] = {}; f32x4 acc1[6] = {};
        for (int u = 0; u < 4; ++u) {
            const bf16x8* ap0 = apre + ((size_t)(6 * 4 + u) * 23) * 64 + lane;
            const bf16x8* ap1 = ap0 + 4 * 23 * 64;
            const USH* srow = sbase + u * (54 * CSTR);
            #pragma unroll 2
            for (int dy = 0; dy < 23; ++dy) {
                bf16x8 a0 = *ap0, a1 = *ap1;
                #pragma unroll
                for (int xi = 0; xi < 6; ++xi) {
                    bf16x8 bfr = *(const bf16x8*)(srow + 8 * xi);
                    acc0[xi] = MFMA16(a0, bfr, acc0[xi]);
                    acc1[xi] = MFMA16(a1, bfr, acc1[xi]);
                }
                ap0 += 64; ap1 += 64; srow += CSTR;
            }
        }
        CONV_EPILOGUE(acc0, 6)
        CONV_EPILOGUE(acc1, 7)
    }
#undef CONV_PASS3
#undef CONV_EPILOGUE

    // GN partials: reduce Σ/Σ² over nl within each quad group (channel fixed)
    SG += __shfl_xor(SG, 1); SG += __shfl_xor(SG, 2); SG += __shfl_xor(SG, 4); SG += __shfl_xor(SG, 8);
    QG += __shfl_xor(QG, 1); QG += __shfl_xor(QG, 2); QG += __shfl_xor(QG, 4); QG += __shfl_xor(QG, 8);
    if (nl == 0) { gn_s[wv * 4 + quad] = SG; gn_q[wv * 4 + quad] = QG; }
    __syncthreads();
    if (tid < 4) {
        float s = gn_s[tid] + gn_s[4 + tid] + gn_s[8 + tid] + gn_s[12 + tid];
        float q = gn_q[tid] + gn_q[4 + tid] + gn_q[8 + tid] + gn_q[12 + tid];
        int lin = img * 12 + yt * 2 + xh;
        gnp2[lin * 8 + tid * 2]     = s;
        gnp2[lin * 8 + tid * 2 + 1] = q;
    }
}

// ---------------------------------------------------------------- GroupNorm stats from conv partials
// gnp2[((b*16+vvch)*12 + tile)*8 + quad*2 + {0,1}] ; group g: quad=g>>1, vvch in (g&1)*8..+8
__global__ void gn_passB_k(const float* __restrict__ gnp2, float* __restrict__ stats) {
    int t = threadIdx.x;
    if (t < 32) {
        int b = t >> 3, g = t & 7;
        int quad = g >> 1, v0 = (g & 1) * 8;
        float s = 0.f, q = 0.f;
        for (int vv = 0; vv < 8; ++vv)
            for (int tile = 0; tile < 12; ++tile) {
                const float* p = gnp2 + ((size_t)((b * 16 + v0 + vv) * 12 + tile)) * 8 + quad * 2;
                s += p[0]; q += p[1];
            }
        float mean = s / 294912.0f;
        float var = q / 294912.0f - mean * mean;
        stats[t * 2] = mean;
        stats[t * 2 + 1] = rsqrtf(fmaxf(var, 0.0f) + 1e-5f);
    }
}

// ---------------------------------------------------------------- FUSED GroupNorm-normalize + QKV GEMM (L->L+1)
// Replaces gn_passC + qkv_gemm: no XT round trip. Per block (b, nt64): normalize
// 64n x 64c tile into LDS f32 (transpose64's conflict-free [64][65] pattern),
// pack B-frags with the same f2bf as the old XT path (bit-identical numerics),
// then the proven 24-MFMA qkv body; wave wq handles n-subtile wq.
__global__ __launch_bounds__(256) void gn_qkv_k(
    const USH* __restrict__ yb, const float* __restrict__ stats,
    const float* __restrict__ gg, const float* __restrict__ gb,
    const bf16x8* __restrict__ apre, const float* __restrict__ bias,
    USH* __restrict__ qT, USH* __restrict__ kbuf, USH* __restrict__ vbuf) {
    __shared__ float tf[64][65];
    __shared__ float sc[64], sb[64];
    const int bid = blockIdx.x; const int b = bid / 576; const int nt = bid - b * 576; const int n0 = nt * 64;
    const int tid = threadIdx.x, lane = tid & 63, wq = tid >> 6;
    const int nl = lane & 15, quad = lane >> 4;
    bf16x8 afr[24];
    #pragma unroll
    for (int i = 0; i < 24; ++i) afr[i] = apre[i * 64 + lane];
    if (tid < 64) {
        int g = tid >> 3;
        float mean = stats[(b * 8 + g) * 2], rstd = stats[(b * 8 + g) * 2 + 1];
        float ga = gg[tid];
        sc[tid] = rstd * ga;
        sb[tid] = gb[tid] - mean * rstd * ga;
    }
    __syncthreads();
    for (int p = 0; p < 8; ++p) {
        int c = p * 8 + (tid >> 5), nn = (tid & 31) * 2;
        ushort2 y2 = *(const ushort2*)(yb + ((size_t)b * 64 + c) * NN + n0 + nn);
        tf[nn][c]     = bf2f(y2.x) * sc[c] + sb[c];
        tf[nn + 1][c] = bf2f(y2.y) * sc[c] + sb[c];
    }
    __syncthreads();
    bf16x8 b0, b1;
    #pragma unroll
    for (int j = 0; j < 8; ++j) {
        b0[j] = (short)f2bf(tf[wq * 16 + nl][quad * 8 + j]);
        b1[j] = (short)f2bf(tf[wq * 16 + nl][32 + quad * 8 + j]);
    }
    const int n = n0 + wq * 16 + nl;
    #pragma unroll
    for (int mt = 0; mt < 12; ++mt) {
        f32x4 acc = {0.f, 0.f, 0.f, 0.f};
        acc = MFMA16(afr[mt * 2 + 0], b0, acc);
        acc = MFMA16(afr[mt * 2 + 1], b1, acc);
        int o0 = mt * 16 + quad * 4;
        float4 bs = *(const float4*)(bias + o0);
        float v0 = acc[0] + bs.x, v1 = acc[1] + bs.y, v2 = acc[2] + bs.z, v3 = acc[3] + bs.w;
        if (mt < 4) {
            ushort4 pk; pk.x = f2bf(v0); pk.y = f2bf(v1); pk.z = f2bf(v2); pk.w = f2bf(v3);
            *(ushort4*)(qT + ((size_t)b * NN + n) * 64 + o0) = pk;
        } else if (mt < 8) {
            int ko = o0 - 64;
            kbuf[((size_t)b * 64 + ko    ) * NN + n] = f2bf(v0);
            kbuf[((size_t)b * 64 + ko + 1) * NN + n] = f2bf(v1);
            kbuf[((size_t)b * 64 + ko + 2) * NN + n] = f2bf(v2);
            kbuf[((size_t)b * 64 + ko + 3) * NN + n] = f2bf(v3);
        } else {
            int u = mt - 8, vv0 = quad * 4;
            vbuf[(((size_t)b * 16 + vv0    ) * 4 + u) * NN + n] = f2bf(v0);
            vbuf[(((size_t)b * 16 + vv0 + 1) * 4 + u) * NN + n] = f2bf(v1);
            vbuf[(((size_t)b * 16 + vv0 + 2) * 4 + u) * NN + n] = f2bf(v2);
            vbuf[(((size_t)b * 16 + vv0 + 3) * 4 + u) * NN + n] = f2bf(v3);
        }
    }
}

// ---------------------------------------------------------------- FUSED GroupNorm-normalize + final conv1x1 + *0.2 + x
__global__ __launch_bounds__(256) void gn_final_k(
    const USH* __restrict__ yb, const float* __restrict__ stats,
    const float* __restrict__ gg, const float* __restrict__ gb,
    const bf16x8* __restrict__ apre, const float* __restrict__ cb,
    const float* __restrict__ xin, float* __restrict__ out) {
    __shared__ float tf[64][65];
    __shared__ float sc[64], sb[64];
    const int bid = blockIdx.x; const int b = bid / 576; const int nt = bid - b * 576; const int n0 = nt * 64;
    const int tid = threadIdx.x, lane = tid & 63, wq = tid >> 6;
    const int nl = lane & 15, quad = lane >> 4;
    bf16x8 afr[8];
    #pragma unroll
    for (int i = 0; i < 8; ++i) afr[i] = apre[i * 64 + lane];
    if (tid < 64) {
        int g = tid >> 3;
        float mean = stats[(b * 8 + g) * 2], rstd = stats[(b * 8 + g) * 2 + 1];
        float ga = gg[tid];
        sc[tid] = rstd * ga;
        sb[tid] = gb[tid] - mean * rstd * ga;
    }
    __syncthreads();
    for (int p = 0; p < 8; ++p) {
        int c = p * 8 + (tid >> 5), nn = (tid & 31) * 2;
        ushort2 y2 = *(const ushort2*)(yb + ((size_t)b * 64 + c) * NN + n0 + nn);
        tf[nn][c]     = bf2f(y2.x) * sc[c] + sb[c];
        tf[nn + 1][c] = bf2f(y2.y) * sc[c] + sb[c];
    }
    __syncthreads();
    bf16x8 b0, b1;
    #pragma unroll
    for (int j = 0; j < 8; ++j) {
        b0[j] = (short)f2bf(tf[wq * 16 + nl][quad * 8 + j]);
        b1[j] = (short)f2bf(tf[wq * 16 + nl][32 + quad * 8 + j]);
    }
    const int n = n0 + wq * 16 + nl;
    #pragma unroll
    for (int mt = 0; mt < 4; ++mt) {
        f32x4 acc = {0.f, 0.f, 0.f, 0.f};
        acc = MFMA16(afr[mt * 2 + 0], b0, acc);
        acc = MFMA16(afr[mt * 2 + 1], b1, acc);
        int o0 = mt * 16 + quad * 4;
        float4 cb4 = *(const float4*)(cb + o0);
        float cbv[4] = { cb4.x, cb4.y, cb4.z, cb4.w };
        #pragma unroll
        for (int rg = 0; rg < 4; ++rg) {
            int o = o0 + rg;
            float xv = xin[((size_t)b * 64 + o) * NN + n];
            out[((size_t)b * 64 + o) * NN + n] = (acc[rg] + cbv[rg]) * 0.2f + xv;
        }
    }
}

// ================================================================ host
extern "C" void kernel_launch(void* const* d_in, const int* in_sizes, int n_in,
                              void* d_out, int out_size, void* d_ws, size_t ws_size,
                              hipStream_t stream) {
    (void)in_sizes; (void)n_in; (void)out_size; (void)ws_size;
    const float* x = (const float*)d_in[0];
    char* ws = (char*)d_ws;

    // 4 bf16 planes, ping-pong aliasing (ybuf(L) = kbuf(L) plane; next-layer k
    // goes to the dead plane): L0 y=P2 -> k'=P0 ; L1 y=P0 -> k'=P2 ; L2 y=P2 -> out.
    const size_t SZP = (size_t)NTOT * 64 * 2;          // 18,874,368 B
    USH*   P0 = (USH*)(ws);                            // XT (L0 input), then k(L1)/y(L1)
    USH*   P1 = (USH*)(ws + SZP);                      // qT (all layers)
    USH*   P2 = (USH*)(ws + 2 * SZP);                  // k(L0)/y(L0), k(L2)/y(L2)
    USH*   P3 = (USH*)(ws + 3 * SZP);                  // v (all layers)
    char*  tail  = ws + 4 * SZP;
    USH*   apc   = (USH*)(tail);            tail += 753664 * 3;   // conv A-frags x3 layers
    USH*   apq   = (USH*)(tail);            tail += 24576 * 3;    // qkv A-frags x3
    float* biasq = (float*)(tail);          tail += 768 * 3;
    USH*   apf   = (USH*)(tail);            tail += 8192;         // final A-frags
    float* lcp   = (float*)(tail);          tail += 589824;       // lam_c partials
    float* lcf   = (float*)(tail);          tail += 4096;         // lam_c + pb, [b][vv][kk]
    float* gnp2  = (float*)(tail);          tail += 24576;        // GN partials from conv (6144 floats)
    float* gns   = (float*)(tail);                                // GN mean/rstd (256 B)

    PrepArgs pa;
    for (int L = 0; L < 3; ++L) {
        int base = 1 + L * 9;
        pa.wq[L] = (const float*)d_in[base + 0];
        pa.wk[L] = (const float*)d_in[base + 1];
        pa.wv[L] = (const float*)d_in[base + 2];
        pa.qg[L] = (const float*)d_in[base + 3];
        pa.qb[L] = (const float*)d_in[base + 4];
        pa.vg[L] = (const float*)d_in[base + 5];
        pa.vb[L] = (const float*)d_in[base + 6];
        pa.pw[L] = (const float*)d_in[base + 7];
    }
    pa.cw = (const float*)d_in[32];

    transpose64_k<<<2304, 256, 0, stream>>>(x, P0);
    prep_all_k<<<572, 256, 0, stream>>>(pa, apc, apq, biasq, apf);

    // L0 qkv from XT
    qkv_gemm_k<<<1152, 256, 0, stream>>>(P0, (const bf16x8*)apq, biasq, P1, P2, P3);

    for (int L = 0; L < 3; ++L) {
        const float* pb = (const float*)d_in[1 + L * 9 + 8];
        USH* kv = (L == 1) ? P0 : P2;          // kbuf == ybuf plane of this layer

        softmax_k<<<256, 1024, 0, stream>>>(kv);
        lamc_stage1_k<<<576, 256, 0, stream>>>(kv, P3, lcp);
        lamc_stage2_k<<<4, 256, 0, stream>>>(lcp, pb, lcf);
        dim3 cg(2, 6, 64);
        conv_pos_fused_k<<<cg, 256, 0, stream>>>(P3, (const bf16x8*)apc + (size_t)L * 47104,
                                                 P1, lcf, kv, gnp2);
        gn_passB_k<<<1, 256, 0, stream>>>(gnp2, gns);
        if (L < 2) {
            const float* gg = (const float*)d_in[28];
            const float* gb = (const float*)d_in[29];
            USH* knext = (L == 0) ? P0 : P2;
            gn_qkv_k<<<2304, 256, 0, stream>>>(kv, gns, gg, gb,
                                               (const bf16x8*)apq + (size_t)(L + 1) * 1536,
                                               biasq + (L + 1) * 192, P1, knext, P3);
        } else {
            const float* gg = (const float*)d_in[30];
            const float* gb = (const float*)d_in[31];
            gn_final_k<<<2304, 256, 0, stream>>>(kv, gns, gg, gb, (const bf16x8*)apf,
                                                 (const float*)d_in[33], x, (float*)d_out);
        }
    }
}

// Round 6
// 1010.636 us; speedup vs baseline: 1.5155x; 1.1337x over previous
//
#include <hip/hip_runtime.h>

typedef unsigned short USH;
typedef __attribute__((ext_vector_type(8))) short bf16x8;   // 8 bf16 = 4 VGPR
typedef __attribute__((ext_vector_type(4))) float f32x4;

#define MFMA16(a,b,c) __builtin_amdgcn_mfma_f32_16x16x32_bf16((a),(b),(c),0,0,0)

#define BB 4
#define HH 192
#define NN 36864            // 192*192
#define NTOT 147456         // 4*NN
#define CSTR 120            // conv LDS row stride (USH); 118 needed, 120 keeps 16B align, 51.9KB -> 3 blocks/CU

__device__ __forceinline__ float bf2f(USH h) {
    union { unsigned int u; float f; } v; v.u = ((unsigned int)h) << 16; return v.f;
}
__device__ __forceinline__ USH f2bf(float f) {
    union { float f; unsigned int u; } v; v.f = f;
    unsigned int u = v.u;
    return (USH)((u + 0x7FFFu + ((u >> 16) & 1u)) >> 16);
}

// ---------------------------------------------------------------- transpose x: fp32 [b][c][n] -> bf16 [b][n][c]
__global__ void transpose64_k(const float* __restrict__ in, USH* __restrict__ out) {
    __shared__ float tf[64][65];
    int bid = blockIdx.x; int b = bid / 576; int nt = bid - b * 576; int n0 = nt * 64;
    int tid = threadIdx.x;
    for (int p = 0; p < 16; ++p) {
        int idx = p * 256 + tid; int c = idx >> 6, nn = idx & 63;
        tf[nn][c] = in[((size_t)b * 64 + c) * NN + n0 + nn];
    }
    __syncthreads();
    for (int p = 0; p < 16; ++p) {
        int idx = p * 256 + tid; int nn = idx >> 6, c = idx & 63;
        out[((size_t)b * NN + n0 + nn) * 64 + c] = f2bf(tf[nn][c]);
    }
}

// ---------------------------------------------------------------- ALL weight prep in ONE dispatch
struct PrepArgs {
    const float* wq[3]; const float* wk[3]; const float* wv[3];
    const float* qg[3]; const float* qb[3]; const float* vg[3]; const float* vb[3];
    const float* pw[3]; const float* cw;
};
__global__ void prep_all_k(PrepArgs pa, USH* __restrict__ apc, USH* __restrict__ apq,
                           float* __restrict__ biasq, USH* __restrict__ apf) {
    int bid = blockIdx.x, tid = threadIdx.x;
    if (bid < 552) {
        // conv A-frags: chunk cg=(r*4+u)*23+dy ; slot k=(lane>>4)*8+j -> dx=k-r ; kk=lane&15
        int L = bid / 184, cb = bid - L * 184;
        int t = cb * 256 + tid;
        if (t < 736 * 64) {
            const float* pw = pa.pw[L];
            USH* ap = apc + (size_t)L * 376832;       // 736*64*8 USH per layer
            int lane = t & 63, cg = t >> 6;
            int dy = cg % 23; int ru = cg / 23; int u = ru & 3; int r = ru >> 2;
            int kk = lane & 15, q8 = (lane >> 4) * 8;
            for (int j = 0; j < 8; ++j) {
                int k = q8 + j, dx = k - r;
                USH w = 0;
                if (dx >= 0 && dx < 23) w = f2bf(pw[((kk * 4 + u) * 23 + dy) * 23 + dx]);
                ap[t * 8 + j] = w;
            }
        }
    } else if (bid < 570) {
        // qkv A-frags: o = mt*16+(lane&15), c = kc*32+(lane>>4)*8+j
        int idx = bid - 552; int L = idx / 6; int qblk = idx - L * 6;
        int t = qblk * 256 + tid;
        USH* apl = apq + (size_t)L * 12288;
        float* bl = biasq + L * 192;
        if (t < 1536) {
            int lane = t & 63, chunk = t >> 6;
            int mt = chunk >> 1, kc = chunk & 1;
            int o = mt * 16 + (lane & 15);
            int c0 = kc * 32 + (lane >> 4) * 8;
            float scale; const float* wrow;
            if (o < 64)       { scale = pa.qg[L][o]       * rsqrtf(1.0f + 1e-5f); wrow = pa.wq[L] + o * 64; }
            else if (o < 128) { scale = 1.0f;                                     wrow = pa.wk[L] + (o - 64) * 64; }
            else              { scale = pa.vg[L][o - 128] * rsqrtf(1.0f + 1e-5f); wrow = pa.wv[L] + (o - 128) * 64; }
            for (int j = 0; j < 8; ++j) apl[t * 8 + j] = f2bf(wrow[c0 + j] * scale);
        }
        if (t < 192) {
            float bvv;
            if (t < 64) bvv = pa.qb[L][t]; else if (t < 128) bvv = 0.0f; else bvv = pa.vb[L][t - 128];
            bl[t] = bvv;
        }
    } else {
        int t = (bid - 570) * 256 + tid;
        if (t < 512) {
            int lane = t & 63, chunk = t >> 6;
            int mt = chunk >> 1, kc = chunk & 1;
            int o = mt * 16 + (lane & 15);
            int c0 = kc * 32 + (lane >> 4) * 8;
            for (int j = 0; j < 8; ++j) apf[t * 8 + j] = f2bf(pa.cw[o * 64 + c0 + j]);
        }
    }
}

// ---------------------------------------------------------------- QKV GEMM (L0 only; B from global XT)
__global__ __launch_bounds__(256) void qkv_gemm_k(
    const USH* __restrict__ XT, const bf16x8* __restrict__ apre, const float* __restrict__ bias,
    USH* __restrict__ qT, USH* __restrict__ kbuf, USH* __restrict__ vbuf) {
    const int tid = threadIdx.x, lane = tid & 63, wv = tid >> 6;
    const int gw = blockIdx.x * 4 + wv;
    const int nl = lane & 15, quad = lane >> 4;
    bf16x8 afr[24];
    #pragma unroll
    for (int i = 0; i < 24; ++i) afr[i] = apre[i * 64 + lane];
    for (int t = 0; t < 2; ++t) {
        int tile = gw * 2 + t;
        int b = tile / 2304, nt = tile - b * 2304;
        int n = nt * 16 + nl;
        const USH* xrow = XT + ((size_t)b * NN + n) * 64 + quad * 8;
        bf16x8 b0 = *(const bf16x8*)(xrow);
        bf16x8 b1 = *(const bf16x8*)(xrow + 32);
        #pragma unroll
        for (int mt = 0; mt < 12; ++mt) {
            f32x4 acc = {0.f, 0.f, 0.f, 0.f};
            acc = MFMA16(afr[mt * 2 + 0], b0, acc);
            acc = MFMA16(afr[mt * 2 + 1], b1, acc);
            int o0 = mt * 16 + quad * 4;
            float4 bs = *(const float4*)(bias + o0);
            float v0 = acc[0] + bs.x, v1 = acc[1] + bs.y, v2 = acc[2] + bs.z, v3 = acc[3] + bs.w;
            if (mt < 4) {                       // q -> qT[b][n][o] (o = h*16+kk)
                ushort4 pk; pk.x = f2bf(v0); pk.y = f2bf(v1); pk.z = f2bf(v2); pk.w = f2bf(v3);
                *(ushort4*)(qT + ((size_t)b * NN + n) * 64 + o0) = pk;
            } else if (mt < 8) {                // k raw -> kbuf[b][u*16+kk][n]
                int ko = o0 - 64;
                kbuf[((size_t)b * 64 + ko    ) * NN + n] = f2bf(v0);
                kbuf[((size_t)b * 64 + ko + 1) * NN + n] = f2bf(v1);
                kbuf[((size_t)b * 64 + ko + 2) * NN + n] = f2bf(v2);
                kbuf[((size_t)b * 64 + ko + 3) * NN + n] = f2bf(v3);
            } else {                            // v -> vbuf[(b*16+vv)*4+u][n]
                int u = mt - 8, vv0 = quad * 4;
                vbuf[(((size_t)b * 16 + vv0    ) * 4 + u) * NN + n] = f2bf(v0);
                vbuf[(((size_t)b * 16 + vv0 + 1) * 4 + u) * NN + n] = f2bf(v1);
                vbuf[(((size_t)b * 16 + vv0 + 2) * 4 + u) * NN + n] = f2bf(v2);
                vbuf[(((size_t)b * 16 + vv0 + 3) * 4 + u) * NN + n] = f2bf(v3);
            }
        }
    }
}

// ---------------------------------------------------------------- softmax over n, in-place, 1 block/row (LDS row cache)
__global__ __launch_bounds__(1024) void softmax_k(USH* __restrict__ kbuf) {
    __shared__ USH row_s[NN];                  // 73,728 B
    __shared__ float red[64];
    USH* p = kbuf + (size_t)blockIdx.x * NN;
    int tid = threadIdx.x, lane = tid & 63, w = tid >> 6;
    float m = -1e30f;
    for (int i = tid * 4; i < NN; i += 4096) {
        ushort4 t4 = *(const ushort4*)(p + i);
        *(ushort4*)(row_s + i) = t4;
        m = fmaxf(m, fmaxf(fmaxf(bf2f(t4.x), bf2f(t4.y)), fmaxf(bf2f(t4.z), bf2f(t4.w))));
    }
    for (int off = 32; off; off >>= 1) m = fmaxf(m, __shfl_down(m, off));
    if (lane == 0) red[w] = m;
    __syncthreads();
    if (tid == 0) { float mm = red[0]; for (int i = 1; i < 16; ++i) mm = fmaxf(mm, red[i]); red[16] = mm; }
    __syncthreads();
    float M = red[16];
    float s = 0.f;
    for (int i = tid * 4; i < NN; i += 4096) {
        ushort4 t4 = *(const ushort4*)(row_s + i);
        s += __expf(bf2f(t4.x) - M) + __expf(bf2f(t4.y) - M)
           + __expf(bf2f(t4.z) - M) + __expf(bf2f(t4.w) - M);
    }
    for (int off = 32; off; off >>= 1) s += __shfl_down(s, off);
    if (lane == 0) red[32 + w] = s;
    __syncthreads();
    if (tid == 0) { float ss = 0.f; for (int i = 0; i < 16; ++i) ss += red[32 + i]; red[17] = 1.0f / ss; }
    __syncthreads();
    float inv = red[17];
    for (int i = tid * 4; i < NN; i += 4096) {
        ushort4 t4 = *(const ushort4*)(row_s + i);
        ushort4 o4;
        o4.x = f2bf(__expf(bf2f(t4.x) - M) * inv);
        o4.y = f2bf(__expf(bf2f(t4.y) - M) * inv);
        o4.z = f2bf(__expf(bf2f(t4.z) - M) * inv);
        o4.w = f2bf(__expf(bf2f(t4.w) - M) * inv);
        *(ushort4*)(p + i) = o4;
    }
}

// ---------------------------------------------------------------- lam_c split-K stage 1 -- MFMA version (R6)
// lam_c[b,u][kk][vv] = sum_n k[kk][n] * v[vv][n]  ==  16x16 GEMM, K = NN.
// Old form had 16x read redundancy (every k elem read by 16 vv-threads and
// vice versa: ~590MB L2 traffic). MFMA form reads each element ONCE (37.8MB):
// A-frag = k row (lane&15 = kk, (lane>>4)*8+j along n), B-frag = v row
// (lane&15 = vv), 32 MFMAs over the 1024-n chunk, 1 wave per block.
// D mapping: col = lane&15 -> vv, row = quad*4+reg -> kk; partial written at
// the same vv*16+kk linear index as before, so stage2 is unchanged.
__global__ __launch_bounds__(64) void lamc_stage1_k(
    const USH* __restrict__ kbuf, const USH* __restrict__ vbuf,
    float* __restrict__ part) {
    int bid = blockIdx.x;                  // (cidx 0..35)*16 + b*4 + u
    int cidx = bid / 16; int rem = bid - cidx * 16; int b = rem >> 2; int u = rem & 3;
    int lane = threadIdx.x; int nl = lane & 15, quad = lane >> 4;
    const USH* kp = kbuf + ((size_t)b * 64 + u * 16 + nl) * NN + cidx * 1024 + quad * 8;
    const USH* vp = vbuf + (((size_t)b * 16 + nl) * 4 + u) * NN + cidx * 1024 + quad * 8;
    f32x4 acc = {0.f, 0.f, 0.f, 0.f};
    #pragma unroll 4
    for (int s = 0; s < 32; ++s) {
        bf16x8 ka = *(const bf16x8*)(kp + s * 32);
        bf16x8 va = *(const bf16x8*)(vp + s * 32);
        acc = MFMA16(ka, va, acc);
    }
    float* pout = part + ((size_t)(cidx * 4 + b) * 4 + u) * 256;
    #pragma unroll
    for (int rg = 0; rg < 4; ++rg)
        pout[nl * 16 + quad * 4 + rg] = acc[rg];
}
__global__ void lamc_stage2_k(const float* __restrict__ part, const float* __restrict__ pb,
                              float* __restrict__ lamcf) {
    int b = blockIdx.x, tid = threadIdx.x;   // tid = vv*16+kk
    float acc = 0.f;
    for (int c = 0; c < 36; ++c)
        for (int u = 0; u < 4; ++u)
            acc += part[((size_t)(c * 4 + b) * 4 + u) * 256 + tid];
    lamcf[b * 256 + tid] = acc + pb[tid & 15];   // fold conv bias pb[kk]
}

// ---------------------------------------------------------------- position conv 23x23 (MFMA implicit GEMM)
// + FUSED y-epilogue + FUSED GroupNorm partial sums (replaces gn_passA).
// Proven R2 config: 3-way r-blocking, rolled dy (unroll 2), tile 32x96, 3 blocks/CU.
// GN partials: per lane Σw, Σw² over its 48 bf16-rounded outputs (identical data
// gn_passA would have re-read); shfl_xor reduce within 16-lane quad group
// (channel = quad*16+vvch); cross-wave via 128B LDS; 8 floats/block -> gnp2.
__global__ __launch_bounds__(256, 3) void conv_pos_fused_k(
    const USH* __restrict__ vbuf, const bf16x8* __restrict__ apre,
    const USH* __restrict__ qT, const float* __restrict__ lamcf,
    USH* __restrict__ yb, float* __restrict__ gnp2) {
    __shared__ __align__(16) USH in_s[4 * 54 * CSTR];     // 51,840 B
    __shared__ float lc_s[16];
    __shared__ float gn_s[16], gn_q[16];
    const int xh = blockIdx.x, yt = blockIdx.y, img = blockIdx.z;
    const int b = img >> 4, vvch = img & 15;
    const int tid = threadIdx.x;
    if (tid < 16) lc_s[tid] = lamcf[b * 256 + vvch * 16 + tid];
    {
        const USH* vb = vbuf + (size_t)img * 4 * NN;
        const int y0 = yt * 32 - 11, x0 = xh * 96 - 11;
        for (int idx = tid; idx < 4 * 54 * CSTR; idx += 256) {
            int u = idx / (54 * CSTR);
            int rem = idx - u * (54 * CSTR);
            int rr = rem / CSTR;
            int cc = rem - rr * CSTR;
            int gy = y0 + rr, gx = x0 + cc;
            USH val = 0;
            if (gy >= 0 && gy < HH && gx >= 0 && gx < HH) val = vb[u * NN + gy * HH + gx];
            in_s[idx] = val;
        }
    }
    __syncthreads();

    const int lane = tid & 63, wv = tid >> 6;
    const int wy = wv >> 1, wx = wv & 1;
    const int nl = lane & 15, quad = lane >> 4;
    const USH* sbase = in_s + (wy * 16 + nl) * CSTR + wx * 48 + quad * 8;
    const int ybase = yt * 32 + wy * 16 + nl;
    float lcr0 = lc_s[quad * 4], lcr1 = lc_s[quad * 4 + 1],
          lcr2 = lc_s[quad * 4 + 2], lcr3 = lc_s[quad * 4 + 3];
    const USH* qbase = qT + ((size_t)b * NN + ybase * HH) * 64 + quad * 4;
    USH* ybbase = yb + ((size_t)b * 64 + quad * 16 + vvch) * NN + ybase * HH;
    float SG = 0.f, QG = 0.f;

#define CONV_EPILOGUE(ACC, RVAL)                                                            \
    {                                                                                       \
        _Pragma("unroll")                                                                   \
        for (int xi = 0; xi < 6; ++xi) {                                                    \
            int x = xh * 96 + wx * 48 + (RVAL) + 8 * xi;                                    \
            float l0 = ACC[xi][0] + lcr0, l1 = ACC[xi][1] + lcr1;                           \
            float l2 = ACC[xi][2] + lcr2, l3 = ACC[xi][3] + lcr3;                           \
            const USH* qp = qbase + (size_t)x * 64;                                         \
            float s0, s1, s2, s3;                                                           \
            {                                                                               \
                ushort4 q4 = *(const ushort4*)(qp);                                         \
                s0 = bf2f(q4.x) * l0 + bf2f(q4.y) * l1 + bf2f(q4.z) * l2 + bf2f(q4.w) * l3; \
            }                                                                               \
            {                                                                               \
                ushort4 q4 = *(const ushort4*)(qp + 16);                                    \
                s1 = bf2f(q4.x) * l0 + bf2f(q4.y) * l1 + bf2f(q4.z) * l2 + bf2f(q4.w) * l3; \
            }                                                                               \
            {                                                                               \
                ushort4 q4 = *(const ushort4*)(qp + 32);                                    \
                s2 = bf2f(q4.x) * l0 + bf2f(q4.y) * l1 + bf2f(q4.z) * l2 + bf2f(q4.w) * l3; \
            }                                                                               \
            {                                                                               \
                ushort4 q4 = *(const ushort4*)(qp + 48);                                    \
                s3 = bf2f(q4.x) * l0 + bf2f(q4.y) * l1 + bf2f(q4.z) * l2 + bf2f(q4.w) * l3; \
            }                                                                               \
            s0 += __shfl_xor(s0, 16); s0 += __shfl_xor(s0, 32);                             \
            s1 += __shfl_xor(s1, 16); s1 += __shfl_xor(s1, 32);                             \
            s2 += __shfl_xor(s2, 16); s2 += __shfl_xor(s2, 32);                             \
            s3 += __shfl_xor(s3, 16); s3 += __shfl_xor(s3, 32);                             \
            float sel = (quad == 0) ? s0 : (quad == 1) ? s1 : (quad == 2) ? s2 : s3;        \
            USH wo = f2bf(sel);                                                             \
            ybbase[x] = wo;                                                                 \
            float wf = bf2f(wo);                                                            \
            SG += wf; QG += wf * wf;                                                        \
        }                                                                                   \
    }

#define CONV_PASS3(R0)                                                                      \
    {                                                                                       \
        f32x4 acc0[6] = {}; f32x4 acc1[6] = {}; f32x4 acc2[6] = {};                         \
        for (int u = 0; u < 4; ++u) {                                                       \
            const bf16x8* ap0 = apre + ((size_t)((R0) * 4 + u) * 23) * 64 + lane;           \
            const bf16x8* ap1 = ap0 + 4 * 23 * 64;                                          \
            const bf16x8* ap2 = ap0 + 2 * 4 * 23 * 64;                                      \
            const USH* srow = sbase + u * (54 * CSTR);                                      \
            _Pragma("unroll 2")                                                             \
            for (int dy = 0; dy < 23; ++dy) {                                               \
                bf16x8 a0 = *ap0, a1 = *ap1, a2 = *ap2;                                     \
                _Pragma("unroll")                                                           \
                for (int xi = 0; xi < 6; ++xi) {                                            \
                    bf16x8 bfr = *(const bf16x8*)(srow + 8 * xi);                           \
                    acc0[xi] = MFMA16(a0, bfr, acc0[xi]);                                   \
                    acc1[xi] = MFMA16(a1, bfr, acc1[xi]);                                   \
                    acc2[xi] = MFMA16(a2, bfr, acc2[xi]);                                   \
                }                                                                           \
                ap0 += 64; ap1 += 64; ap2 += 64; srow += CSTR;                               \
            }                                                                               \
        }                                                                                   \
        CONV_EPILOGUE(acc0, (R0))                                                           \
        CONV_EPILOGUE(acc1, (R0) + 1)                                                       \
        CONV_EPILOGUE(acc2, (R0) + 2)                                                       \
    }

    CONV_PASS3(0)
    CONV_PASS3(3)
    {   // last pass: r = 6,7
        f32x4 acc0[6] = {}; f32x4 acc1[6] = {};
        for (int u = 0; u < 4; ++u) {
            const bf16x8* ap0 = apre + ((size_t)(6 * 4 + u) * 23) * 64 + lane;
            const bf16x8* ap1 = ap0 + 4 * 23 * 64;
            const USH* srow = sbase + u * (54 * CSTR);
            #pragma unroll 2
            for (int dy = 0; dy < 23; ++dy) {
                bf16x8 a0 = *ap0, a1 = *ap1;
                #pragma unroll
                for (int xi = 0; xi < 6; ++xi) {
                    bf16x8 bfr = *(const bf16x8*)(srow + 8 * xi);
                    acc0[xi] = MFMA16(a0, bfr, acc0[xi]);
                    acc1[xi] = MFMA16(a1, bfr, acc1[xi]);
                }
                ap0 += 64; ap1 += 64; srow += CSTR;
            }
        }
        CONV_EPILOGUE(acc0, 6)
        CONV_EPILOGUE(acc1, 7)
    }
#undef CONV_PASS3
#undef CONV_EPILOGUE

    // GN partials: reduce Σ/Σ² over nl within each quad group (channel fixed)
    SG += __shfl_xor(SG, 1); SG += __shfl_xor(SG, 2); SG += __shfl_xor(SG, 4); SG += __shfl_xor(SG, 8);
    QG += __shfl_xor(QG, 1); QG += __shfl_xor(QG, 2); QG += __shfl_xor(QG, 4); QG += __shfl_xor(QG, 8);
    if (nl == 0) { gn_s[wv * 4 + quad] = SG; gn_q[wv * 4 + quad] = QG; }
    __syncthreads();
    if (tid < 4) {
        float s = gn_s[tid] + gn_s[4 + tid] + gn_s[8 + tid] + gn_s[12 + tid];
        float q = gn_q[tid] + gn_q[4 + tid] + gn_q[8 + tid] + gn_q[12 + tid];
        int lin = img * 12 + yt * 2 + xh;
        gnp2[lin * 8 + tid * 2]     = s;
        gnp2[lin * 8 + tid * 2 + 1] = q;
    }
}

// ---------------------------------------------------------------- GroupNorm stats from conv partials
// gnp2[((b*16+vvch)*12 + tile)*8 + quad*2 + {0,1}] ; group g: quad=g>>1, vvch in (g&1)*8..+8
__global__ void gn_passB_k(const float* __restrict__ gnp2, float* __restrict__ stats) {
    int t = threadIdx.x;
    if (t < 32) {
        int b = t >> 3, g = t & 7;
        int quad = g >> 1, v0 = (g & 1) * 8;
        float s = 0.f, q = 0.f;
        for (int vv = 0; vv < 8; ++vv)
            for (int tile = 0; tile < 12; ++tile) {
                const float* p = gnp2 + ((size_t)((b * 16 + v0 + vv) * 12 + tile)) * 8 + quad * 2;
                s += p[0]; q += p[1];
            }
        float mean = s / 294912.0f;
        float var = q / 294912.0f - mean * mean;
        stats[t * 2] = mean;
        stats[t * 2 + 1] = rsqrtf(fmaxf(var, 0.0f) + 1e-5f);
    }
}

// ---------------------------------------------------------------- FUSED GroupNorm-normalize + QKV GEMM (L->L+1)
// Per block (b, nt64): normalize 64n x 64c tile into LDS f32 ([64][65] pattern),
// pack B-frags with the same f2bf as the old XT path, then the 24-MFMA qkv body.
// R6: y-read vectorized ushort2 -> ushort4 (4 passes, c = p*16+(tid>>4),
// nn = (tid&15)*4; 16 lanes x 8B = 128B contiguous per quarter-wave).
__global__ __launch_bounds__(256) void gn_qkv_k(
    const USH* __restrict__ yb, const float* __restrict__ stats,
    const float* __restrict__ gg, const float* __restrict__ gb,
    const bf16x8* __restrict__ apre, const float* __restrict__ bias,
    USH* __restrict__ qT, USH* __restrict__ kbuf, USH* __restrict__ vbuf) {
    __shared__ float tf[64][65];
    __shared__ float sc[64], sb[64];
    const int bid = blockIdx.x; const int b = bid / 576; const int nt = bid - b * 576; const int n0 = nt * 64;
    const int tid = threadIdx.x, lane = tid & 63, wq = tid >> 6;
    const int nl = lane & 15, quad = lane >> 4;
    bf16x8 afr[24];
    #pragma unroll
    for (int i = 0; i < 24; ++i) afr[i] = apre[i * 64 + lane];
    if (tid < 64) {
        int g = tid >> 3;
        float mean = stats[(b * 8 + g) * 2], rstd = stats[(b * 8 + g) * 2 + 1];
        float ga = gg[tid];
        sc[tid] = rstd * ga;
        sb[tid] = gb[tid] - mean * rstd * ga;
    }
    __syncthreads();
    #pragma unroll
    for (int p = 0; p < 4; ++p) {
        int c = p * 16 + (tid >> 4), nn = (tid & 15) * 4;
        ushort4 y4 = *(const ushort4*)(yb + ((size_t)b * 64 + c) * NN + n0 + nn);
        float scc = sc[c], sbc = sb[c];
        tf[nn][c]     = bf2f(y4.x) * scc + sbc;
        tf[nn + 1][c] = bf2f(y4.y) * scc + sbc;
        tf[nn + 2][c] = bf2f(y4.z) * scc + sbc;
        tf[nn + 3][c] = bf2f(y4.w) * scc + sbc;
    }
    __syncthreads();
    bf16x8 b0, b1;
    #pragma unroll
    for (int j = 0; j < 8; ++j) {
        b0[j] = (short)f2bf(tf[wq * 16 + nl][quad * 8 + j]);
        b1[j] = (short)f2bf(tf[wq * 16 + nl][32 + quad * 8 + j]);
    }
    const int n = n0 + wq * 16 + nl;
    #pragma unroll
    for (int mt = 0; mt < 12; ++mt) {
        f32x4 acc = {0.f, 0.f, 0.f, 0.f};
        acc = MFMA16(afr[mt * 2 + 0], b0, acc);
        acc = MFMA16(afr[mt * 2 + 1], b1, acc);
        int o0 = mt * 16 + quad * 4;
        float4 bs = *(const float4*)(bias + o0);
        float v0 = acc[0] + bs.x, v1 = acc[1] + bs.y, v2 = acc[2] + bs.z, v3 = acc[3] + bs.w;
        if (mt < 4) {
            ushort4 pk; pk.x = f2bf(v0); pk.y = f2bf(v1); pk.z = f2bf(v2); pk.w = f2bf(v3);
            *(ushort4*)(qT + ((size_t)b * NN + n) * 64 + o0) = pk;
        } else if (mt < 8) {
            int ko = o0 - 64;
            kbuf[((size_t)b * 64 + ko    ) * NN + n] = f2bf(v0);
            kbuf[((size_t)b * 64 + ko + 1) * NN + n] = f2bf(v1);
            kbuf[((size_t)b * 64 + ko + 2) * NN + n] = f2bf(v2);
            kbuf[((size_t)b * 64 + ko + 3) * NN + n] = f2bf(v3);
        } else {
            int u = mt - 8, vv0 = quad * 4;
            vbuf[(((size_t)b * 16 + vv0    ) * 4 + u) * NN + n] = f2bf(v0);
            vbuf[(((size_t)b * 16 + vv0 + 1) * 4 + u) * NN + n] = f2bf(v1);
            vbuf[(((size_t)b * 16 + vv0 + 2) * 4 + u) * NN + n] = f2bf(v2);
            vbuf[(((size_t)b * 16 + vv0 + 3) * 4 + u) * NN + n] = f2bf(v3);
        }
    }
}

// ---------------------------------------------------------------- FUSED GroupNorm-normalize + final conv1x1 + *0.2 + x
__global__ __launch_bounds__(256) void gn_final_k(
    const USH* __restrict__ yb, const float* __restrict__ stats,
    const float* __restrict__ gg, const float* __restrict__ gb,
    const bf16x8* __restrict__ apre, const float* __restrict__ cb,
    const float* __restrict__ xin, float* __restrict__ out) {
    __shared__ float tf[64][65];
    __shared__ float sc[64], sb[64];
    const int bid = blockIdx.x; const int b = bid / 576; const int nt = bid - b * 576; const int n0 = nt * 64;
    const int tid = threadIdx.x, lane = tid & 63, wq = tid >> 6;
    const int nl = lane & 15, quad = lane >> 4;
    bf16x8 afr[8];
    #pragma unroll
    for (int i = 0; i < 8; ++i) afr[i] = apre[i * 64 + lane];
    if (tid < 64) {
        int g = tid >> 3;
        float mean = stats[(b * 8 + g) * 2], rstd = stats[(b * 8 + g) * 2 + 1];
        float ga = gg[tid];
        sc[tid] = rstd * ga;
        sb[tid] = gb[tid] - mean * rstd * ga;
    }
    __syncthreads();
    #pragma unroll
    for (int p = 0; p < 4; ++p) {
        int c = p * 16 + (tid >> 4), nn = (tid & 15) * 4;
        ushort4 y4 = *(const ushort4*)(yb + ((size_t)b * 64 + c) * NN + n0 + nn);
        float scc = sc[c], sbc = sb[c];
        tf[nn][c]     = bf2f(y4.x) * scc + sbc;
        tf[nn + 1][c] = bf2f(y4.y) * scc + sbc;
        tf[nn + 2][c] = bf2f(y4.z) * scc + sbc;
        tf[nn + 3][c] = bf2f(y4.w) * scc + sbc;
    }
    __syncthreads();
    bf16x8 b0, b1;
    #pragma unroll
    for (int j = 0; j < 8; ++j) {
        b0[j] = (short)f2bf(tf[wq * 16 + nl][quad * 8 + j]);
        b1[j] = (short)f2bf(tf[wq * 16 + nl][32 + quad * 8 + j]);
    }
    const int n = n0 + wq * 16 + nl;
    #pragma unroll
    for (int mt = 0; mt < 4; ++mt) {
        f32x4 acc = {0.f, 0.f, 0.f, 0.f};
        acc = MFMA16(afr[mt * 2 + 0], b0, acc);
        acc = MFMA16(afr[mt * 2 + 1], b1, acc);
        int o0 = mt * 16 + quad * 4;
        float4 cb4 = *(const float4*)(cb + o0);
        float cbv[4] = { cb4.x, cb4.y, cb4.z, cb4.w };
        #pragma unroll
        for (int rg = 0; rg < 4; ++rg) {
            int o = o0 + rg;
            float xv = xin[((size_t)b * 64 + o) * NN + n];
            out[((size_t)b * 64 + o) * NN + n] = (acc[rg] + cbv[rg]) * 0.2f + xv;
        }
    }
}

// ================================================================ host
extern "C" void kernel_launch(void* const* d_in, const int* in_sizes, int n_in,
                              void* d_out, int out_size, void* d_ws, size_t ws_size,
                              hipStream_t stream) {
    (void)in_sizes; (void)n_in; (void)out_size; (void)ws_size;
    const float* x = (const float*)d_in[0];
    char* ws = (char*)d_ws;

    // 4 bf16 planes, ping-pong aliasing (ybuf(L) = kbuf(L) plane; next-layer k
    // goes to the dead plane): L0 y=P2 -> k'=P0 ; L1 y=P0 -> k'=P2 ; L2 y=P2 -> out.
    const size_t SZP = (size_t)NTOT * 64 * 2;          // 18,874,368 B
    USH*   P0 = (USH*)(ws);                            // XT (L0 input), then k(L1)/y(L1)
    USH*   P1 = (USH*)(ws + SZP);                      // qT (all layers)
    USH*   P2 = (USH*)(ws + 2 * SZP);                  // k(L0)/y(L0), k(L2)/y(L2)
    USH*   P3 = (USH*)(ws + 3 * SZP);                  // v (all layers)
    char*  tail  = ws + 4 * SZP;
    USH*   apc   = (USH*)(tail);            tail += 753664 * 3;   // conv A-frags x3 layers
    USH*   apq   = (USH*)(tail);            tail += 24576 * 3;    // qkv A-frags x3
    float* biasq = (float*)(tail);          tail += 768 * 3;
    USH*   apf   = (USH*)(tail);            tail += 8192;         // final A-frags
    float* lcp   = (float*)(tail);          tail += 589824;       // lam_c partials
    float* lcf   = (float*)(tail);          tail += 4096;         // lam_c + pb, [b][vv][kk]
    float* gnp2  = (float*)(tail);          tail += 24576;        // GN partials from conv (6144 floats)
    float* gns   = (float*)(tail);                                // GN mean/rstd (256 B)

    PrepArgs pa;
    for (int L = 0; L < 3; ++L) {
        int base = 1 + L * 9;
        pa.wq[L] = (const float*)d_in[base + 0];
        pa.wk[L] = (const float*)d_in[base + 1];
        pa.wv[L] = (const float*)d_in[base + 2];
        pa.qg[L] = (const float*)d_in[base + 3];
        pa.qb[L] = (const float*)d_in[base + 4];
        pa.vg[L] = (const float*)d_in[base + 5];
        pa.vb[L] = (const float*)d_in[base + 6];
        pa.pw[L] = (const float*)d_in[base + 7];
    }
    pa.cw = (const float*)d_in[32];

    transpose64_k<<<2304, 256, 0, stream>>>(x, P0);
    prep_all_k<<<572, 256, 0, stream>>>(pa, apc, apq, biasq, apf);

    // L0 qkv from XT
    qkv_gemm_k<<<1152, 256, 0, stream>>>(P0, (const bf16x8*)apq, biasq, P1, P2, P3);

    for (int L = 0; L < 3; ++L) {
        const float* pb = (const float*)d_in[1 + L * 9 + 8];
        USH* kv = (L == 1) ? P0 : P2;          // kbuf == ybuf plane of this layer

        softmax_k<<<256, 1024, 0, stream>>>(kv);
        lamc_stage1_k<<<576, 64, 0, stream>>>(kv, P3, lcp);
        lamc_stage2_k<<<4, 256, 0, stream>>>(lcp, pb, lcf);
        dim3 cg(2, 6, 64);
        conv_pos_fused_k<<<cg, 256, 0, stream>>>(P3, (const bf16x8*)apc + (size_t)L * 47104,
                                                 P1, lcf, kv, gnp2);
        gn_passB_k<<<1, 256, 0, stream>>>(gnp2, gns);
        if (L < 2) {
            const float* gg = (const float*)d_in[28];
            const float* gb = (const float*)d_in[29];
            USH* knext = (L == 0) ? P0 : P2;
            gn_qkv_k<<<2304, 256, 0, stream>>>(kv, gns, gg, gb,
                                               (const bf16x8*)apq + (size_t)(L + 1) * 1536,
                                               biasq + (L + 1) * 192, P1, knext, P3);
        } else {
            const float* gg = (const float*)d_in[30];
            const float* gb = (const float*)d_in[31];
            gn_final_k<<<2304, 256, 0, stream>>>(kv, gns, gg, gb, (const bf16x8*)apf,
                                                 (const float*)d_in[33], x, (float*)d_out);
        }
    }
}

// Round 7
// 1006.831 us; speedup vs baseline: 1.5213x; 1.0038x over previous
//
#include <hip/hip_runtime.h>

typedef unsigned short USH;
typedef __attribute__((ext_vector_type(8))) short bf16x8;   // 8 bf16 = 4 VGPR
typedef __attribute__((ext_vector_type(4))) float f32x4;

#define MFMA16(a,b,c) __builtin_amdgcn_mfma_f32_16x16x32_bf16((a),(b),(c),0,0,0)

#define BB 4
#define HH 192
#define NN 36864            // 192*192
#define NTOT 147456         // 4*NN
#define CSTR 120            // conv LDS row stride (USH); 118 needed, 120 keeps 16B align, 51.9KB -> 3 blocks/CU

__device__ __forceinline__ float bf2f(USH h) {
    union { unsigned int u; float f; } v; v.u = ((unsigned int)h) << 16; return v.f;
}
__device__ __forceinline__ USH f2bf(float f) {
    union { float f; unsigned int u; } v; v.f = f;
    unsigned int u = v.u;
    return (USH)((u + 0x7FFFu + ((u >> 16) & 1u)) >> 16);
}

// ---------------------------------------------------------------- ALL weight prep in ONE dispatch
struct PrepArgs {
    const float* wq[3]; const float* wk[3]; const float* wv[3];
    const float* qg[3]; const float* qb[3]; const float* vg[3]; const float* vb[3];
    const float* pw[3]; const float* cw;
};
__global__ void prep_all_k(PrepArgs pa, USH* __restrict__ apc, USH* __restrict__ apq,
                           float* __restrict__ biasq, USH* __restrict__ apf) {
    int bid = blockIdx.x, tid = threadIdx.x;
    if (bid < 552) {
        // conv A-frags: chunk cg=(r*4+u)*23+dy ; slot k=(lane>>4)*8+j -> dx=k-r ; kk=lane&15
        int L = bid / 184, cb = bid - L * 184;
        int t = cb * 256 + tid;
        if (t < 736 * 64) {
            const float* pw = pa.pw[L];
            USH* ap = apc + (size_t)L * 376832;       // 736*64*8 USH per layer
            int lane = t & 63, cg = t >> 6;
            int dy = cg % 23; int ru = cg / 23; int u = ru & 3; int r = ru >> 2;
            int kk = lane & 15, q8 = (lane >> 4) * 8;
            for (int j = 0; j < 8; ++j) {
                int k = q8 + j, dx = k - r;
                USH w = 0;
                if (dx >= 0 && dx < 23) w = f2bf(pw[((kk * 4 + u) * 23 + dy) * 23 + dx]);
                ap[t * 8 + j] = w;
            }
        }
    } else if (bid < 570) {
        // qkv A-frags: o = mt*16+(lane&15), c = kc*32+(lane>>4)*8+j
        int idx = bid - 552; int L = idx / 6; int qblk = idx - L * 6;
        int t = qblk * 256 + tid;
        USH* apl = apq + (size_t)L * 12288;
        float* bl = biasq + L * 192;
        if (t < 1536) {
            int lane = t & 63, chunk = t >> 6;
            int mt = chunk >> 1, kc = chunk & 1;
            int o = mt * 16 + (lane & 15);
            int c0 = kc * 32 + (lane >> 4) * 8;
            float scale; const float* wrow;
            if (o < 64)       { scale = pa.qg[L][o]       * rsqrtf(1.0f + 1e-5f); wrow = pa.wq[L] + o * 64; }
            else if (o < 128) { scale = 1.0f;                                     wrow = pa.wk[L] + (o - 64) * 64; }
            else              { scale = pa.vg[L][o - 128] * rsqrtf(1.0f + 1e-5f); wrow = pa.wv[L] + (o - 128) * 64; }
            for (int j = 0; j < 8; ++j) apl[t * 8 + j] = f2bf(wrow[c0 + j] * scale);
        }
        if (t < 192) {
            float bvv;
            if (t < 64) bvv = pa.qb[L][t]; else if (t < 128) bvv = 0.0f; else bvv = pa.vb[L][t - 128];
            bl[t] = bvv;
        }
    } else {
        int t = (bid - 570) * 256 + tid;
        if (t < 512) {
            int lane = t & 63, chunk = t >> 6;
            int mt = chunk >> 1, kc = chunk & 1;
            int o = mt * 16 + (lane & 15);
            int c0 = kc * 32 + (lane >> 4) * 8;
            for (int j = 0; j < 8; ++j) apf[t * 8 + j] = f2bf(pa.cw[o * 64 + c0 + j]);
        }
    }
}

// ---------------------------------------------------------------- FUSED transpose + QKV GEMM (L0)
// R7: replaces transpose64_k + qkv_gemm_k. Reads fp32 x tile (64c x 64n) into
// the conflict-free [64][65] LDS transpose pattern, packs B-frags with the
// same f2bf as the old XT path (bit-identical), runs the 24-MFMA qkv body.
// Removes the 37.8MB XT write+read round trip and one dispatch.
__global__ __launch_bounds__(256) void x_qkv_k(
    const float* __restrict__ xin, const bf16x8* __restrict__ apre, const float* __restrict__ bias,
    USH* __restrict__ qT, USH* __restrict__ kbuf, USH* __restrict__ vbuf) {
    __shared__ float tf[64][65];
    const int bid = blockIdx.x; const int b = bid / 576; const int nt = bid - b * 576; const int n0 = nt * 64;
    const int tid = threadIdx.x, lane = tid & 63, wq = tid >> 6;
    const int nl = lane & 15, quad = lane >> 4;
    bf16x8 afr[24];
    #pragma unroll
    for (int i = 0; i < 24; ++i) afr[i] = apre[i * 64 + lane];
    #pragma unroll
    for (int p = 0; p < 16; ++p) {
        int idx = p * 256 + tid; int c = idx >> 6, nn = idx & 63;
        tf[nn][c] = xin[((size_t)b * 64 + c) * NN + n0 + nn];
    }
    __syncthreads();
    bf16x8 b0, b1;
    #pragma unroll
    for (int j = 0; j < 8; ++j) {
        b0[j] = (short)f2bf(tf[wq * 16 + nl][quad * 8 + j]);
        b1[j] = (short)f2bf(tf[wq * 16 + nl][32 + quad * 8 + j]);
    }
    const int n = n0 + wq * 16 + nl;
    #pragma unroll
    for (int mt = 0; mt < 12; ++mt) {
        f32x4 acc = {0.f, 0.f, 0.f, 0.f};
        acc = MFMA16(afr[mt * 2 + 0], b0, acc);
        acc = MFMA16(afr[mt * 2 + 1], b1, acc);
        int o0 = mt * 16 + quad * 4;
        float4 bs = *(const float4*)(bias + o0);
        float v0 = acc[0] + bs.x, v1 = acc[1] + bs.y, v2 = acc[2] + bs.z, v3 = acc[3] + bs.w;
        if (mt < 4) {                       // q -> qT[b][n][o] (o = h*16+kk)
            ushort4 pk; pk.x = f2bf(v0); pk.y = f2bf(v1); pk.z = f2bf(v2); pk.w = f2bf(v3);
            *(ushort4*)(qT + ((size_t)b * NN + n) * 64 + o0) = pk;
        } else if (mt < 8) {                // k raw -> kbuf[b][u*16+kk][n]
            int ko = o0 - 64;
            kbuf[((size_t)b * 64 + ko    ) * NN + n] = f2bf(v0);
            kbuf[((size_t)b * 64 + ko + 1) * NN + n] = f2bf(v1);
            kbuf[((size_t)b * 64 + ko + 2) * NN + n] = f2bf(v2);
            kbuf[((size_t)b * 64 + ko + 3) * NN + n] = f2bf(v3);
        } else {                            // v -> vbuf[(b*16+vv)*4+u][n]
            int u = mt - 8, vv0 = quad * 4;
            vbuf[(((size_t)b * 16 + vv0    ) * 4 + u) * NN + n] = f2bf(v0);
            vbuf[(((size_t)b * 16 + vv0 + 1) * 4 + u) * NN + n] = f2bf(v1);
            vbuf[(((size_t)b * 16 + vv0 + 2) * 4 + u) * NN + n] = f2bf(v2);
            vbuf[(((size_t)b * 16 + vv0 + 3) * 4 + u) * NN + n] = f2bf(v3);
        }
    }
}

// ---------------------------------------------------------------- softmax over n, in-place, 1 block/row (LDS row cache)
__global__ __launch_bounds__(1024) void softmax_k(USH* __restrict__ kbuf) {
    __shared__ USH row_s[NN];                  // 73,728 B
    __shared__ float red[64];
    USH* p = kbuf + (size_t)blockIdx.x * NN;
    int tid = threadIdx.x, lane = tid & 63, w = tid >> 6;
    float m = -1e30f;
    for (int i = tid * 4; i < NN; i += 4096) {
        ushort4 t4 = *(const ushort4*)(p + i);
        *(ushort4*)(row_s + i) = t4;
        m = fmaxf(m, fmaxf(fmaxf(bf2f(t4.x), bf2f(t4.y)), fmaxf(bf2f(t4.z), bf2f(t4.w))));
    }
    for (int off = 32; off; off >>= 1) m = fmaxf(m, __shfl_down(m, off));
    if (lane == 0) red[w] = m;
    __syncthreads();
    if (tid == 0) { float mm = red[0]; for (int i = 1; i < 16; ++i) mm = fmaxf(mm, red[i]); red[16] = mm; }
    __syncthreads();
    float M = red[16];
    float s = 0.f;
    for (int i = tid * 4; i < NN; i += 4096) {
        ushort4 t4 = *(const ushort4*)(row_s + i);
        s += __expf(bf2f(t4.x) - M) + __expf(bf2f(t4.y) - M)
           + __expf(bf2f(t4.z) - M) + __expf(bf2f(t4.w) - M);
    }
    for (int off = 32; off; off >>= 1) s += __shfl_down(s, off);
    if (lane == 0) red[32 + w] = s;
    __syncthreads();
    if (tid == 0) { float ss = 0.f; for (int i = 0; i < 16; ++i) ss += red[32 + i]; red[17] = 1.0f / ss; }
    __syncthreads();
    float inv = red[17];
    for (int i = tid * 4; i < NN; i += 4096) {
        ushort4 t4 = *(const ushort4*)(row_s + i);
        ushort4 o4;
        o4.x = f2bf(__expf(bf2f(t4.x) - M) * inv);
        o4.y = f2bf(__expf(bf2f(t4.y) - M) * inv);
        o4.z = f2bf(__expf(bf2f(t4.z) - M) * inv);
        o4.w = f2bf(__expf(bf2f(t4.w) - M) * inv);
        *(ushort4*)(p + i) = o4;
    }
}

// ---------------------------------------------------------------- lam_c split-K stage 1 -- MFMA (R6)
__global__ __launch_bounds__(64) void lamc_stage1_k(
    const USH* __restrict__ kbuf, const USH* __restrict__ vbuf,
    float* __restrict__ part) {
    int bid = blockIdx.x;                  // (cidx 0..35)*16 + b*4 + u
    int cidx = bid / 16; int rem = bid - cidx * 16; int b = rem >> 2; int u = rem & 3;
    int lane = threadIdx.x; int nl = lane & 15, quad = lane >> 4;
    const USH* kp = kbuf + ((size_t)b * 64 + u * 16 + nl) * NN + cidx * 1024 + quad * 8;
    const USH* vp = vbuf + (((size_t)b * 16 + nl) * 4 + u) * NN + cidx * 1024 + quad * 8;
    f32x4 acc = {0.f, 0.f, 0.f, 0.f};
    #pragma unroll 4
    for (int s = 0; s < 32; ++s) {
        bf16x8 ka = *(const bf16x8*)(kp + s * 32);
        bf16x8 va = *(const bf16x8*)(vp + s * 32);
        acc = MFMA16(ka, va, acc);
    }
    float* pout = part + ((size_t)(cidx * 4 + b) * 4 + u) * 256;
    #pragma unroll
    for (int rg = 0; rg < 4; ++rg)
        pout[nl * 16 + quad * 4 + rg] = acc[rg];
}
__global__ void lamc_stage2_k(const float* __restrict__ part, const float* __restrict__ pb,
                              float* __restrict__ lamcf) {
    int b = blockIdx.x, tid = threadIdx.x;   // tid = vv*16+kk
    float acc = 0.f;
    for (int c = 0; c < 36; ++c)
        for (int u = 0; u < 4; ++u)
            acc += part[((size_t)(c * 4 + b) * 4 + u) * 256 + tid];
    lamcf[b * 256 + tid] = acc + pb[tid & 15];   // fold conv bias pb[kk]
}

// ---------------------------------------------------------------- position conv 23x23 (MFMA implicit GEMM)
// + FUSED y-epilogue + FUSED GroupNorm partial sums. Proven R2 config.
// R7: s_setprio(1) wrapped around the MFMA-dense u/dy loops (T5): conv waves
// are barrier-free in the main loop and phase-desynchronized across blocks
// (the wave-role-diversity regime where setprio measured +4-7%; null only in
// lockstep-barrier GEMMs). Epilogues/staging run at prio 0.
__global__ __launch_bounds__(256, 3) void conv_pos_fused_k(
    const USH* __restrict__ vbuf, const bf16x8* __restrict__ apre,
    const USH* __restrict__ qT, const float* __restrict__ lamcf,
    USH* __restrict__ yb, float* __restrict__ gnp2) {
    __shared__ __align__(16) USH in_s[4 * 54 * CSTR];     // 51,840 B
    __shared__ float lc_s[16];
    __shared__ float gn_s[16], gn_q[16];
    const int xh = blockIdx.x, yt = blockIdx.y, img = blockIdx.z;
    const int b = img >> 4, vvch = img & 15;
    const int tid = threadIdx.x;
    if (tid < 16) lc_s[tid] = lamcf[b * 256 + vvch * 16 + tid];
    {
        const USH* vb = vbuf + (size_t)img * 4 * NN;
        const int y0 = yt * 32 - 11, x0 = xh * 96 - 11;
        for (int idx = tid; idx < 4 * 54 * CSTR; idx += 256) {
            int u = idx / (54 * CSTR);
            int rem = idx - u * (54 * CSTR);
            int rr = rem / CSTR;
            int cc = rem - rr * CSTR;
            int gy = y0 + rr, gx = x0 + cc;
            USH val = 0;
            if (gy >= 0 && gy < HH && gx >= 0 && gx < HH) val = vb[u * NN + gy * HH + gx];
            in_s[idx] = val;
        }
    }
    __syncthreads();

    const int lane = tid & 63, wv = tid >> 6;
    const int wy = wv >> 1, wx = wv & 1;
    const int nl = lane & 15, quad = lane >> 4;
    const USH* sbase = in_s + (wy * 16 + nl) * CSTR + wx * 48 + quad * 8;
    const int ybase = yt * 32 + wy * 16 + nl;
    float lcr0 = lc_s[quad * 4], lcr1 = lc_s[quad * 4 + 1],
          lcr2 = lc_s[quad * 4 + 2], lcr3 = lc_s[quad * 4 + 3];
    const USH* qbase = qT + ((size_t)b * NN + ybase * HH) * 64 + quad * 4;
    USH* ybbase = yb + ((size_t)b * 64 + quad * 16 + vvch) * NN + ybase * HH;
    float SG = 0.f, QG = 0.f;

#define CONV_EPILOGUE(ACC, RVAL)                                                            \
    {                                                                                       \
        _Pragma("unroll")                                                                   \
        for (int xi = 0; xi < 6; ++xi) {                                                    \
            int x = xh * 96 + wx * 48 + (RVAL) + 8 * xi;                                    \
            float l0 = ACC[xi][0] + lcr0, l1 = ACC[xi][1] + lcr1;                           \
            float l2 = ACC[xi][2] + lcr2, l3 = ACC[xi][3] + lcr3;                           \
            const USH* qp = qbase + (size_t)x * 64;                                         \
            float s0, s1, s2, s3;                                                           \
            {                                                                               \
                ushort4 q4 = *(const ushort4*)(qp);                                         \
                s0 = bf2f(q4.x) * l0 + bf2f(q4.y) * l1 + bf2f(q4.z) * l2 + bf2f(q4.w) * l3; \
            }                                                                               \
            {                                                                               \
                ushort4 q4 = *(const ushort4*)(qp + 16);                                    \
                s1 = bf2f(q4.x) * l0 + bf2f(q4.y) * l1 + bf2f(q4.z) * l2 + bf2f(q4.w) * l3; \
            }                                                                               \
            {                                                                               \
                ushort4 q4 = *(const ushort4*)(qp + 32);                                    \
                s2 = bf2f(q4.x) * l0 + bf2f(q4.y) * l1 + bf2f(q4.z) * l2 + bf2f(q4.w) * l3; \
            }                                                                               \
            {                                                                               \
                ushort4 q4 = *(const ushort4*)(qp + 48);                                    \
                s3 = bf2f(q4.x) * l0 + bf2f(q4.y) * l1 + bf2f(q4.z) * l2 + bf2f(q4.w) * l3; \
            }                                                                               \
            s0 += __shfl_xor(s0, 16); s0 += __shfl_xor(s0, 32);                             \
            s1 += __shfl_xor(s1, 16); s1 += __shfl_xor(s1, 32);                             \
            s2 += __shfl_xor(s2, 16); s2 += __shfl_xor(s2, 32);                             \
            s3 += __shfl_xor(s3, 16); s3 += __shfl_xor(s3, 32);                             \
            float sel = (quad == 0) ? s0 : (quad == 1) ? s1 : (quad == 2) ? s2 : s3;        \
            USH wo = f2bf(sel);                                                             \
            ybbase[x] = wo;                                                                 \
            float wf = bf2f(wo);                                                            \
            SG += wf; QG += wf * wf;                                                        \
        }                                                                                   \
    }

#define CONV_PASS3(R0)                                                                      \
    {                                                                                       \
        f32x4 acc0[6] = {}; f32x4 acc1[6] = {}; f32x4 acc2[6] = {};                         \
        __builtin_amdgcn_s_setprio(1);                                                      \
        for (int u = 0; u < 4; ++u) {                                                       \
            const bf16x8* ap0 = apre + ((size_t)((R0) * 4 + u) * 23) * 64 + lane;           \
            const bf16x8* ap1 = ap0 + 4 * 23 * 64;                                          \
            const bf16x8* ap2 = ap0 + 2 * 4 * 23 * 64;                                      \
            const USH* srow = sbase + u * (54 * CSTR);                                      \
            _Pragma("unroll 2")                                                             \
            for (int dy = 0; dy < 23; ++dy) {                                               \
                bf16x8 a0 = *ap0, a1 = *ap1, a2 = *ap2;                                     \
                _Pragma("unroll")                                                           \
                for (int xi = 0; xi < 6; ++xi) {                                            \
                    bf16x8 bfr = *(const bf16x8*)(srow + 8 * xi);                           \
                    acc0[xi] = MFMA16(a0, bfr, acc0[xi]);                                   \
                    acc1[xi] = MFMA16(a1, bfr, acc1[xi]);                                   \
                    acc2[xi] = MFMA16(a2, bfr, acc2[xi]);                                   \
                }                                                                           \
                ap0 += 64; ap1 += 64; ap2 += 64; srow += CSTR;                               \
            }                                                                               \
        }                                                                                   \
        __builtin_amdgcn_s_setprio(0);                                                      \
        CONV_EPILOGUE(acc0, (R0))                                                           \
        CONV_EPILOGUE(acc1, (R0) + 1)                                                       \
        CONV_EPILOGUE(acc2, (R0) + 2)                                                       \
    }

    CONV_PASS3(0)
    CONV_PASS3(3)
    {   // last pass: r = 6,7
        f32x4 acc0[6] = {}; f32x4 acc1[6] = {};
        __builtin_amdgcn_s_setprio(1);
        for (int u = 0; u < 4; ++u) {
            const bf16x8* ap0 = apre + ((size_t)(6 * 4 + u) * 23) * 64 + lane;
            const bf16x8* ap1 = ap0 + 4 * 23 * 64;
            const USH* srow = sbase + u * (54 * CSTR);
            #pragma unroll 2
            for (int dy = 0; dy < 23; ++dy) {
                bf16x8 a0 = *ap0, a1 = *ap1;
                #pragma unroll
                for (int xi = 0; xi < 6; ++xi) {
                    bf16x8 bfr = *(const bf16x8*)(srow + 8 * xi);
                    acc0[xi] = MFMA16(a0, bfr, acc0[xi]);
                    acc1[xi] = MFMA16(a1, bfr, acc1[xi]);
                }
                ap0 += 64; ap1 += 64; srow += CSTR;
            }
        }
        __builtin_amdgcn_s_setprio(0);
        CONV_EPILOGUE(acc0, 6)
        CONV_EPILOGUE(acc1, 7)
    }
#undef CONV_PASS3
#undef CONV_EPILOGUE

    // GN partials: reduce Σ/Σ² over nl within each quad group (channel fixed)
    SG += __shfl_xor(SG, 1); SG += __shfl_xor(SG, 2); SG += __shfl_xor(SG, 4); SG += __shfl_xor(SG, 8);
    QG += __shfl_xor(QG, 1); QG += __shfl_xor(QG, 2); QG += __shfl_xor(QG, 4); QG += __shfl_xor(QG, 8);
    if (nl == 0) { gn_s[wv * 4 + quad] = SG; gn_q[wv * 4 + quad] = QG; }
    __syncthreads();
    if (tid < 4) {
        float s = gn_s[tid] + gn_s[4 + tid] + gn_s[8 + tid] + gn_s[12 + tid];
        float q = gn_q[tid] + gn_q[4 + tid] + gn_q[8 + tid] + gn_q[12 + tid];
        int lin = img * 12 + yt * 2 + xh;
        gnp2[lin * 8 + tid * 2]     = s;
        gnp2[lin * 8 + tid * 2 + 1] = q;
    }
}

// ---------------------------------------------------------------- GroupNorm stats from conv partials
__global__ void gn_passB_k(const float* __restrict__ gnp2, float* __restrict__ stats) {
    int t = threadIdx.x;
    if (t < 32) {
        int b = t >> 3, g = t & 7;
        int quad = g >> 1, v0 = (g & 1) * 8;
        float s = 0.f, q = 0.f;
        for (int vv = 0; vv < 8; ++vv)
            for (int tile = 0; tile < 12; ++tile) {
                const float* p = gnp2 + ((size_t)((b * 16 + v0 + vv) * 12 + tile)) * 8 + quad * 2;
                s += p[0]; q += p[1];
            }
        float mean = s / 294912.0f;
        float var = q / 294912.0f - mean * mean;
        stats[t * 2] = mean;
        stats[t * 2 + 1] = rsqrtf(fmaxf(var, 0.0f) + 1e-5f);
    }
}

// ---------------------------------------------------------------- FUSED GroupNorm-normalize + QKV GEMM (L->L+1)
__global__ __launch_bounds__(256) void gn_qkv_k(
    const USH* __restrict__ yb, const float* __restrict__ stats,
    const float* __restrict__ gg, const float* __restrict__ gb,
    const bf16x8* __restrict__ apre, const float* __restrict__ bias,
    USH* __restrict__ qT, USH* __restrict__ kbuf, USH* __restrict__ vbuf) {
    __shared__ float tf[64][65];
    __shared__ float sc[64], sb[64];
    const int bid = blockIdx.x; const int b = bid / 576; const int nt = bid - b * 576; const int n0 = nt * 64;
    const int tid = threadIdx.x, lane = tid & 63, wq = tid >> 6;
    const int nl = lane & 15, quad = lane >> 4;
    bf16x8 afr[24];
    #pragma unroll
    for (int i = 0; i < 24; ++i) afr[i] = apre[i * 64 + lane];
    if (tid < 64) {
        int g = tid >> 3;
        float mean = stats[(b * 8 + g) * 2], rstd = stats[(b * 8 + g) * 2 + 1];
        float ga = gg[tid];
        sc[tid] = rstd * ga;
        sb[tid] = gb[tid] - mean * rstd * ga;
    }
    __syncthreads();
    #pragma unroll
    for (int p = 0; p < 4; ++p) {
        int c = p * 16 + (tid >> 4), nn = (tid & 15) * 4;
        ushort4 y4 = *(const ushort4*)(yb + ((size_t)b * 64 + c) * NN + n0 + nn);
        float scc = sc[c], sbc = sb[c];
        tf[nn][c]     = bf2f(y4.x) * scc + sbc;
        tf[nn + 1][c] = bf2f(y4.y) * scc + sbc;
        tf[nn + 2][c] = bf2f(y4.z) * scc + sbc;
        tf[nn + 3][c] = bf2f(y4.w) * scc + sbc;
    }
    __syncthreads();
    bf16x8 b0, b1;
    #pragma unroll
    for (int j = 0; j < 8; ++j) {
        b0[j] = (short)f2bf(tf[wq * 16 + nl][quad * 8 + j]);
        b1[j] = (short)f2bf(tf[wq * 16 + nl][32 + quad * 8 + j]);
    }
    const int n = n0 + wq * 16 + nl;
    #pragma unroll
    for (int mt = 0; mt < 12; ++mt) {
        f32x4 acc = {0.f, 0.f, 0.f, 0.f};
        acc = MFMA16(afr[mt * 2 + 0], b0, acc);
        acc = MFMA16(afr[mt * 2 + 1], b1, acc);
        int o0 = mt * 16 + quad * 4;
        float4 bs = *(const float4*)(bias + o0);
        float v0 = acc[0] + bs.x, v1 = acc[1] + bs.y, v2 = acc[2] + bs.z, v3 = acc[3] + bs.w;
        if (mt < 4) {
            ushort4 pk; pk.x = f2bf(v0); pk.y = f2bf(v1); pk.z = f2bf(v2); pk.w = f2bf(v3);
            *(ushort4*)(qT + ((size_t)b * NN + n) * 64 + o0) = pk;
        } else if (mt < 8) {
            int ko = o0 - 64;
            kbuf[((size_t)b * 64 + ko    ) * NN + n] = f2bf(v0);
            kbuf[((size_t)b * 64 + ko + 1) * NN + n] = f2bf(v1);
            kbuf[((size_t)b * 64 + ko + 2) * NN + n] = f2bf(v2);
            kbuf[((size_t)b * 64 + ko + 3) * NN + n] = f2bf(v3);
        } else {
            int u = mt - 8, vv0 = quad * 4;
            vbuf[(((size_t)b * 16 + vv0    ) * 4 + u) * NN + n] = f2bf(v0);
            vbuf[(((size_t)b * 16 + vv0 + 1) * 4 + u) * NN + n] = f2bf(v1);
            vbuf[(((size_t)b * 16 + vv0 + 2) * 4 + u) * NN + n] = f2bf(v2);
            vbuf[(((size_t)b * 16 + vv0 + 3) * 4 + u) * NN + n] = f2bf(v3);
        }
    }
}

// ---------------------------------------------------------------- FUSED GroupNorm-normalize + final conv1x1 + *0.2 + x
__global__ __launch_bounds__(256) void gn_final_k(
    const USH* __restrict__ yb, const float* __restrict__ stats,
    const float* __restrict__ gg, const float* __restrict__ gb,
    const bf16x8* __restrict__ apre, const float* __restrict__ cb,
    const float* __restrict__ xin, float* __restrict__ out) {
    __shared__ float tf[64][65];
    __shared__ float sc[64], sb[64];
    const int bid = blockIdx.x; const int b = bid / 576; const int nt = bid - b * 576; const int n0 = nt * 64;
    const int tid = threadIdx.x, lane = tid & 63, wq = tid >> 6;
    const int nl = lane & 15, quad = lane >> 4;
    bf16x8 afr[8];
    #pragma unroll
    for (int i = 0; i < 8; ++i) afr[i] = apre[i * 64 + lane];
    if (tid < 64) {
        int g = tid >> 3;
        float mean = stats[(b * 8 + g) * 2], rstd = stats[(b * 8 + g) * 2 + 1];
        float ga = gg[tid];
        sc[tid] = rstd * ga;
        sb[tid] = gb[tid] - mean * rstd * ga;
    }
    __syncthreads();
    #pragma unroll
    for (int p = 0; p < 4; ++p) {
        int c = p * 16 + (tid >> 4), nn = (tid & 15) * 4;
        ushort4 y4 = *(const ushort4*)(yb + ((size_t)b * 64 + c) * NN + n0 + nn);
        float scc = sc[c], sbc = sb[c];
        tf[nn][c]     = bf2f(y4.x) * scc + sbc;
        tf[nn + 1][c] = bf2f(y4.y) * scc + sbc;
        tf[nn + 2][c] = bf2f(y4.z) * scc + sbc;
        tf[nn + 3][c] = bf2f(y4.w) * scc + sbc;
    }
    __syncthreads();
    bf16x8 b0, b1;
    #pragma unroll
    for (int j = 0; j < 8; ++j) {
        b0[j] = (short)f2bf(tf[wq * 16 + nl][quad * 8 + j]);
        b1[j] = (short)f2bf(tf[wq * 16 + nl][32 + quad * 8 + j]);
    }
    const int n = n0 + wq * 16 + nl;
    #pragma unroll
    for (int mt = 0; mt < 4; ++mt) {
        f32x4 acc = {0.f, 0.f, 0.f, 0.f};
        acc = MFMA16(afr[mt * 2 + 0], b0, acc);
        acc = MFMA16(afr[mt * 2 + 1], b1, acc);
        int o0 = mt * 16 + quad * 4;
        float4 cb4 = *(const float4*)(cb + o0);
        float cbv[4] = { cb4.x, cb4.y, cb4.z, cb4.w };
        #pragma unroll
        for (int rg = 0; rg < 4; ++rg) {
            int o = o0 + rg;
            float xv = xin[((size_t)b * 64 + o) * NN + n];
            out[((size_t)b * 64 + o) * NN + n] = (acc[rg] + cbv[rg]) * 0.2f + xv;
        }
    }
}

// ================================================================ host
extern "C" void kernel_launch(void* const* d_in, const int* in_sizes, int n_in,
                              void* d_out, int out_size, void* d_ws, size_t ws_size,
                              hipStream_t stream) {
    (void)in_sizes; (void)n_in; (void)out_size; (void)ws_size;
    const float* x = (const float*)d_in[0];
    char* ws = (char*)d_ws;

    // 4 bf16 planes, ping-pong aliasing (ybuf(L) = kbuf(L) plane; next-layer k
    // goes to the dead plane): L0 y=P2 -> k'=P0 ; L1 y=P0 -> k'=P2 ; L2 y=P2 -> out.
    const size_t SZP = (size_t)NTOT * 64 * 2;          // 18,874,368 B
    USH*   P0 = (USH*)(ws);                            // k(L1)/y(L1)
    USH*   P1 = (USH*)(ws + SZP);                      // qT (all layers)
    USH*   P2 = (USH*)(ws + 2 * SZP);                  // k(L0)/y(L0), k(L2)/y(L2)
    USH*   P3 = (USH*)(ws + 3 * SZP);                  // v (all layers)
    char*  tail  = ws + 4 * SZP;
    USH*   apc   = (USH*)(tail);            tail += 753664 * 3;   // conv A-frags x3 layers
    USH*   apq   = (USH*)(tail);            tail += 24576 * 3;    // qkv A-frags x3
    float* biasq = (float*)(tail);          tail += 768 * 3;
    USH*   apf   = (USH*)(tail);            tail += 8192;         // final A-frags
    float* lcp   = (float*)(tail);          tail += 589824;       // lam_c partials
    float* lcf   = (float*)(tail);          tail += 4096;         // lam_c + pb, [b][vv][kk]
    float* gnp2  = (float*)(tail);          tail += 24576;        // GN partials from conv (6144 floats)
    float* gns   = (float*)(tail);                                // GN mean/rstd (256 B)

    PrepArgs pa;
    for (int L = 0; L < 3; ++L) {
        int base = 1 + L * 9;
        pa.wq[L] = (const float*)d_in[base + 0];
        pa.wk[L] = (const float*)d_in[base + 1];
        pa.wv[L] = (const float*)d_in[base + 2];
        pa.qg[L] = (const float*)d_in[base + 3];
        pa.qb[L] = (const float*)d_in[base + 4];
        pa.vg[L] = (const float*)d_in[base + 5];
        pa.vb[L] = (const float*)d_in[base + 6];
        pa.pw[L] = (const float*)d_in[base + 7];
    }
    pa.cw = (const float*)d_in[32];

    prep_all_k<<<572, 256, 0, stream>>>(pa, apc, apq, biasq, apf);

    // L0 qkv directly from fp32 x (fused transpose)
    x_qkv_k<<<2304, 256, 0, stream>>>(x, (const bf16x8*)apq, biasq, P1, P2, P3);

    for (int L = 0; L < 3; ++L) {
        const float* pb = (const float*)d_in[1 + L * 9 + 8];
        USH* kv = (L == 1) ? P0 : P2;          // kbuf == ybuf plane of this layer

        softmax_k<<<256, 1024, 0, stream>>>(kv);
        lamc_stage1_k<<<576, 64, 0, stream>>>(kv, P3, lcp);
        lamc_stage2_k<<<4, 256, 0, stream>>>(lcp, pb, lcf);
        dim3 cg(2, 6, 64);
        conv_pos_fused_k<<<cg, 256, 0, stream>>>(P3, (const bf16x8*)apc + (size_t)L * 47104,
                                                 P1, lcf, kv, gnp2);
        gn_passB_k<<<1, 256, 0, stream>>>(gnp2, gns);
        if (L < 2) {
            const float* gg = (const float*)d_in[28];
            const float* gb = (const float*)d_in[29];
            USH* knext = (L == 0) ? P0 : P2;
            gn_qkv_k<<<2304, 256, 0, stream>>>(kv, gns, gg, gb,
                                               (const bf16x8*)apq + (size_t)(L + 1) * 1536,
                                               biasq + (L + 1) * 192, P1, knext, P3);
        } else {
            const float* gg = (const float*)d_in[30];
            const float* gb = (const float*)d_in[31];
            gn_final_k<<<2304, 256, 0, stream>>>(kv, gns, gg, gb, (const bf16x8*)apf,
                                                 (const float*)d_in[33], x, (float*)d_out);
        }
    }
}

// Round 8
// 942.069 us; speedup vs baseline: 1.6258x; 1.0687x over previous
//
#include <hip/hip_runtime.h>

typedef unsigned short USH;
typedef __attribute__((ext_vector_type(8))) short bf16x8;   // 8 bf16 = 4 VGPR
typedef __attribute__((ext_vector_type(4))) float f32x4;

#define MFMA16(a,b,c) __builtin_amdgcn_mfma_f32_16x16x32_bf16((a),(b),(c),0,0,0)

#define BB 4
#define HH 192
#define NN 36864            // 192*192
#define NTOT 147456         // 4*NN
#define CSTR 120            // conv LDS row stride (USH); 119 needed, 120 keeps 16B align, 51.9KB -> 3 blocks/CU

__device__ __forceinline__ float bf2f(USH h) {
    union { unsigned int u; float f; } v; v.u = ((unsigned int)h) << 16; return v.f;
}
__device__ __forceinline__ USH f2bf(float f) {
    union { float f; unsigned int u; } v; v.f = f;
    unsigned int u = v.u;
    return (USH)((u + 0x7FFFu + ((u >> 16) & 1u)) >> 16);
}

// ---------------------------------------------------------------- ALL weight prep in ONE dispatch
struct PrepArgs {
    const float* wq[3]; const float* wk[3]; const float* wv[3];
    const float* qg[3]; const float* qb[3]; const float* vg[3]; const float* vb[3];
    const float* pw[3]; const float* cw;
};
__global__ void prep_all_k(PrepArgs pa, USH* __restrict__ apc, USH* __restrict__ apq,
                           float* __restrict__ biasq, USH* __restrict__ apf) {
    int bid = blockIdx.x, tid = threadIdx.x;
    if (bid < 552) {
        // conv A-frags: chunk cg=(r*4+u)*23+dy ; slot k=(lane>>4)*8+j -> dx=k-r-1 ; kk=lane&15
        // R8: dx shifted by -1 so the input window origin is x0 = xh*96-12 (mod-4
        // aligned), enabling vectorized conv staging. Epilogue x-map unchanged.
        int L = bid / 184, cb = bid - L * 184;
        int t = cb * 256 + tid;
        if (t < 736 * 64) {
            const float* pw = pa.pw[L];
            USH* ap = apc + (size_t)L * 376832;       // 736*64*8 USH per layer
            int lane = t & 63, cg = t >> 6;
            int dy = cg % 23; int ru = cg / 23; int u = ru & 3; int r = ru >> 2;
            int kk = lane & 15, q8 = (lane >> 4) * 8;
            for (int j = 0; j < 8; ++j) {
                int k = q8 + j, dx = k - r - 1;
                USH w = 0;
                if (dx >= 0 && dx < 23) w = f2bf(pw[((kk * 4 + u) * 23 + dy) * 23 + dx]);
                ap[t * 8 + j] = w;
            }
        }
    } else if (bid < 570) {
        // qkv A-frags: o = mt*16+(lane&15), c = kc*32+(lane>>4)*8+j
        int idx = bid - 552; int L = idx / 6; int qblk = idx - L * 6;
        int t = qblk * 256 + tid;
        USH* apl = apq + (size_t)L * 12288;
        float* bl = biasq + L * 192;
        if (t < 1536) {
            int lane = t & 63, chunk = t >> 6;
            int mt = chunk >> 1, kc = chunk & 1;
            int o = mt * 16 + (lane & 15);
            int c0 = kc * 32 + (lane >> 4) * 8;
            float scale; const float* wrow;
            if (o < 64)       { scale = pa.qg[L][o]       * rsqrtf(1.0f + 1e-5f); wrow = pa.wq[L] + o * 64; }
            else if (o < 128) { scale = 1.0f;                                     wrow = pa.wk[L] + (o - 64) * 64; }
            else              { scale = pa.vg[L][o - 128] * rsqrtf(1.0f + 1e-5f); wrow = pa.wv[L] + (o - 128) * 64; }
            for (int j = 0; j < 8; ++j) apl[t * 8 + j] = f2bf(wrow[c0 + j] * scale);
        }
        if (t < 192) {
            float bvv;
            if (t < 64) bvv = pa.qb[L][t]; else if (t < 128) bvv = 0.0f; else bvv = pa.vb[L][t - 128];
            bl[t] = bvv;
        }
    } else {
        int t = (bid - 570) * 256 + tid;
        if (t < 512) {
            int lane = t & 63, chunk = t >> 6;
            int mt = chunk >> 1, kc = chunk & 1;
            int o = mt * 16 + (lane & 15);
            int c0 = kc * 32 + (lane >> 4) * 8;
            for (int j = 0; j < 8; ++j) apf[t * 8 + j] = f2bf(pa.cw[o * 64 + c0 + j]);
        }
    }
}

// ---------------------------------------------------------------- FUSED transpose + QKV GEMM (L0)
__global__ __launch_bounds__(256) void x_qkv_k(
    const float* __restrict__ xin, const bf16x8* __restrict__ apre, const float* __restrict__ bias,
    USH* __restrict__ qT, USH* __restrict__ kbuf, USH* __restrict__ vbuf) {
    __shared__ float tf[64][65];
    const int bid = blockIdx.x; const int b = bid / 576; const int nt = bid - b * 576; const int n0 = nt * 64;
    const int tid = threadIdx.x, lane = tid & 63, wq = tid >> 6;
    const int nl = lane & 15, quad = lane >> 4;
    bf16x8 afr[24];
    #pragma unroll
    for (int i = 0; i < 24; ++i) afr[i] = apre[i * 64 + lane];
    #pragma unroll
    for (int p = 0; p < 16; ++p) {
        int idx = p * 256 + tid; int c = idx >> 6, nn = idx & 63;
        tf[nn][c] = xin[((size_t)b * 64 + c) * NN + n0 + nn];
    }
    __syncthreads();
    bf16x8 b0, b1;
    #pragma unroll
    for (int j = 0; j < 8; ++j) {
        b0[j] = (short)f2bf(tf[wq * 16 + nl][quad * 8 + j]);
        b1[j] = (short)f2bf(tf[wq * 16 + nl][32 + quad * 8 + j]);
    }
    const int n = n0 + wq * 16 + nl;
    #pragma unroll
    for (int mt = 0; mt < 12; ++mt) {
        f32x4 acc = {0.f, 0.f, 0.f, 0.f};
        acc = MFMA16(afr[mt * 2 + 0], b0, acc);
        acc = MFMA16(afr[mt * 2 + 1], b1, acc);
        int o0 = mt * 16 + quad * 4;
        float4 bs = *(const float4*)(bias + o0);
        float v0 = acc[0] + bs.x, v1 = acc[1] + bs.y, v2 = acc[2] + bs.z, v3 = acc[3] + bs.w;
        if (mt < 4) {                       // q -> qT[b][n][o] (o = h*16+kk)
            ushort4 pk; pk.x = f2bf(v0); pk.y = f2bf(v1); pk.z = f2bf(v2); pk.w = f2bf(v3);
            *(ushort4*)(qT + ((size_t)b * NN + n) * 64 + o0) = pk;
        } else if (mt < 8) {                // k raw -> kbuf[b][u*16+kk][n]
            int ko = o0 - 64;
            kbuf[((size_t)b * 64 + ko    ) * NN + n] = f2bf(v0);
            kbuf[((size_t)b * 64 + ko + 1) * NN + n] = f2bf(v1);
            kbuf[((size_t)b * 64 + ko + 2) * NN + n] = f2bf(v2);
            kbuf[((size_t)b * 64 + ko + 3) * NN + n] = f2bf(v3);
        } else {                            // v -> vbuf[(b*16+vv)*4+u][n]
            int u = mt - 8, vv0 = quad * 4;
            vbuf[(((size_t)b * 16 + vv0    ) * 4 + u) * NN + n] = f2bf(v0);
            vbuf[(((size_t)b * 16 + vv0 + 1) * 4 + u) * NN + n] = f2bf(v1);
            vbuf[(((size_t)b * 16 + vv0 + 2) * 4 + u) * NN + n] = f2bf(v2);
            vbuf[(((size_t)b * 16 + vv0 + 3) * 4 + u) * NN + n] = f2bf(v3);
        }
    }
}

// ---------------------------------------------------------------- softmax STATS only (R8)
// k' (softmaxed k) is consumed only by lam_c, so don't materialize it: compute
// per-row M and inv=1/sum; lamc applies f2bf(exp(x-M)*inv) inline before its
// MFMA (bit-identical rounding point). Saves the 18.9MB write pass.
__global__ __launch_bounds__(1024) void softstat_k(const USH* __restrict__ kbuf,
                                                   float* __restrict__ kstat) {
    __shared__ USH row_s[NN];                  // 73,728 B
    __shared__ float red[64];
    const USH* p = kbuf + (size_t)blockIdx.x * NN;
    int tid = threadIdx.x, lane = tid & 63, w = tid >> 6;
    float m = -1e30f;
    for (int i = tid * 4; i < NN; i += 4096) {
        ushort4 t4 = *(const ushort4*)(p + i);
        *(ushort4*)(row_s + i) = t4;
        m = fmaxf(m, fmaxf(fmaxf(bf2f(t4.x), bf2f(t4.y)), fmaxf(bf2f(t4.z), bf2f(t4.w))));
    }
    for (int off = 32; off; off >>= 1) m = fmaxf(m, __shfl_down(m, off));
    if (lane == 0) red[w] = m;
    __syncthreads();
    if (tid == 0) { float mm = red[0]; for (int i = 1; i < 16; ++i) mm = fmaxf(mm, red[i]); red[16] = mm; }
    __syncthreads();
    float M = red[16];
    float s = 0.f;
    for (int i = tid * 4; i < NN; i += 4096) {
        ushort4 t4 = *(const ushort4*)(row_s + i);
        s += __expf(bf2f(t4.x) - M) + __expf(bf2f(t4.y) - M)
           + __expf(bf2f(t4.z) - M) + __expf(bf2f(t4.w) - M);
    }
    for (int off = 32; off; off >>= 1) s += __shfl_down(s, off);
    if (lane == 0) red[32 + w] = s;
    __syncthreads();
    if (tid == 0) {
        float ss = 0.f;
        for (int i = 0; i < 16; ++i) ss += red[32 + i];
        kstat[blockIdx.x * 2]     = M;
        kstat[blockIdx.x * 2 + 1] = 1.0f / ss;
    }
}

// ---------------------------------------------------------------- lam_c split-K stage 1 -- MFMA + fused softmax (R8)
// Reads RAW k; applies ka = f2bf(exp(k - M) * inv) per element (identical to the
// old materialized k'), then 16x16 MFMA. 512-n chunks (grid 1152) for latency
// hiding of the exp VALU at 1-wave blocks.
__global__ __launch_bounds__(64) void lamc_stage1_k(
    const USH* __restrict__ kbuf, const USH* __restrict__ vbuf,
    const float* __restrict__ kstat, float* __restrict__ part) {
    int bid = blockIdx.x;                  // (cidx 0..71)*16 + b*4 + u
    int cidx = bid >> 4; int rem = bid & 15; int b = rem >> 2; int u = rem & 3;
    int lane = threadIdx.x; int nl = lane & 15, quad = lane >> 4;
    int krow = b * 64 + u * 16 + nl;
    float M = kstat[krow * 2], inv = kstat[krow * 2 + 1];
    const USH* kp = kbuf + (size_t)krow * NN + cidx * 512 + quad * 8;
    const USH* vp = vbuf + (((size_t)b * 16 + nl) * 4 + u) * NN + cidx * 512 + quad * 8;
    f32x4 acc = {0.f, 0.f, 0.f, 0.f};
    #pragma unroll 4
    for (int s = 0; s < 16; ++s) {
        bf16x8 kr = *(const bf16x8*)(kp + s * 32);
        bf16x8 va = *(const bf16x8*)(vp + s * 32);
        bf16x8 ka;
        #pragma unroll
        for (int j = 0; j < 8; ++j)
            ka[j] = (short)f2bf(__expf(bf2f((USH)kr[j]) - M) * inv);
        acc = MFMA16(ka, va, acc);
    }
    float* pout = part + ((size_t)(cidx * 4 + b) * 4 + u) * 256;
    #pragma unroll
    for (int rg = 0; rg < 4; ++rg)
        pout[nl * 16 + quad * 4 + rg] = acc[rg];
}
__global__ void lamc_stage2_k(const float* __restrict__ part, const float* __restrict__ pb,
                              float* __restrict__ lamcf) {
    int b = blockIdx.x, tid = threadIdx.x;   // tid = vv*16+kk
    float acc = 0.f;
    for (int c = 0; c < 72; ++c)
        for (int u = 0; u < 4; ++u)
            acc += part[((size_t)(c * 4 + b) * 4 + u) * 256 + tid];
    lamcf[b * 256 + tid] = acc + pb[tid & 15];   // fold conv bias pb[kk]
}

// ---------------------------------------------------------------- position conv 23x23 (MFMA implicit GEMM)
// + FUSED y-epilogue + FUSED GroupNorm partial sums. Proven R2/R6 config.
// R8: staging VECTORIZED (ushort4): window origin x0 = xh*96-12 is mod-4
// aligned (enabled by the dx=k-r-1 weight re-pad), and HH%4==0 means chunks
// never straddle the image edge -> pure {vec load | zero} with 8B-aligned
// global and LDS sides. 101 scalar iters/thread -> ~26 vec iters/thread.
// setprio removed (R7 measured null on this kernel).
__global__ __launch_bounds__(256, 3) void conv_pos_fused_k(
    const USH* __restrict__ vbuf, const bf16x8* __restrict__ apre,
    const USH* __restrict__ qT, const float* __restrict__ lamcf,
    USH* __restrict__ yb, float* __restrict__ gnp2) {
    __shared__ __align__(16) USH in_s[4 * 54 * CSTR];     // 51,840 B
    __shared__ float lc_s[16];
    __shared__ float gn_s[16], gn_q[16];
    const int xh = blockIdx.x, yt = blockIdx.y, img = blockIdx.z;
    const int b = img >> 4, vvch = img & 15;
    const int tid = threadIdx.x;
    if (tid < 16) lc_s[tid] = lamcf[b * 256 + vvch * 16 + tid];
    {
        const USH* vb = vbuf + (size_t)img * 4 * NN;
        const int y0 = yt * 32 - 11, x0 = xh * 96 - 12;
        for (int i4 = tid; i4 < 6480; i4 += 256) {       // 4u*54rr*30c4
            int u = i4 / 1620;
            int rem = i4 - u * 1620;
            int rr = rem / 30;
            int cc = (rem - rr * 30) * 4;
            int gy = y0 + rr, gx = x0 + cc;
            ushort4 val = {0, 0, 0, 0};
            if (gy >= 0 && gy < HH && gx >= 0 && gx <= HH - 4)
                val = *(const ushort4*)(vb + u * NN + gy * HH + gx);
            *(ushort4*)(in_s + (u * 54 + rr) * CSTR + cc) = val;
        }
    }
    __syncthreads();

    const int lane = tid & 63, wv = tid >> 6;
    const int wy = wv >> 1, wx = wv & 1;
    const int nl = lane & 15, quad = lane >> 4;
    const USH* sbase = in_s + (wy * 16 + nl) * CSTR + wx * 48 + quad * 8;
    const int ybase = yt * 32 + wy * 16 + nl;
    float lcr0 = lc_s[quad * 4], lcr1 = lc_s[quad * 4 + 1],
          lcr2 = lc_s[quad * 4 + 2], lcr3 = lc_s[quad * 4 + 3];
    const USH* qbase = qT + ((size_t)b * NN + ybase * HH) * 64 + quad * 4;
    USH* ybbase = yb + ((size_t)b * 64 + quad * 16 + vvch) * NN + ybase * HH;
    float SG = 0.f, QG = 0.f;

#define CONV_EPILOGUE(ACC, RVAL)                                                            \
    {                                                                                       \
        _Pragma("unroll")                                                                   \
        for (int xi = 0; xi < 6; ++xi) {                                                    \
            int x = xh * 96 + wx * 48 + (RVAL) + 8 * xi;                                    \
            float l0 = ACC[xi][0] + lcr0, l1 = ACC[xi][1] + lcr1;                           \
            float l2 = ACC[xi][2] + lcr2, l3 = ACC[xi][3] + lcr3;                           \
            const USH* qp = qbase + (size_t)x * 64;                                         \
            float s0, s1, s2, s3;                                                           \
            {                                                                               \
                ushort4 q4 = *(const ushort4*)(qp);                                         \
                s0 = bf2f(q4.x) * l0 + bf2f(q4.y) * l1 + bf2f(q4.z) * l2 + bf2f(q4.w) * l3; \
            }                                                                               \
            {                                                                               \
                ushort4 q4 = *(const ushort4*)(qp + 16);                                    \
                s1 = bf2f(q4.x) * l0 + bf2f(q4.y) * l1 + bf2f(q4.z) * l2 + bf2f(q4.w) * l3; \
            }                                                                               \
            {                                                                               \
                ushort4 q4 = *(const ushort4*)(qp + 32);                                    \
                s2 = bf2f(q4.x) * l0 + bf2f(q4.y) * l1 + bf2f(q4.z) * l2 + bf2f(q4.w) * l3; \
            }                                                                               \
            {                                                                               \
                ushort4 q4 = *(const ushort4*)(qp + 48);                                    \
                s3 = bf2f(q4.x) * l0 + bf2f(q4.y) * l1 + bf2f(q4.z) * l2 + bf2f(q4.w) * l3; \
            }                                                                               \
            s0 += __shfl_xor(s0, 16); s0 += __shfl_xor(s0, 32);                             \
            s1 += __shfl_xor(s1, 16); s1 += __shfl_xor(s1, 32);                             \
            s2 += __shfl_xor(s2, 16); s2 += __shfl_xor(s2, 32);                             \
            s3 += __shfl_xor(s3, 16); s3 += __shfl_xor(s3, 32);                             \
            float sel = (quad == 0) ? s0 : (quad == 1) ? s1 : (quad == 2) ? s2 : s3;        \
            USH wo = f2bf(sel);                                                             \
            ybbase[x] = wo;                                                                 \
            float wf = bf2f(wo);                                                            \
            SG += wf; QG += wf * wf;                                                        \
        }                                                                                   \
    }

#define CONV_PASS3(R0)                                                                      \
    {                                                                                       \
        f32x4 acc0[6] = {}; f32x4 acc1[6] = {}; f32x4 acc2[6] = {};                         \
        for (int u = 0; u < 4; ++u) {                                                       \
            const bf16x8* ap0 = apre + ((size_t)((R0) * 4 + u) * 23) * 64 + lane;           \
            const bf16x8* ap1 = ap0 + 4 * 23 * 64;                                          \
            const bf16x8* ap2 = ap0 + 2 * 4 * 23 * 64;                                      \
            const USH* srow = sbase + u * (54 * CSTR);                                      \
            _Pragma("unroll 2")                                                             \
            for (int dy = 0; dy < 23; ++dy) {                                               \
                bf16x8 a0 = *ap0, a1 = *ap1, a2 = *ap2;                                     \
                _Pragma("unroll")                                                           \
                for (int xi = 0; xi < 6; ++xi) {                                            \
                    bf16x8 bfr = *(const bf16x8*)(srow + 8 * xi);                           \
                    acc0[xi] = MFMA16(a0, bfr, acc0[xi]);                                   \
                    acc1[xi] = MFMA16(a1, bfr, acc1[xi]);                                   \
                    acc2[xi] = MFMA16(a2, bfr, acc2[xi]);                                   \
                }                                                                           \
                ap0 += 64; ap1 += 64; ap2 += 64; srow += CSTR;                               \
            }                                                                               \
        }                                                                                   \
        CONV_EPILOGUE(acc0, (R0))                                                           \
        CONV_EPILOGUE(acc1, (R0) + 1)                                                       \
        CONV_EPILOGUE(acc2, (R0) + 2)                                                       \
    }

    CONV_PASS3(0)
    CONV_PASS3(3)
    {   // last pass: r = 6,7
        f32x4 acc0[6] = {}; f32x4 acc1[6] = {};
        for (int u = 0; u < 4; ++u) {
            const bf16x8* ap0 = apre + ((size_t)(6 * 4 + u) * 23) * 64 + lane;
            const bf16x8* ap1 = ap0 + 4 * 23 * 64;
            const USH* srow = sbase + u * (54 * CSTR);
            #pragma unroll 2
            for (int dy = 0; dy < 23; ++dy) {
                bf16x8 a0 = *ap0, a1 = *ap1;
                #pragma unroll
                for (int xi = 0; xi < 6; ++xi) {
                    bf16x8 bfr = *(const bf16x8*)(srow + 8 * xi);
                    acc0[xi] = MFMA16(a0, bfr, acc0[xi]);
                    acc1[xi] = MFMA16(a1, bfr, acc1[xi]);
                }
                ap0 += 64; ap1 += 64; srow += CSTR;
            }
        }
        CONV_EPILOGUE(acc0, 6)
        CONV_EPILOGUE(acc1, 7)
    }
#undef CONV_PASS3
#undef CONV_EPILOGUE

    // GN partials: reduce Σ/Σ² over nl within each quad group (channel fixed)
    SG += __shfl_xor(SG, 1); SG += __shfl_xor(SG, 2); SG += __shfl_xor(SG, 4); SG += __shfl_xor(SG, 8);
    QG += __shfl_xor(QG, 1); QG += __shfl_xor(QG, 2); QG += __shfl_xor(QG, 4); QG += __shfl_xor(QG, 8);
    if (nl == 0) { gn_s[wv * 4 + quad] = SG; gn_q[wv * 4 + quad] = QG; }
    __syncthreads();
    if (tid < 4) {
        float s = gn_s[tid] + gn_s[4 + tid] + gn_s[8 + tid] + gn_s[12 + tid];
        float q = gn_q[tid] + gn_q[4 + tid] + gn_q[8 + tid] + gn_q[12 + tid];
        int lin = img * 12 + yt * 2 + xh;
        gnp2[lin * 8 + tid * 2]     = s;
        gnp2[lin * 8 + tid * 2 + 1] = q;
    }
}

// ---------------------------------------------------------------- GroupNorm stats from conv partials
__global__ void gn_passB_k(const float* __restrict__ gnp2, float* __restrict__ stats) {
    int t = threadIdx.x;
    if (t < 32) {
        int b = t >> 3, g = t & 7;
        int quad = g >> 1, v0 = (g & 1) * 8;
        float s = 0.f, q = 0.f;
        for (int vv = 0; vv < 8; ++vv)
            for (int tile = 0; tile < 12; ++tile) {
                const float* p = gnp2 + ((size_t)((b * 16 + v0 + vv) * 12 + tile)) * 8 + quad * 2;
                s += p[0]; q += p[1];
            }
        float mean = s / 294912.0f;
        float var = q / 294912.0f - mean * mean;
        stats[t * 2] = mean;
        stats[t * 2 + 1] = rsqrtf(fmaxf(var, 0.0f) + 1e-5f);
    }
}

// ---------------------------------------------------------------- FUSED GroupNorm-normalize + QKV GEMM (L->L+1)
__global__ __launch_bounds__(256) void gn_qkv_k(
    const USH* __restrict__ yb, const float* __restrict__ stats,
    const float* __restrict__ gg, const float* __restrict__ gb,
    const bf16x8* __restrict__ apre, const float* __restrict__ bias,
    USH* __restrict__ qT, USH* __restrict__ kbuf, USH* __restrict__ vbuf) {
    __shared__ float tf[64][65];
    __shared__ float sc[64], sb[64];
    const int bid = blockIdx.x; const int b = bid / 576; const int nt = bid - b * 576; const int n0 = nt * 64;
    const int tid = threadIdx.x, lane = tid & 63, wq = tid >> 6;
    const int nl = lane & 15, quad = lane >> 4;
    bf16x8 afr[24];
    #pragma unroll
    for (int i = 0; i < 24; ++i) afr[i] = apre[i * 64 + lane];
    if (tid < 64) {
        int g = tid >> 3;
        float mean = stats[(b * 8 + g) * 2], rstd = stats[(b * 8 + g) * 2 + 1];
        float ga = gg[tid];
        sc[tid] = rstd * ga;
        sb[tid] = gb[tid] - mean * rstd * ga;
    }
    __syncthreads();
    #pragma unroll
    for (int p = 0; p < 4; ++p) {
        int c = p * 16 + (tid >> 4), nn = (tid & 15) * 4;
        ushort4 y4 = *(const ushort4*)(yb + ((size_t)b * 64 + c) * NN + n0 + nn);
        float scc = sc[c], sbc = sb[c];
        tf[nn][c]     = bf2f(y4.x) * scc + sbc;
        tf[nn + 1][c] = bf2f(y4.y) * scc + sbc;
        tf[nn + 2][c] = bf2f(y4.z) * scc + sbc;
        tf[nn + 3][c] = bf2f(y4.w) * scc + sbc;
    }
    __syncthreads();
    bf16x8 b0, b1;
    #pragma unroll
    for (int j = 0; j < 8; ++j) {
        b0[j] = (short)f2bf(tf[wq * 16 + nl][quad * 8 + j]);
        b1[j] = (short)f2bf(tf[wq * 16 + nl][32 + quad * 8 + j]);
    }
    const int n = n0 + wq * 16 + nl;
    #pragma unroll
    for (int mt = 0; mt < 12; ++mt) {
        f32x4 acc = {0.f, 0.f, 0.f, 0.f};
        acc = MFMA16(afr[mt * 2 + 0], b0, acc);
        acc = MFMA16(afr[mt * 2 + 1], b1, acc);
        int o0 = mt * 16 + quad * 4;
        float4 bs = *(const float4*)(bias + o0);
        float v0 = acc[0] + bs.x, v1 = acc[1] + bs.y, v2 = acc[2] + bs.z, v3 = acc[3] + bs.w;
        if (mt < 4) {
            ushort4 pk; pk.x = f2bf(v0); pk.y = f2bf(v1); pk.z = f2bf(v2); pk.w = f2bf(v3);
            *(ushort4*)(qT + ((size_t)b * NN + n) * 64 + o0) = pk;
        } else if (mt < 8) {
            int ko = o0 - 64;
            kbuf[((size_t)b * 64 + ko    ) * NN + n] = f2bf(v0);
            kbuf[((size_t)b * 64 + ko + 1) * NN + n] = f2bf(v1);
            kbuf[((size_t)b * 64 + ko + 2) * NN + n] = f2bf(v2);
            kbuf[((size_t)b * 64 + ko + 3) * NN + n] = f2bf(v3);
        } else {
            int u = mt - 8, vv0 = quad * 4;
            vbuf[(((size_t)b * 16 + vv0    ) * 4 + u) * NN + n] = f2bf(v0);
            vbuf[(((size_t)b * 16 + vv0 + 1) * 4 + u) * NN + n] = f2bf(v1);
            vbuf[(((size_t)b * 16 + vv0 + 2) * 4 + u) * NN + n] = f2bf(v2);
            vbuf[(((size_t)b * 16 + vv0 + 3) * 4 + u) * NN + n] = f2bf(v3);
        }
    }
}

// ---------------------------------------------------------------- FUSED GroupNorm-normalize + final conv1x1 + *0.2 + x
__global__ __launch_bounds__(256) void gn_final_k(
    const USH* __restrict__ yb, const float* __restrict__ stats,
    const float* __restrict__ gg, const float* __restrict__ gb,
    const bf16x8* __restrict__ apre, const float* __restrict__ cb,
    const float* __restrict__ xin, float* __restrict__ out) {
    __shared__ float tf[64][65];
    __shared__ float sc[64], sb[64];
    const int bid = blockIdx.x; const int b = bid / 576; const int nt = bid - b * 576; const int n0 = nt * 64;
    const int tid = threadIdx.x, lane = tid & 63, wq = tid >> 6;
    const int nl = lane & 15, quad = lane >> 4;
    bf16x8 afr[8];
    #pragma unroll
    for (int i = 0; i < 8; ++i) afr[i] = apre[i * 64 + lane];
    if (tid < 64) {
        int g = tid >> 3;
        float mean = stats[(b * 8 + g) * 2], rstd = stats[(b * 8 + g) * 2 + 1];
        float ga = gg[tid];
        sc[tid] = rstd * ga;
        sb[tid] = gb[tid] - mean * rstd * ga;
    }
    __syncthreads();
    #pragma unroll
    for (int p = 0; p < 4; ++p) {
        int c = p * 16 + (tid >> 4), nn = (tid & 15) * 4;
        ushort4 y4 = *(const ushort4*)(yb + ((size_t)b * 64 + c) * NN + n0 + nn);
        float scc = sc[c], sbc = sb[c];
        tf[nn][c]     = bf2f(y4.x) * scc + sbc;
        tf[nn + 1][c] = bf2f(y4.y) * scc + sbc;
        tf[nn + 2][c] = bf2f(y4.z) * scc + sbc;
        tf[nn + 3][c] = bf2f(y4.w) * scc + sbc;
    }
    __syncthreads();
    bf16x8 b0, b1;
    #pragma unroll
    for (int j = 0; j < 8; ++j) {
        b0[j] = (short)f2bf(tf[wq * 16 + nl][quad * 8 + j]);
        b1[j] = (short)f2bf(tf[wq * 16 + nl][32 + quad * 8 + j]);
    }
    const int n = n0 + wq * 16 + nl;
    #pragma unroll
    for (int mt = 0; mt < 4; ++mt) {
        f32x4 acc = {0.f, 0.f, 0.f, 0.f};
        acc = MFMA16(afr[mt * 2 + 0], b0, acc);
        acc = MFMA16(afr[mt * 2 + 1], b1, acc);
        int o0 = mt * 16 + quad * 4;
        float4 cb4 = *(const float4*)(cb + o0);
        float cbv[4] = { cb4.x, cb4.y, cb4.z, cb4.w };
        #pragma unroll
        for (int rg = 0; rg < 4; ++rg) {
            int o = o0 + rg;
            float xv = xin[((size_t)b * 64 + o) * NN + n];
            out[((size_t)b * 64 + o) * NN + n] = (acc[rg] + cbv[rg]) * 0.2f + xv;
        }
    }
}

// ================================================================ host
extern "C" void kernel_launch(void* const* d_in, const int* in_sizes, int n_in,
                              void* d_out, int out_size, void* d_ws, size_t ws_size,
                              hipStream_t stream) {
    (void)in_sizes; (void)n_in; (void)out_size; (void)ws_size;
    const float* x = (const float*)d_in[0];
    char* ws = (char*)d_ws;

    // 4 bf16 planes, ping-pong aliasing (ybuf(L) = kbuf(L) plane; next-layer k
    // goes to the dead plane): L0 y=P2 -> k'=P0 ; L1 y=P0 -> k'=P2 ; L2 y=P2 -> out.
    const size_t SZP = (size_t)NTOT * 64 * 2;          // 18,874,368 B
    USH*   P0 = (USH*)(ws);                            // k(L1)/y(L1)
    USH*   P1 = (USH*)(ws + SZP);                      // qT (all layers)
    USH*   P2 = (USH*)(ws + 2 * SZP);                  // k(L0)/y(L0), k(L2)/y(L2)
    USH*   P3 = (USH*)(ws + 3 * SZP);                  // v (all layers)
    char*  tail  = ws + 4 * SZP;
    USH*   apc   = (USH*)(tail);            tail += 753664 * 3;   // conv A-frags x3 layers
    USH*   apq   = (USH*)(tail);            tail += 24576 * 3;    // qkv A-frags x3
    float* biasq = (float*)(tail);          tail += 768 * 3;
    USH*   apf   = (USH*)(tail);            tail += 8192;         // final A-frags
    float* lcp   = (float*)(tail);          tail += 1179648;      // lam_c partials (72 chunks)
    float* lcf   = (float*)(tail);          tail += 4096;         // lam_c + pb, [b][vv][kk]
    float* gnp2  = (float*)(tail);          tail += 24576;        // GN partials from conv (6144 floats)
    float* gns   = (float*)(tail);          tail += 256;          // GN mean/rstd
    float* kst   = (float*)(tail);                                // softmax stats (256 rows x 2)

    PrepArgs pa;
    for (int L = 0; L < 3; ++L) {
        int base = 1 + L * 9;
        pa.wq[L] = (const float*)d_in[base + 0];
        pa.wk[L] = (const float*)d_in[base + 1];
        pa.wv[L] = (const float*)d_in[base + 2];
        pa.qg[L] = (const float*)d_in[base + 3];
        pa.qb[L] = (const float*)d_in[base + 4];
        pa.vg[L] = (const float*)d_in[base + 5];
        pa.vb[L] = (const float*)d_in[base + 6];
        pa.pw[L] = (const float*)d_in[base + 7];
    }
    pa.cw = (const float*)d_in[32];

    prep_all_k<<<572, 256, 0, stream>>>(pa, apc, apq, biasq, apf);

    // L0 qkv directly from fp32 x (fused transpose)
    x_qkv_k<<<2304, 256, 0, stream>>>(x, (const bf16x8*)apq, biasq, P1, P2, P3);

    for (int L = 0; L < 3; ++L) {
        const float* pb = (const float*)d_in[1 + L * 9 + 8];
        USH* kv = (L == 1) ? P0 : P2;          // kbuf == ybuf plane of this layer

        softstat_k<<<256, 1024, 0, stream>>>(kv, kst);
        lamc_stage1_k<<<1152, 64, 0, stream>>>(kv, P3, kst, lcp);
        lamc_stage2_k<<<4, 256, 0, stream>>>(lcp, pb, lcf);
        dim3 cg(2, 6, 64);
        conv_pos_fused_k<<<cg, 256, 0, stream>>>(P3, (const bf16x8*)apc + (size_t)L * 47104,
                                                 P1, lcf, kv, gnp2);
        gn_passB_k<<<1, 256, 0, stream>>>(gnp2, gns);
        if (L < 2) {
            const float* gg = (const float*)d_in[28];
            const float* gb = (const float*)d_in[29];
            USH* knext = (L == 0) ? P0 : P2;
            gn_qkv_k<<<2304, 256, 0, stream>>>(kv, gns, gg, gb,
                                               (const bf16x8*)apq + (size_t)(L + 1) * 1536,
                                               biasq + (L + 1) * 192, P1, knext, P3);
        } else {
            const float* gg = (const float*)d_in[30];
            const float* gb = (const float*)d_in[31];
            gn_final_k<<<2304, 256, 0, stream>>>(kv, gns, gg, gb, (const bf16x8*)apf,
                                                 (const float*)d_in[33], x, (float*)d_out);
        }
    }
}

// Round 9
// 909.271 us; speedup vs baseline: 1.6845x; 1.0361x over previous
//
#include <hip/hip_runtime.h>

typedef unsigned short USH;
typedef __attribute__((ext_vector_type(8))) short bf16x8;   // 8 bf16 = 4 VGPR
typedef __attribute__((ext_vector_type(4))) float f32x4;

#define MFMA16(a,b,c) __builtin_amdgcn_mfma_f32_16x16x32_bf16((a),(b),(c),0,0,0)

#define BB 4
#define HH 192
#define NN 36864            // 192*192
#define NTOT 147456         // 4*NN
#define CSTR 120            // conv LDS row stride (USH); 119 needed, 120 keeps 16B align
#define NCH 192             // lam_c chunks (192 n each) -> grid 3072, 12 waves/CU

__device__ __forceinline__ float bf2f(USH h) {
    union { unsigned int u; float f; } v; v.u = ((unsigned int)h) << 16; return v.f;
}
__device__ __forceinline__ USH f2bf(float f) {
    union { float f; unsigned int u; } v; v.f = f;
    unsigned int u = v.u;
    return (USH)((u + 0x7FFFu + ((u >> 16) & 1u)) >> 16);
}

// ---------------------------------------------------------------- ALL weight prep in ONE dispatch
struct PrepArgs {
    const float* wq[3]; const float* wk[3]; const float* wv[3];
    const float* qg[3]; const float* qb[3]; const float* vg[3]; const float* vb[3];
    const float* pw[3]; const float* cw;
};
__global__ void prep_all_k(PrepArgs pa, USH* __restrict__ apc, USH* __restrict__ apq,
                           float* __restrict__ biasq, USH* __restrict__ apf) {
    int bid = blockIdx.x, tid = threadIdx.x;
    if (bid < 552) {
        // conv A-frags: chunk cg=(r*4+u)*23+dy ; slot k=(lane>>4)*8+j -> dx=k-r-1 ; kk=lane&15
        // dx shifted by -1 so the input window origin x0 = xh*96-12 is mod-4
        // aligned, enabling vectorized conv staging. Epilogue x-map unchanged.
        int L = bid / 184, cb = bid - L * 184;
        int t = cb * 256 + tid;
        if (t < 736 * 64) {
            const float* pw = pa.pw[L];
            USH* ap = apc + (size_t)L * 376832;       // 736*64*8 USH per layer
            int lane = t & 63, cg = t >> 6;
            int dy = cg % 23; int ru = cg / 23; int u = ru & 3; int r = ru >> 2;
            int kk = lane & 15, q8 = (lane >> 4) * 8;
            for (int j = 0; j < 8; ++j) {
                int k = q8 + j, dx = k - r - 1;
                USH w = 0;
                if (dx >= 0 && dx < 23) w = f2bf(pw[((kk * 4 + u) * 23 + dy) * 23 + dx]);
                ap[t * 8 + j] = w;
            }
        }
    } else if (bid < 570) {
        // qkv A-frags: o = mt*16+(lane&15), c = kc*32+(lane>>4)*8+j
        int idx = bid - 552; int L = idx / 6; int qblk = idx - L * 6;
        int t = qblk * 256 + tid;
        USH* apl = apq + (size_t)L * 12288;
        float* bl = biasq + L * 192;
        if (t < 1536) {
            int lane = t & 63, chunk = t >> 6;
            int mt = chunk >> 1, kc = chunk & 1;
            int o = mt * 16 + (lane & 15);
            int c0 = kc * 32 + (lane >> 4) * 8;
            float scale; const float* wrow;
            if (o < 64)       { scale = pa.qg[L][o]       * rsqrtf(1.0f + 1e-5f); wrow = pa.wq[L] + o * 64; }
            else if (o < 128) { scale = 1.0f;                                     wrow = pa.wk[L] + (o - 64) * 64; }
            else              { scale = pa.vg[L][o - 128] * rsqrtf(1.0f + 1e-5f); wrow = pa.wv[L] + (o - 128) * 64; }
            for (int j = 0; j < 8; ++j) apl[t * 8 + j] = f2bf(wrow[c0 + j] * scale);
        }
        if (t < 192) {
            float bvv;
            if (t < 64) bvv = pa.qb[L][t]; else if (t < 128) bvv = 0.0f; else bvv = pa.vb[L][t - 128];
            bl[t] = bvv;
        }
    } else {
        int t = (bid - 570) * 256 + tid;
        if (t < 512) {
            int lane = t & 63, chunk = t >> 6;
            int mt = chunk >> 1, kc = chunk & 1;
            int o = mt * 16 + (lane & 15);
            int c0 = kc * 32 + (lane >> 4) * 8;
            for (int j = 0; j < 8; ++j) apf[t * 8 + j] = f2bf(pa.cw[o * 64 + c0 + j]);
        }
    }
}

// ---------------------------------------------------------------- FUSED transpose + QKV GEMM (L0)
__global__ __launch_bounds__(256) void x_qkv_k(
    const float* __restrict__ xin, const bf16x8* __restrict__ apre, const float* __restrict__ bias,
    USH* __restrict__ qT, USH* __restrict__ kbuf, USH* __restrict__ vbuf) {
    __shared__ float tf[64][65];
    const int bid = blockIdx.x; const int b = bid / 576; const int nt = bid - b * 576; const int n0 = nt * 64;
    const int tid = threadIdx.x, lane = tid & 63, wq = tid >> 6;
    const int nl = lane & 15, quad = lane >> 4;
    bf16x8 afr[24];
    #pragma unroll
    for (int i = 0; i < 24; ++i) afr[i] = apre[i * 64 + lane];
    #pragma unroll
    for (int p = 0; p < 16; ++p) {
        int idx = p * 256 + tid; int c = idx >> 6, nn = idx & 63;
        tf[nn][c] = xin[((size_t)b * 64 + c) * NN + n0 + nn];
    }
    __syncthreads();
    bf16x8 b0, b1;
    #pragma unroll
    for (int j = 0; j < 8; ++j) {
        b0[j] = (short)f2bf(tf[wq * 16 + nl][quad * 8 + j]);
        b1[j] = (short)f2bf(tf[wq * 16 + nl][32 + quad * 8 + j]);
    }
    const int n = n0 + wq * 16 + nl;
    #pragma unroll
    for (int mt = 0; mt < 12; ++mt) {
        f32x4 acc = {0.f, 0.f, 0.f, 0.f};
        acc = MFMA16(afr[mt * 2 + 0], b0, acc);
        acc = MFMA16(afr[mt * 2 + 1], b1, acc);
        int o0 = mt * 16 + quad * 4;
        float4 bs = *(const float4*)(bias + o0);
        float v0 = acc[0] + bs.x, v1 = acc[1] + bs.y, v2 = acc[2] + bs.z, v3 = acc[3] + bs.w;
        if (mt < 4) {                       // q -> qT[b][n][o] (o = h*16+kk)
            ushort4 pk; pk.x = f2bf(v0); pk.y = f2bf(v1); pk.z = f2bf(v2); pk.w = f2bf(v3);
            *(ushort4*)(qT + ((size_t)b * NN + n) * 64 + o0) = pk;
        } else if (mt < 8) {                // k raw -> kbuf[b][u*16+kk][n]
            int ko = o0 - 64;
            kbuf[((size_t)b * 64 + ko    ) * NN + n] = f2bf(v0);
            kbuf[((size_t)b * 64 + ko + 1) * NN + n] = f2bf(v1);
            kbuf[((size_t)b * 64 + ko + 2) * NN + n] = f2bf(v2);
            kbuf[((size_t)b * 64 + ko + 3) * NN + n] = f2bf(v3);
        } else {                            // v -> vbuf[(b*16+vv)*4+u][n]
            int u = mt - 8, vv0 = quad * 4;
            vbuf[(((size_t)b * 16 + vv0    ) * 4 + u) * NN + n] = f2bf(v0);
            vbuf[(((size_t)b * 16 + vv0 + 1) * 4 + u) * NN + n] = f2bf(v1);
            vbuf[(((size_t)b * 16 + vv0 + 2) * 4 + u) * NN + n] = f2bf(v2);
            vbuf[(((size_t)b * 16 + vv0 + 3) * 4 + u) * NN + n] = f2bf(v3);
        }
    }
}

// ---------------------------------------------------------------- softmax STATS only
// k' is consumed only by lam_c; compute per-row M and inv=1/sum; lamc applies
// f2bf(exp(x-M)*inv) inline (bit-identical rounding point).
__global__ __launch_bounds__(1024) void softstat_k(const USH* __restrict__ kbuf,
                                                   float* __restrict__ kstat) {
    __shared__ USH row_s[NN];                  // 73,728 B
    __shared__ float red[64];
    const USH* p = kbuf + (size_t)blockIdx.x * NN;
    int tid = threadIdx.x, lane = tid & 63, w = tid >> 6;
    float m = -1e30f;
    for (int i = tid * 4; i < NN; i += 4096) {
        ushort4 t4 = *(const ushort4*)(p + i);
        *(ushort4*)(row_s + i) = t4;
        m = fmaxf(m, fmaxf(fmaxf(bf2f(t4.x), bf2f(t4.y)), fmaxf(bf2f(t4.z), bf2f(t4.w))));
    }
    for (int off = 32; off; off >>= 1) m = fmaxf(m, __shfl_down(m, off));
    if (lane == 0) red[w] = m;
    __syncthreads();
    if (tid == 0) { float mm = red[0]; for (int i = 1; i < 16; ++i) mm = fmaxf(mm, red[i]); red[16] = mm; }
    __syncthreads();
    float M = red[16];
    float s = 0.f;
    for (int i = tid * 4; i < NN; i += 4096) {
        ushort4 t4 = *(const ushort4*)(row_s + i);
        s += __expf(bf2f(t4.x) - M) + __expf(bf2f(t4.y) - M)
           + __expf(bf2f(t4.z) - M) + __expf(bf2f(t4.w) - M);
    }
    for (int off = 32; off; off >>= 1) s += __shfl_down(s, off);
    if (lane == 0) red[32 + w] = s;
    __syncthreads();
    if (tid == 0) {
        float ss = 0.f;
        for (int i = 0; i < 16; ++i) ss += red[32 + i];
        kstat[blockIdx.x * 2]     = M;
        kstat[blockIdx.x * 2 + 1] = 1.0f / ss;
    }
}

// ---------------------------------------------------------------- lam_c split-K stage 1 -- MFMA + fused softmax
// R9: chunk 512 -> 192 n (grid 3072 = 12 waves/CU; was 4.5): this kernel is
// memory-latency bound at 1 wave/block, occupancy is the lever.
__global__ __launch_bounds__(64) void lamc_stage1_k(
    const USH* __restrict__ kbuf, const USH* __restrict__ vbuf,
    const float* __restrict__ kstat, float* __restrict__ part) {
    int bid = blockIdx.x;                  // cidx*16 + b*4 + u ; cidx in [0,NCH)
    int cidx = bid >> 4; int rem = bid & 15; int b = rem >> 2; int u = rem & 3;
    int lane = threadIdx.x; int nl = lane & 15, quad = lane >> 4;
    int krow = b * 64 + u * 16 + nl;
    float M = kstat[krow * 2], inv = kstat[krow * 2 + 1];
    const USH* kp = kbuf + (size_t)krow * NN + cidx * 192 + quad * 8;
    const USH* vp = vbuf + (((size_t)b * 16 + nl) * 4 + u) * NN + cidx * 192 + quad * 8;
    f32x4 acc = {0.f, 0.f, 0.f, 0.f};
    #pragma unroll
    for (int s = 0; s < 6; ++s) {
        bf16x8 kr = *(const bf16x8*)(kp + s * 32);
        bf16x8 va = *(const bf16x8*)(vp + s * 32);
        bf16x8 ka;
        #pragma unroll
        for (int j = 0; j < 8; ++j)
            ka[j] = (short)f2bf(__expf(bf2f((USH)kr[j]) - M) * inv);
        acc = MFMA16(ka, va, acc);
    }
    float* pout = part + ((size_t)(cidx * 4 + b) * 4 + u) * 256;
    #pragma unroll
    for (int rg = 0; rg < 4; ++rg)
        pout[nl * 16 + quad * 4 + rg] = acc[rg];
}

// ---------------------------------------------------------------- position conv 23x23 (MFMA implicit GEMM)
// + FUSED y-epilogue + FUSED GroupNorm partials + FUSED lam_c stage-2 (R9):
// each block reduces its own 16 lam_c values from the stage-1 partials
// (48 L2 loads/thread, overlapped with staging; +1KB LDS = 53.2KB, still
// 3 blocks/CU under the 54.6KB limit). Removes the 4-block lamc_stage2
// dispatch + its stream sync per layer.
__global__ __launch_bounds__(256, 3) void conv_pos_fused_k(
    const USH* __restrict__ vbuf, const bf16x8* __restrict__ apre,
    const USH* __restrict__ qT, const float* __restrict__ lcp,
    const float* __restrict__ pb, USH* __restrict__ yb, float* __restrict__ gnp2) {
    __shared__ __align__(16) USH in_s[4 * 54 * CSTR];     // 51,840 B
    __shared__ float lc_red[16][16];
    __shared__ float lc_s[16];
    __shared__ float gn_s[16], gn_q[16];
    const int xh = blockIdx.x, yt = blockIdx.y, img = blockIdx.z;
    const int b = img >> 4, vvch = img & 15;
    const int tid = threadIdx.x;
    {   // lam_c stage-2 partials: slice of the (cidx,u) pair space per thread
        int kk = tid & 15, slice = tid >> 4;
        float s = 0.f;
        for (int p = slice * 48; p < slice * 48 + 48; ++p) {   // NCH*4/16 = 48
            int cidx = p >> 2, u = p & 3;
            s += lcp[((size_t)(cidx * 4 + b) * 4 + u) * 256 + vvch * 16 + kk];
        }
        lc_red[slice][kk] = s;
    }
    {
        const USH* vb = vbuf + (size_t)img * 4 * NN;
        const int y0 = yt * 32 - 11, x0 = xh * 96 - 12;
        for (int i4 = tid; i4 < 6480; i4 += 256) {       // 4u*54rr*30c4
            int u = i4 / 1620;
            int rem = i4 - u * 1620;
            int rr = rem / 30;
            int cc = (rem - rr * 30) * 4;
            int gy = y0 + rr, gx = x0 + cc;
            ushort4 val = {0, 0, 0, 0};
            if (gy >= 0 && gy < HH && gx >= 0 && gx <= HH - 4)
                val = *(const ushort4*)(vb + u * NN + gy * HH + gx);
            *(ushort4*)(in_s + (u * 54 + rr) * CSTR + cc) = val;
        }
    }
    __syncthreads();
    if (tid < 16) {
        float s = 0.f;
        #pragma unroll
        for (int sl = 0; sl < 16; ++sl) s += lc_red[sl][tid];
        lc_s[tid] = s + pb[tid];
    }
    __syncthreads();

    const int lane = tid & 63, wv = tid >> 6;
    const int wy = wv >> 1, wx = wv & 1;
    const int nl = lane & 15, quad = lane >> 4;
    const USH* sbase = in_s + (wy * 16 + nl) * CSTR + wx * 48 + quad * 8;
    const int ybase = yt * 32 + wy * 16 + nl;
    float lcr0 = lc_s[quad * 4], lcr1 = lc_s[quad * 4 + 1],
          lcr2 = lc_s[quad * 4 + 2], lcr3 = lc_s[quad * 4 + 3];
    const USH* qbase = qT + ((size_t)b * NN + ybase * HH) * 64 + quad * 4;
    USH* ybbase = yb + ((size_t)b * 64 + quad * 16 + vvch) * NN + ybase * HH;
    float SG = 0.f, QG = 0.f;

#define CONV_EPILOGUE(ACC, RVAL)                                                            \
    {                                                                                       \
        _Pragma("unroll")                                                                   \
        for (int xi = 0; xi < 6; ++xi) {                                                    \
            int x = xh * 96 + wx * 48 + (RVAL) + 8 * xi;                                    \
            float l0 = ACC[xi][0] + lcr0, l1 = ACC[xi][1] + lcr1;                           \
            float l2 = ACC[xi][2] + lcr2, l3 = ACC[xi][3] + lcr3;                           \
            const USH* qp = qbase + (size_t)x * 64;                                         \
            float s0, s1, s2, s3;                                                           \
            {                                                                               \
                ushort4 q4 = *(const ushort4*)(qp);                                         \
                s0 = bf2f(q4.x) * l0 + bf2f(q4.y) * l1 + bf2f(q4.z) * l2 + bf2f(q4.w) * l3; \
            }                                                                               \
            {                                                                               \
                ushort4 q4 = *(const ushort4*)(qp + 16);                                    \
                s1 = bf2f(q4.x) * l0 + bf2f(q4.y) * l1 + bf2f(q4.z) * l2 + bf2f(q4.w) * l3; \
            }                                                                               \
            {                                                                               \
                ushort4 q4 = *(const ushort4*)(qp + 32);                                    \
                s2 = bf2f(q4.x) * l0 + bf2f(q4.y) * l1 + bf2f(q4.z) * l2 + bf2f(q4.w) * l3; \
            }                                                                               \
            {                                                                               \
                ushort4 q4 = *(const ushort4*)(qp + 48);                                    \
                s3 = bf2f(q4.x) * l0 + bf2f(q4.y) * l1 + bf2f(q4.z) * l2 + bf2f(q4.w) * l3; \
            }                                                                               \
            s0 += __shfl_xor(s0, 16); s0 += __shfl_xor(s0, 32);                             \
            s1 += __shfl_xor(s1, 16); s1 += __shfl_xor(s1, 32);                             \
            s2 += __shfl_xor(s2, 16); s2 += __shfl_xor(s2, 32);                             \
            s3 += __shfl_xor(s3, 16); s3 += __shfl_xor(s3, 32);                             \
            float sel = (quad == 0) ? s0 : (quad == 1) ? s1 : (quad == 2) ? s2 : s3;        \
            USH wo = f2bf(sel);                                                             \
            ybbase[x] = wo;                                                                 \
            float wf = bf2f(wo);                                                            \
            SG += wf; QG += wf * wf;                                                        \
        }                                                                                   \
    }

#define CONV_PASS3(R0)                                                                      \
    {                                                                                       \
        f32x4 acc0[6] = {}; f32x4 acc1[6] = {}; f32x4 acc2[6] = {};                         \
        for (int u = 0; u < 4; ++u) {                                                       \
            const bf16x8* ap0 = apre + ((size_t)((R0) * 4 + u) * 23) * 64 + lane;           \
            const bf16x8* ap1 = ap0 + 4 * 23 * 64;                                          \
            const bf16x8* ap2 = ap0 + 2 * 4 * 23 * 64;                                      \
            const USH* srow = sbase + u * (54 * CSTR);                                      \
            _Pragma("unroll 2")                                                             \
            for (int dy = 0; dy < 23; ++dy) {                                               \
                bf16x8 a0 = *ap0, a1 = *ap1, a2 = *ap2;                                     \
                _Pragma("unroll")                                                           \
                for (int xi = 0; xi < 6; ++xi) {                                            \
                    bf16x8 bfr = *(const bf16x8*)(srow + 8 * xi);                           \
                    acc0[xi] = MFMA16(a0, bfr, acc0[xi]);                                   \
                    acc1[xi] = MFMA16(a1, bfr, acc1[xi]);                                   \
                    acc2[xi] = MFMA16(a2, bfr, acc2[xi]);                                   \
                }                                                                           \
                ap0 += 64; ap1 += 64; ap2 += 64; srow += CSTR;                               \
            }                                                                               \
        }                                                                                   \
        CONV_EPILOGUE(acc0, (R0))                                                           \
        CONV_EPILOGUE(acc1, (R0) + 1)                                                       \
        CONV_EPILOGUE(acc2, (R0) + 2)                                                       \
    }

    CONV_PASS3(0)
    CONV_PASS3(3)
    {   // last pass: r = 6,7
        f32x4 acc0[6] = {}; f32x4 acc1[6] = {};
        for (int u = 0; u < 4; ++u) {
            const bf16x8* ap0 = apre + ((size_t)(6 * 4 + u) * 23) * 64 + lane;
            const bf16x8* ap1 = ap0 + 4 * 23 * 64;
            const USH* srow = sbase + u * (54 * CSTR);
            #pragma unroll 2
            for (int dy = 0; dy < 23; ++dy) {
                bf16x8 a0 = *ap0, a1 = *ap1;
                #pragma unroll
                for (int xi = 0; xi < 6; ++xi) {
                    bf16x8 bfr = *(const bf16x8*)(srow + 8 * xi);
                    acc0[xi] = MFMA16(a0, bfr, acc0[xi]);
                    acc1[xi] = MFMA16(a1, bfr, acc1[xi]);
                }
                ap0 += 64; ap1 += 64; srow += CSTR;
            }
        }
        CONV_EPILOGUE(acc0, 6)
        CONV_EPILOGUE(acc1, 7)
    }
#undef CONV_PASS3
#undef CONV_EPILOGUE

    // GN partials: reduce Σ/Σ² over nl within each quad group (channel fixed)
    SG += __shfl_xor(SG, 1); SG += __shfl_xor(SG, 2); SG += __shfl_xor(SG, 4); SG += __shfl_xor(SG, 8);
    QG += __shfl_xor(QG, 1); QG += __shfl_xor(QG, 2); QG += __shfl_xor(QG, 4); QG += __shfl_xor(QG, 8);
    if (nl == 0) { gn_s[wv * 4 + quad] = SG; gn_q[wv * 4 + quad] = QG; }
    __syncthreads();
    if (tid < 4) {
        float s = gn_s[tid] + gn_s[4 + tid] + gn_s[8 + tid] + gn_s[12 + tid];
        float q = gn_q[tid] + gn_q[4 + tid] + gn_q[8 + tid] + gn_q[12 + tid];
        int lin = img * 12 + yt * 2 + xh;
        gnp2[lin * 8 + tid * 2]     = s;
        gnp2[lin * 8 + tid * 2 + 1] = q;
    }
}

// ---------------------------------------------------------------- FUSED GN-stats + GN-normalize + QKV GEMM (L->L+1)
// R9: gn_passB folded in — 64-thread partials (per (g,vv), tile-inner order
// matching the old gn_passB loop exactly) + 8-thread combine (vv order ==
// old outer loop) -> identical numerics, one fewer dispatch per layer.
__global__ __launch_bounds__(256) void gn_qkv_k(
    const USH* __restrict__ yb, const float* __restrict__ gnp2,
    const float* __restrict__ gg, const float* __restrict__ gb,
    const bf16x8* __restrict__ apre, const float* __restrict__ bias,
    USH* __restrict__ qT, USH* __restrict__ kbuf, USH* __restrict__ vbuf) {
    __shared__ float tf[64][65];
    __shared__ float sc[64], sb[64];
    __shared__ float grs[64], grq[64], st_s[16];
    const int bid = blockIdx.x; const int b = bid / 576; const int nt = bid - b * 576; const int n0 = nt * 64;
    const int tid = threadIdx.x, lane = tid & 63, wq = tid >> 6;
    const int nl = lane & 15, quad = lane >> 4;
    bf16x8 afr[24];
    #pragma unroll
    for (int i = 0; i < 24; ++i) afr[i] = apre[i * 64 + lane];
    if (tid < 64) {
        int g = tid >> 3, vv = tid & 7;
        int qg = g >> 1, v0 = (g & 1) * 8;
        float s = 0.f, q = 0.f;
        #pragma unroll
        for (int tile = 0; tile < 12; ++tile) {
            const float* p = gnp2 + ((size_t)((b * 16 + v0 + vv) * 12 + tile)) * 8 + qg * 2;
            s += p[0]; q += p[1];
        }
        grs[tid] = s; grq[tid] = q;
    }
    __syncthreads();
    if (tid < 8) {
        float s = 0.f, q = 0.f;
        #pragma unroll
        for (int vv = 0; vv < 8; ++vv) { s += grs[tid * 8 + vv]; q += grq[tid * 8 + vv]; }
        float mean = s / 294912.0f;
        float var = q / 294912.0f - mean * mean;
        st_s[tid * 2] = mean;
        st_s[tid * 2 + 1] = rsqrtf(fmaxf(var, 0.0f) + 1e-5f);
    }
    __syncthreads();
    if (tid < 64) {
        int g = tid >> 3;
        float mean = st_s[g * 2], rstd = st_s[g * 2 + 1];
        float ga = gg[tid];
        sc[tid] = rstd * ga;
        sb[tid] = gb[tid] - mean * rstd * ga;
    }
    __syncthreads();
    #pragma unroll
    for (int p = 0; p < 4; ++p) {
        int c = p * 16 + (tid >> 4), nn = (tid & 15) * 4;
        ushort4 y4 = *(const ushort4*)(yb + ((size_t)b * 64 + c) * NN + n0 + nn);
        float scc = sc[c], sbc = sb[c];
        tf[nn][c]     = bf2f(y4.x) * scc + sbc;
        tf[nn + 1][c] = bf2f(y4.y) * scc + sbc;
        tf[nn + 2][c] = bf2f(y4.z) * scc + sbc;
        tf[nn + 3][c] = bf2f(y4.w) * scc + sbc;
    }
    __syncthreads();
    bf16x8 b0, b1;
    #pragma unroll
    for (int j = 0; j < 8; ++j) {
        b0[j] = (short)f2bf(tf[wq * 16 + nl][quad * 8 + j]);
        b1[j] = (short)f2bf(tf[wq * 16 + nl][32 + quad * 8 + j]);
    }
    const int n = n0 + wq * 16 + nl;
    #pragma unroll
    for (int mt = 0; mt < 12; ++mt) {
        f32x4 acc = {0.f, 0.f, 0.f, 0.f};
        acc = MFMA16(afr[mt * 2 + 0], b0, acc);
        acc = MFMA16(afr[mt * 2 + 1], b1, acc);
        int o0 = mt * 16 + quad * 4;
        float4 bs = *(const float4*)(bias + o0);
        float v0 = acc[0] + bs.x, v1 = acc[1] + bs.y, v2 = acc[2] + bs.z, v3 = acc[3] + bs.w;
        if (mt < 4) {
            ushort4 pk; pk.x = f2bf(v0); pk.y = f2bf(v1); pk.z = f2bf(v2); pk.w = f2bf(v3);
            *(ushort4*)(qT + ((size_t)b * NN + n) * 64 + o0) = pk;
        } else if (mt < 8) {
            int ko = o0 - 64;
            kbuf[((size_t)b * 64 + ko    ) * NN + n] = f2bf(v0);
            kbuf[((size_t)b * 64 + ko + 1) * NN + n] = f2bf(v1);
            kbuf[((size_t)b * 64 + ko + 2) * NN + n] = f2bf(v2);
            kbuf[((size_t)b * 64 + ko + 3) * NN + n] = f2bf(v3);
        } else {
            int u = mt - 8, vv0 = quad * 4;
            vbuf[(((size_t)b * 16 + vv0    ) * 4 + u) * NN + n] = f2bf(v0);
            vbuf[(((size_t)b * 16 + vv0 + 1) * 4 + u) * NN + n] = f2bf(v1);
            vbuf[(((size_t)b * 16 + vv0 + 2) * 4 + u) * NN + n] = f2bf(v2);
            vbuf[(((size_t)b * 16 + vv0 + 3) * 4 + u) * NN + n] = f2bf(v3);
        }
    }
}

// ---------------------------------------------------------------- FUSED GN-stats + GN-normalize + final conv1x1 + *0.2 + x
__global__ __launch_bounds__(256) void gn_final_k(
    const USH* __restrict__ yb, const float* __restrict__ gnp2,
    const float* __restrict__ gg, const float* __restrict__ gb,
    const bf16x8* __restrict__ apre, const float* __restrict__ cb,
    const float* __restrict__ xin, float* __restrict__ out) {
    __shared__ float tf[64][65];
    __shared__ float sc[64], sb[64];
    __shared__ float grs[64], grq[64], st_s[16];
    const int bid = blockIdx.x; const int b = bid / 576; const int nt = bid - b * 576; const int n0 = nt * 64;
    const int tid = threadIdx.x, lane = tid & 63, wq = tid >> 6;
    const int nl = lane & 15, quad = lane >> 4;
    bf16x8 afr[8];
    #pragma unroll
    for (int i = 0; i < 8; ++i) afr[i] = apre[i * 64 + lane];
    if (tid < 64) {
        int g = tid >> 3, vv = tid & 7;
        int qg = g >> 1, v0 = (g & 1) * 8;
        float s = 0.f, q = 0.f;
        #pragma unroll
        for (int tile = 0; tile < 12; ++tile) {
            const float* p = gnp2 + ((size_t)((b * 16 + v0 + vv) * 12 + tile)) * 8 + qg * 2;
            s += p[0]; q += p[1];
        }
        grs[tid] = s; grq[tid] = q;
    }
    __syncthreads();
    if (tid < 8) {
        float s = 0.f, q = 0.f;
        #pragma unroll
        for (int vv = 0; vv < 8; ++vv) { s += grs[tid * 8 + vv]; q += grq[tid * 8 + vv]; }
        float mean = s / 294912.0f;
        float var = q / 294912.0f - mean * mean;
        st_s[tid * 2] = mean;
        st_s[tid * 2 + 1] = rsqrtf(fmaxf(var, 0.0f) + 1e-5f);
    }
    __syncthreads();
    if (tid < 64) {
        int g = tid >> 3;
        float mean = st_s[g * 2], rstd = st_s[g * 2 + 1];
        float ga = gg[tid];
        sc[tid] = rstd * ga;
        sb[tid] = gb[tid] - mean * rstd * ga;
    }
    __syncthreads();
    #pragma unroll
    for (int p = 0; p < 4; ++p) {
        int c = p * 16 + (tid >> 4), nn = (tid & 15) * 4;
        ushort4 y4 = *(const ushort4*)(yb + ((size_t)b * 64 + c) * NN + n0 + nn);
        float scc = sc[c], sbc = sb[c];
        tf[nn][c]     = bf2f(y4.x) * scc + sbc;
        tf[nn + 1][c] = bf2f(y4.y) * scc + sbc;
        tf[nn + 2][c] = bf2f(y4.z) * scc + sbc;
        tf[nn + 3][c] = bf2f(y4.w) * scc + sbc;
    }
    __syncthreads();
    bf16x8 b0, b1;
    #pragma unroll
    for (int j = 0; j < 8; ++j) {
        b0[j] = (short)f2bf(tf[wq * 16 + nl][quad * 8 + j]);
        b1[j] = (short)f2bf(tf[wq * 16 + nl][32 + quad * 8 + j]);
    }
    const int n = n0 + wq * 16 + nl;
    #pragma unroll
    for (int mt = 0; mt < 4; ++mt) {
        f32x4 acc = {0.f, 0.f, 0.f, 0.f};
        acc = MFMA16(afr[mt * 2 + 0], b0, acc);
        acc = MFMA16(afr[mt * 2 + 1], b1, acc);
        int o0 = mt * 16 + quad * 4;
        float4 cb4 = *(const float4*)(cb + o0);
        float cbv[4] = { cb4.x, cb4.y, cb4.z, cb4.w };
        #pragma unroll
        for (int rg = 0; rg < 4; ++rg) {
            int o = o0 + rg;
            float xv = xin[((size_t)b * 64 + o) * NN + n];
            out[((size_t)b * 64 + o) * NN + n] = (acc[rg] + cbv[rg]) * 0.2f + xv;
        }
    }
}

// ================================================================ host
extern "C" void kernel_launch(void* const* d_in, const int* in_sizes, int n_in,
                              void* d_out, int out_size, void* d_ws, size_t ws_size,
                              hipStream_t stream) {
    (void)in_sizes; (void)n_in; (void)out_size; (void)ws_size;
    const float* x = (const float*)d_in[0];
    char* ws = (char*)d_ws;

    // 4 bf16 planes, ping-pong aliasing (ybuf(L) = kbuf(L) plane; next-layer k
    // goes to the dead plane): L0 y=P2 -> k'=P0 ; L1 y=P0 -> k'=P2 ; L2 y=P2 -> out.
    const size_t SZP = (size_t)NTOT * 64 * 2;          // 18,874,368 B
    USH*   P0 = (USH*)(ws);                            // k(L1)/y(L1)
    USH*   P1 = (USH*)(ws + SZP);                      // qT (all layers)
    USH*   P2 = (USH*)(ws + 2 * SZP);                  // k(L0)/y(L0), k(L2)/y(L2)
    USH*   P3 = (USH*)(ws + 3 * SZP);                  // v (all layers)
    char*  tail  = ws + 4 * SZP;
    USH*   apc   = (USH*)(tail);            tail += 753664 * 3;   // conv A-frags x3 layers
    USH*   apq   = (USH*)(tail);            tail += 24576 * 3;    // qkv A-frags x3
    float* biasq = (float*)(tail);          tail += 768 * 3;
    USH*   apf   = (USH*)(tail);            tail += 8192;         // final A-frags
    float* lcp   = (float*)(tail);          tail += 3145728;      // lam_c partials (NCH=192 chunks)
    float* gnp2  = (float*)(tail);          tail += 24576;        // GN partials from conv (6144 floats)
    float* kst   = (float*)(tail);                                // softmax stats (256 rows x 2)

    PrepArgs pa;
    for (int L = 0; L < 3; ++L) {
        int base = 1 + L * 9;
        pa.wq[L] = (const float*)d_in[base + 0];
        pa.wk[L] = (const float*)d_in[base + 1];
        pa.wv[L] = (const float*)d_in[base + 2];
        pa.qg[L] = (const float*)d_in[base + 3];
        pa.qb[L] = (const float*)d_in[base + 4];
        pa.vg[L] = (const float*)d_in[base + 5];
        pa.vb[L] = (const float*)d_in[base + 6];
        pa.pw[L] = (const float*)d_in[base + 7];
    }
    pa.cw = (const float*)d_in[32];

    prep_all_k<<<572, 256, 0, stream>>>(pa, apc, apq, biasq, apf);

    // L0 qkv directly from fp32 x (fused transpose)
    x_qkv_k<<<2304, 256, 0, stream>>>(x, (const bf16x8*)apq, biasq, P1, P2, P3);

    for (int L = 0; L < 3; ++L) {
        const float* pb = (const float*)d_in[1 + L * 9 + 8];
        USH* kv = (L == 1) ? P0 : P2;          // kbuf == ybuf plane of this layer

        softstat_k<<<256, 1024, 0, stream>>>(kv, kst);
        lamc_stage1_k<<<NCH * 16, 64, 0, stream>>>(kv, P3, kst, lcp);
        dim3 cg(2, 6, 64);
        conv_pos_fused_k<<<cg, 256, 0, stream>>>(P3, (const bf16x8*)apc + (size_t)L * 47104,
                                                 P1, lcp, pb, kv, gnp2);
        if (L < 2) {
            const float* gg = (const float*)d_in[28];
            const float* gb = (const float*)d_in[29];
            USH* knext = (L == 0) ? P0 : P2;
            gn_qkv_k<<<2304, 256, 0, stream>>>(kv, gnp2, gg, gb,
                                               (const bf16x8*)apq + (size_t)(L + 1) * 1536,
                                               biasq + (L + 1) * 192, P1, knext, P3);
        } else {
            const float* gg = (const float*)d_in[30];
            const float* gb = (const float*)d_in[31];
            gn_final_k<<<2304, 256, 0, stream>>>(kv, gnp2, gg, gb, (const bf16x8*)apf,
                                                 (const float*)d_in[33], x, (float*)d_out);
        }
    }
}